// Round 1
// baseline (15644.991 us; speedup 1.0000x reference)
//
#include <hip/hip_runtime.h>
#include <math.h>

#define S_LEN 1024
#define D_MODEL 768
#define NHEAD 12
#define NKMAX 257
#define NEG_INF -3.4028234663852886e38f

__device__ __forceinline__ float gelu_exact(float v) {
  return 0.5f * v * (1.0f + erff(v * 0.7071067811865475f));
}

// ---------------- embedding + sinusoidal positional encoding ----------------
__global__ __launch_bounds__(256) void embed_kernel(
    const int* __restrict__ tok, const float* __restrict__ emb,
    float* __restrict__ X, int total) {
  int i = blockIdx.x * 256 + threadIdx.x;
  if (i >= total) return;
  int d = i % D_MODEL;
  int bs = i / D_MODEL;
  int s = bs & (S_LEN - 1);
  int t = tok[bs];
  double div = exp((double)(d & ~1) * (-9.210340371976184 / 768.0));
  double ang = (double)s * div;
  float pe = (d & 1) ? (float)cos(ang) : (float)sin(ang);
  X[i] = emb[(size_t)t * D_MODEL + d] + pe;
}

// ---------------- LayerNorm over D=768, one block (256 thr) per row ----------------
__global__ __launch_bounds__(256) void ln_kernel(
    const float* __restrict__ X, const float* __restrict__ gam,
    const float* __restrict__ bet, float* __restrict__ Y) {
  __shared__ float scratch[4];
  const int row = blockIdx.x;
  const int tid = threadIdx.x;
  const float* xr = X + (size_t)row * D_MODEL;
  float v0 = xr[tid], v1 = xr[tid + 256], v2 = xr[tid + 512];
  float s = v0 + v1 + v2;
#pragma unroll
  for (int o = 32; o; o >>= 1) s += __shfl_xor(s, o, 64);
  if ((tid & 63) == 0) scratch[tid >> 6] = s;
  __syncthreads();
  float mean = (scratch[0] + scratch[1] + scratch[2] + scratch[3]) * (1.0f / 768.0f);
  __syncthreads();
  float d0 = v0 - mean, d1 = v1 - mean, d2 = v2 - mean;
  float ss = d0 * d0 + d1 * d1 + d2 * d2;
#pragma unroll
  for (int o = 32; o; o >>= 1) ss += __shfl_xor(ss, o, 64);
  if ((tid & 63) == 0) scratch[tid >> 6] = ss;
  __syncthreads();
  float var = (scratch[0] + scratch[1] + scratch[2] + scratch[3]) * (1.0f / 768.0f);
  float rstd = rsqrtf(var + 1e-5f);
  float* yr = Y + (size_t)row * D_MODEL;
  yr[tid]       = d0 * rstd * gam[tid]       + bet[tid];
  yr[tid + 256] = d1 * rstd * gam[tid + 256] + bet[tid + 256];
  yr[tid + 512] = d2 * rstd * gam[tid + 512] + bet[tid + 512];
}

// ---------------- fp32 tiled GEMM: C[m,n] = sum_k A[m,k]*W[n,k] (+bias, epilogue) ----
// EPI 0: C = acc+bias   1: C = gelu(acc+bias)   2: C += acc+bias (residual)
template <int EPI>
__global__ __launch_bounds__(256) void gemm_nt(
    const float* __restrict__ A, const float* __restrict__ Wm,
    const float* __restrict__ bias, float* __restrict__ C,
    int M, int N, int K) {
  __shared__ __align__(16) float As[16][64];
  __shared__ __align__(16) float Bs[16][64];
  const int tid = threadIdx.x;
  const int m0 = blockIdx.y << 6, n0 = blockIdx.x << 6;
  const int lr = tid >> 2;          // 0..63 row within tile
  const int lc = (tid & 3) << 2;    // 0,4,8,12 k offset
  const int ty = tid >> 4, tx = tid & 15;
  float acc[4][4] = {};
  const float* Ap = A + (size_t)(m0 + lr) * K + lc;
  const float* Wp = Wm + (size_t)(n0 + lr) * K + lc;
  for (int k0 = 0; k0 < K; k0 += 16) {
    float4 a4 = *(const float4*)(Ap + k0);
    float4 w4 = *(const float4*)(Wp + k0);
    As[lc + 0][lr] = a4.x; As[lc + 1][lr] = a4.y; As[lc + 2][lr] = a4.z; As[lc + 3][lr] = a4.w;
    Bs[lc + 0][lr] = w4.x; Bs[lc + 1][lr] = w4.y; Bs[lc + 2][lr] = w4.z; Bs[lc + 3][lr] = w4.w;
    __syncthreads();
#pragma unroll
    for (int k = 0; k < 16; ++k) {
      float4 av = *(const float4*)(&As[k][ty << 2]);
      float4 wv = *(const float4*)(&Bs[k][tx << 2]);
      float aa[4] = {av.x, av.y, av.z, av.w};
      float ww[4] = {wv.x, wv.y, wv.z, wv.w};
#pragma unroll
      for (int i = 0; i < 4; ++i)
#pragma unroll
        for (int j = 0; j < 4; ++j)
          acc[i][j] += aa[i] * ww[j];
    }
    __syncthreads();
  }
  const int n_off = n0 + (tx << 2);
  float4 bv = *(const float4*)(bias + n_off);
#pragma unroll
  for (int i = 0; i < 4; ++i) {
    const int m = m0 + (ty << 2) + i;
    float* crow = C + (size_t)m * N + n_off;
    float r0 = acc[i][0] + bv.x, r1 = acc[i][1] + bv.y;
    float r2 = acc[i][2] + bv.z, r3 = acc[i][3] + bv.w;
    if (EPI == 1) { r0 = gelu_exact(r0); r1 = gelu_exact(r1); r2 = gelu_exact(r2); r3 = gelu_exact(r3); }
    if (EPI == 2) { float4 cv = *(const float4*)crow; r0 += cv.x; r1 += cv.y; r2 += cv.z; r3 += cv.w; }
    float4 ov; ov.x = r0; ov.y = r1; ov.z = r2; ov.w = r3;
    *(float4*)crow = ov;
  }
}

// ---------------- banded attention: one block per (b,q), 12 waves = 12 heads ------
__global__ __launch_bounds__(768) void attn_kernel(
    const float* __restrict__ qkv, const int* __restrict__ mask,
    float* __restrict__ attn_out, float* __restrict__ allw) {
  const int q = blockIdx.x;
  const int b = blockIdx.y;
  const int tid = threadIdx.x;
  const int h = tid >> 6, lane = tid & 63;
  __shared__ __align__(16) float qv[D_MODEL];
  __shared__ float wls[NHEAD * NKMAX];
  const size_t rowq = ((size_t)b * S_LEN + q) * 2304;
  qv[tid] = qkv[rowq + tid] * 0.125f;  // 1/sqrt(64)
  __syncthreads();
  int k0 = q - 128; if (k0 < 0) k0 = 0;
  int k1 = q + 128; if (k1 > S_LEN - 1) k1 = S_LEN - 1;
  const int nk = k1 - k0 + 1;
  const float* qh = &qv[h << 6];
  // scores
  for (int j = lane; j < nk; j += 64) {
    const int kk = k0 + j;
    const float* kr = qkv + ((size_t)b * S_LEN + kk) * 2304 + 768 + (h << 6);
    float acc = 0.0f;
#pragma unroll
    for (int d = 0; d < 64; d += 4) {
      float4 kvv = *(const float4*)(kr + d);
      float4 qq = *(const float4*)(qh + d);
      acc += qq.x * kvv.x + qq.y * kvv.y + qq.z * kvv.z + qq.w * kvv.w;
    }
    if (mask[b * S_LEN + kk] == 0) acc = NEG_INF;
    wls[h * NKMAX + j] = acc;
  }
  // per-wave softmax (each wave owns its head's row; own-lane LDS slots only)
  float lmax = NEG_INF;
  for (int j = lane; j < nk; j += 64) lmax = fmaxf(lmax, wls[h * NKMAX + j]);
#pragma unroll
  for (int o = 32; o; o >>= 1) lmax = fmaxf(lmax, __shfl_xor(lmax, o, 64));
  float lsum = 0.0f;
  for (int j = lane; j < nk; j += 64) {
    float e = expf(wls[h * NKMAX + j] - lmax);
    wls[h * NKMAX + j] = e;
    lsum += e;
  }
#pragma unroll
  for (int o = 32; o; o >>= 1) lsum += __shfl_xor(lsum, o, 64);
  const float inv = 1.0f / lsum;
  for (int j = lane; j < nk; j += 64) wls[h * NKMAX + j] *= inv;
  __syncthreads();
  // attention output: lane = output dim d within head
  {
    float acc = 0.0f;
    const float* vbase = qkv + ((size_t)b * S_LEN + k0) * 2304 + 1536 + (h << 6) + lane;
    const float* wrow = &wls[h * NKMAX];
    for (int j = 0; j < nk; ++j) acc += wrow[j] * vbase[(size_t)j * 2304];
    attn_out[((size_t)b * S_LEN + q) * D_MODEL + (h << 6) + lane] = acc;
  }
  // head-averaged weights -> d_out band (outside band stays memset-0)
  float* wout = allw + ((size_t)b * S_LEN + q) * S_LEN + k0;
  for (int t = tid; t < nk; t += 768) {
    float sum = 0.0f;
#pragma unroll
    for (int hh = 0; hh < NHEAD; ++hh) sum += wls[hh * NKMAX + t];
    wout[t] = sum * (1.0f / 12.0f);
  }
}

// ---------------- attention pooling + classifier head: one block per batch -------
__global__ __launch_bounds__(256) void cls_kernel(
    const float* __restrict__ X, const int* __restrict__ mask,
    const float* __restrict__ pool_w, const float* __restrict__ pool_b,
    const float* __restrict__ ln_s, const float* __restrict__ ln_b,
    const float* __restrict__ w1, const float* __restrict__ b1,
    const float* __restrict__ w2, const float* __restrict__ b2,
    float* __restrict__ out) {
  const int b = blockIdx.x;
  const int tid = threadIdx.x;
  __shared__ float scratch[4];
  __shared__ __align__(16) float sc[S_LEN];
  __shared__ __align__(16) float pbuf[D_MODEL];
  __shared__ __align__(16) float cbuf[D_MODEL];
  const float* xb = X + (size_t)b * S_LEN * D_MODEL;
  for (int d = tid; d < D_MODEL; d += 256) pbuf[d] = pool_w[d];
  __syncthreads();
  // pooling scores
  for (int s = tid; s < S_LEN; s += 256) {
    const float* xr = xb + (size_t)s * D_MODEL;
    float acc = 0.0f;
    for (int d = 0; d < D_MODEL; d += 4) {
      float4 xv = *(const float4*)(xr + d);
      float4 wv = *(const float4*)(&pbuf[d]);
      acc += xv.x * wv.x + xv.y * wv.y + xv.z * wv.z + xv.w * wv.w;
    }
    acc += pool_b[0];
    sc[s] = (mask[b * S_LEN + s] == 0) ? NEG_INF : acc;
  }
  __syncthreads();
  // softmax over S
  float m = NEG_INF;
  for (int s = tid; s < S_LEN; s += 256) m = fmaxf(m, sc[s]);
#pragma unroll
  for (int o = 32; o; o >>= 1) m = fmaxf(m, __shfl_xor(m, o, 64));
  if ((tid & 63) == 0) scratch[tid >> 6] = m;
  __syncthreads();
  m = fmaxf(fmaxf(scratch[0], scratch[1]), fmaxf(scratch[2], scratch[3]));
  __syncthreads();
  float zs = 0.0f;
  for (int s = tid; s < S_LEN; s += 256) { float e = expf(sc[s] - m); sc[s] = e; zs += e; }
#pragma unroll
  for (int o = 32; o; o >>= 1) zs += __shfl_xor(zs, o, 64);
  if ((tid & 63) == 0) scratch[tid >> 6] = zs;
  __syncthreads();
  float Z = scratch[0] + scratch[1] + scratch[2] + scratch[3];
  __syncthreads();
  const float invZ = 1.0f / Z;
  for (int s = tid; s < S_LEN; s += 256) sc[s] *= invZ;
  __syncthreads();
  // pooled = tanh(sum_s w_s * x_s)  -> pbuf
  for (int d = tid; d < D_MODEL; d += 256) {
    float acc = 0.0f;
    for (int s = 0; s < S_LEN; ++s) acc += sc[s] * xb[(size_t)s * D_MODEL + d];
    pbuf[d] = tanhf(acc);
  }
  __syncthreads();
  // LayerNorm(pbuf) -> cbuf
  float ls = 0.0f;
  for (int d = tid; d < D_MODEL; d += 256) ls += pbuf[d];
#pragma unroll
  for (int o = 32; o; o >>= 1) ls += __shfl_xor(ls, o, 64);
  if ((tid & 63) == 0) scratch[tid >> 6] = ls;
  __syncthreads();
  float mean = (scratch[0] + scratch[1] + scratch[2] + scratch[3]) * (1.0f / 768.0f);
  __syncthreads();
  float vs = 0.0f;
  for (int d = tid; d < D_MODEL; d += 256) { float dd = pbuf[d] - mean; vs += dd * dd; }
#pragma unroll
  for (int o = 32; o; o >>= 1) vs += __shfl_xor(vs, o, 64);
  if ((tid & 63) == 0) scratch[tid >> 6] = vs;
  __syncthreads();
  float var = (scratch[0] + scratch[1] + scratch[2] + scratch[3]) * (1.0f / 768.0f);
  float rstd = rsqrtf(var + 1e-5f);
  __syncthreads();
  for (int d = tid; d < D_MODEL; d += 256)
    cbuf[d] = (pbuf[d] - mean) * rstd * ln_s[d] + ln_b[d];
  __syncthreads();
  // c1 = tanh(cbuf @ w1^T + b1) -> sc[0..767]
  for (int i = tid; i < D_MODEL; i += 256) {
    const float* wr = w1 + (size_t)i * D_MODEL;
    float acc = 0.0f;
    for (int d = 0; d < D_MODEL; d += 4) {
      float4 wv = *(const float4*)(wr + d);
      float4 cv = *(const float4*)(&cbuf[d]);
      acc += wv.x * cv.x + wv.y * cv.y + wv.z * cv.z + wv.w * cv.w;
    }
    sc[i] = tanhf(acc + b1[i]);
  }
  __syncthreads();
  // logits
#pragma unroll
  for (int jc = 0; jc < 2; ++jc) {
    float acc = 0.0f;
    for (int i = tid; i < D_MODEL; i += 256) acc += sc[i] * w2[jc * D_MODEL + i];
#pragma unroll
    for (int o = 32; o; o >>= 1) acc += __shfl_xor(acc, o, 64);
    if ((tid & 63) == 0) scratch[tid >> 6] = acc;
    __syncthreads();
    if (tid == 0) out[b * 2 + jc] = scratch[0] + scratch[1] + scratch[2] + scratch[3] + b2[jc];
    __syncthreads();
  }
}

extern "C" void kernel_launch(void* const* d_in, const int* in_sizes, int n_in,
                              void* d_out, int out_size, void* d_ws, size_t ws_size,
                              hipStream_t stream) {
  const int*   tokens  = (const int*)d_in[0];
  const int*   mask    = (const int*)d_in[1];
  const float* emb     = (const float*)d_in[2];
  const float* in_w    = (const float*)d_in[3];
  const float* in_b    = (const float*)d_in[4];
  const float* out_w   = (const float*)d_in[5];
  const float* out_b   = (const float*)d_in[6];
  const float* ln1_s   = (const float*)d_in[7];
  const float* ln1_b   = (const float*)d_in[8];
  const float* ln2_s   = (const float*)d_in[9];
  const float* ln2_b   = (const float*)d_in[10];
  const float* ff_w1   = (const float*)d_in[11];
  const float* ff_b1   = (const float*)d_in[12];
  const float* ff_w2   = (const float*)d_in[13];
  const float* ff_b2   = (const float*)d_in[14];
  const float* pool_w  = (const float*)d_in[15];
  const float* pool_b  = (const float*)d_in[16];
  const float* cls_ln_s = (const float*)d_in[17];
  const float* cls_ln_b = (const float*)d_in[18];
  const float* cls_w1  = (const float*)d_in[19];
  const float* cls_b1  = (const float*)d_in[20];
  const float* cls_w2  = (const float*)d_in[21];
  const float* cls_b2  = (const float*)d_in[22];

  float* outp = (float*)d_out;
  float* ws = (float*)d_ws;
  const size_t XN = (size_t)8 * 1024 * 768;          // 6,291,456 floats
  float* x   = ws;
  float* h   = ws + XN;
  float* big = ws + 2 * XN;                          // 25,165,824 floats
  float* allw = outp + 16;                           // [L,B,S,S] after [B,2]

  // zero d_out: exact zeros outside attention band + clean logits area
  hipMemsetAsync(d_out, 0, (size_t)out_size * sizeof(float), stream);

  const int total = (int)XN;
  embed_kernel<<<(total + 255) / 256, 256, 0, stream>>>(tokens, emb, x, total);

  for (int l = 0; l < 4; ++l) {
    ln_kernel<<<8192, 256, 0, stream>>>(x, ln1_s + l * 768, ln1_b + l * 768, h);
    gemm_nt<0><<<dim3(36, 128), 256, 0, stream>>>(h, in_w + (size_t)l * 2304 * 768,
                                                  in_b + l * 2304, big, 8192, 2304, 768);
    attn_kernel<<<dim3(1024, 8), 768, 0, stream>>>(big, mask, h,
                                                   allw + (size_t)l * 8 * 1024 * 1024);
    gemm_nt<2><<<dim3(12, 128), 256, 0, stream>>>(h, out_w + (size_t)l * 768 * 768,
                                                  out_b + l * 768, x, 8192, 768, 768);
    ln_kernel<<<8192, 256, 0, stream>>>(x, ln2_s + l * 768, ln2_b + l * 768, h);
    gemm_nt<1><<<dim3(48, 128), 256, 0, stream>>>(h, ff_w1 + (size_t)l * 3072 * 768,
                                                  ff_b1 + l * 3072, big, 8192, 3072, 768);
    gemm_nt<2><<<dim3(12, 128), 256, 0, stream>>>(big, ff_w2 + (size_t)l * 768 * 3072,
                                                  ff_b2 + l * 768, x, 8192, 768, 3072);
  }

  cls_kernel<<<8, 256, 0, stream>>>(x, mask, pool_w, pool_b, cls_ln_s, cls_ln_b,
                                    cls_w1, cls_b1, cls_w2, cls_b2, outp);
}

// Round 2
// 8390.100 us; speedup vs baseline: 1.8647x; 1.8647x over previous
//
#include <hip/hip_runtime.h>
#include <math.h>

#define S_LEN 1024
#define D_MODEL 768
#define NHEAD 12
#define NEG_INF -3.4028234663852886e38f

#define QT 32           // queries per block
#define KB 288          // key band per block = QT + 2*128
#define SMS 304         // P/Pm row stride (304 % 32 == 16 -> 2-way max on RMW)

__device__ __forceinline__ float gelu_exact(float v) {
  return 0.5f * v * (1.0f + erff(v * 0.7071067811865475f));
}
__device__ __forceinline__ float bf2f(unsigned short u) {
  union { unsigned int i; float f; } x; x.i = ((unsigned int)u) << 16; return x.f;
}
__device__ __forceinline__ unsigned short f2bf(float f) {
  union { float f; unsigned int i; } x; x.f = f;
  unsigned int u = x.i;
  u += 0x7fffu + ((u >> 16) & 1u);
  return (unsigned short)(u >> 16);
}

// ---------------- embedding + sinusoidal positional encoding (fp32, matches ref) ---
__global__ __launch_bounds__(256) void embed_kernel(
    const int* __restrict__ tok, const float* __restrict__ emb,
    float* __restrict__ X, int total) {
  int i = blockIdx.x * 256 + threadIdx.x;
  if (i >= total) return;
  int d = i % D_MODEL;
  int bs = i / D_MODEL;
  int s = bs & (S_LEN - 1);
  int t = tok[bs];
  float div = expf((float)(d & ~1) * (-9.210340371976184f / 768.0f));
  float ang = (float)s * div;
  float pe = (d & 1) ? cosf(ang) : sinf(ang);
  X[i] = emb[(size_t)t * D_MODEL + d] + pe;
}

// ---------------- LayerNorm over D=768, one block (256 thr) per row ----------------
__global__ __launch_bounds__(256) void ln_kernel(
    const float* __restrict__ X, const float* __restrict__ gam,
    const float* __restrict__ bet, float* __restrict__ Y) {
  __shared__ float scratch[4];
  const int row = blockIdx.x;
  const int tid = threadIdx.x;
  const float* xr = X + (size_t)row * D_MODEL;
  float v0 = xr[tid], v1 = xr[tid + 256], v2 = xr[tid + 512];
  float s = v0 + v1 + v2;
#pragma unroll
  for (int o = 32; o; o >>= 1) s += __shfl_xor(s, o, 64);
  if ((tid & 63) == 0) scratch[tid >> 6] = s;
  __syncthreads();
  float mean = (scratch[0] + scratch[1] + scratch[2] + scratch[3]) * (1.0f / 768.0f);
  __syncthreads();
  float d0 = v0 - mean, d1 = v1 - mean, d2 = v2 - mean;
  float ss = d0 * d0 + d1 * d1 + d2 * d2;
#pragma unroll
  for (int o = 32; o; o >>= 1) ss += __shfl_xor(ss, o, 64);
  if ((tid & 63) == 0) scratch[tid >> 6] = ss;
  __syncthreads();
  float var = (scratch[0] + scratch[1] + scratch[2] + scratch[3]) * (1.0f / 768.0f);
  float rstd = rsqrtf(var + 1e-5f);
  float* yr = Y + (size_t)row * D_MODEL;
  yr[tid]       = d0 * rstd * gam[tid]       + bet[tid];
  yr[tid + 256] = d1 * rstd * gam[tid + 256] + bet[tid + 256];
  yr[tid + 512] = d2 * rstd * gam[tid + 512] + bet[tid + 512];
}

// ---------------- fp32 tiled GEMM: C[m,n] = sum_k A[m,k]*W[n,k] (+bias, epilogue) ----
// EPI 0: C = acc+bias   1: C = gelu(acc+bias)   2: C += acc+bias (residual)
template <int EPI>
__global__ __launch_bounds__(256) void gemm_nt(
    const float* __restrict__ A, const float* __restrict__ Wm,
    const float* __restrict__ bias, float* __restrict__ C,
    int M, int N, int K) {
  __shared__ __align__(16) float As[16][64];
  __shared__ __align__(16) float Bs[16][64];
  const int tid = threadIdx.x;
  const int m0 = blockIdx.y << 6, n0 = blockIdx.x << 6;
  const int lr = tid >> 2;
  const int lc = (tid & 3) << 2;
  const int ty = tid >> 4, tx = tid & 15;
  float acc[4][4] = {};
  const float* Ap = A + (size_t)(m0 + lr) * K + lc;
  const float* Wp = Wm + (size_t)(n0 + lr) * K + lc;
  for (int k0 = 0; k0 < K; k0 += 16) {
    float4 a4 = *(const float4*)(Ap + k0);
    float4 w4 = *(const float4*)(Wp + k0);
    As[lc + 0][lr] = a4.x; As[lc + 1][lr] = a4.y; As[lc + 2][lr] = a4.z; As[lc + 3][lr] = a4.w;
    Bs[lc + 0][lr] = w4.x; Bs[lc + 1][lr] = w4.y; Bs[lc + 2][lr] = w4.z; Bs[lc + 3][lr] = w4.w;
    __syncthreads();
#pragma unroll
    for (int k = 0; k < 16; ++k) {
      float4 av = *(const float4*)(&As[k][ty << 2]);
      float4 wv = *(const float4*)(&Bs[k][tx << 2]);
      float aa[4] = {av.x, av.y, av.z, av.w};
      float ww[4] = {wv.x, wv.y, wv.z, wv.w};
#pragma unroll
      for (int i = 0; i < 4; ++i)
#pragma unroll
        for (int j = 0; j < 4; ++j)
          acc[i][j] += aa[i] * ww[j];
    }
    __syncthreads();
  }
  const int n_off = n0 + (tx << 2);
  float4 bv = *(const float4*)(bias + n_off);
#pragma unroll
  for (int i = 0; i < 4; ++i) {
    const int m = m0 + (ty << 2) + i;
    float* crow = C + (size_t)m * N + n_off;
    float r0 = acc[i][0] + bv.x, r1 = acc[i][1] + bv.y;
    float r2 = acc[i][2] + bv.z, r3 = acc[i][3] + bv.w;
    if (EPI == 1) { r0 = gelu_exact(r0); r1 = gelu_exact(r1); r2 = gelu_exact(r2); r3 = gelu_exact(r3); }
    if (EPI == 2) { float4 cv = *(const float4*)crow; r0 += cv.x; r1 += cv.y; r2 += cv.z; r3 += cv.w; }
    float4 ov; ov.x = r0; ov.y = r1; ov.z = r2; ov.w = r3;
    *(float4*)crow = ov;
  }
}

// ---------------- banded attention, q-tiled, LDS-resident, bf16 K/V -----------------
// block = (qtile, b); 512 threads = 8 waves; loop over 12 heads.
// wave w owns queries qi = w*4 + qsub (qsub = lane>>4); 16 lanes (jg) per query.
__global__ __launch_bounds__(512) void attn_kernel(
    const float* __restrict__ qkv, const int* __restrict__ mask,
    float* __restrict__ attn_out, float* __restrict__ allw) {
  __shared__ __align__(16) unsigned short Ks[KB * 64];   // swizzled bf16
  __shared__ __align__(16) unsigned short Vs[KB * 64];   // swizzled bf16
  __shared__ __align__(16) float Qs[QT][68];             // fp32, padded
  __shared__ __align__(16) float Pm[QT][SMS];            // head-mean accumulator
  __shared__ __align__(16) float Ps[QT][SMS];            // per-head P
  __shared__ int kvalid[KB];

  const int qt0 = blockIdx.x * QT;
  const int b = blockIdx.y;
  const int tid = threadIdx.x;
  const int wave = tid >> 6, lane = tid & 63;
  const int qsub = lane >> 4, jg = lane & 15;
  const int qi = (wave << 2) + qsub;         // 0..31
  const int k0 = qt0 - 128;

  // init Pm, kvalid
  for (int idx = tid; idx < QT * SMS; idx += 512) ((float*)Pm)[idx] = 0.0f;
  for (int j = tid; j < KB; j += 512) {
    int key = k0 + j;
    kvalid[j] = (key >= 0 && key < S_LEN && mask[b * S_LEN + key] != 0) ? 1 : 0;
  }

  const int r0 = tid >> 4;                    // 0..31
  const int cc4 = (tid & 15) << 2;            // 0..60 step 4

  for (int h = 0; h < NHEAD; ++h) {
    // ---- stage Q (fp32, pre-scaled) ----
    {
      const float* qb = qkv + ((size_t)(b * S_LEN + qt0 + r0)) * 2304 + (h << 6) + cc4;
      float4 qd = *(const float4*)qb;
      Qs[r0][cc4 + 0] = qd.x * 0.125f; Qs[r0][cc4 + 1] = qd.y * 0.125f;
      Qs[r0][cc4 + 2] = qd.z * 0.125f; Qs[r0][cc4 + 3] = qd.w * 0.125f;
    }
    // ---- stage K/V band (bf16, XOR-swizzled) ----
#pragma unroll
    for (int p = 0; p < 9; ++p) {
      int r = p * 32 + r0;                    // 0..287
      int key = k0 + r;
      float4 kd = {0, 0, 0, 0}, vd = {0, 0, 0, 0};
      if (key >= 0 && key < S_LEN) {
        const float* base = qkv + ((size_t)(b * S_LEN + key)) * 2304 + (h << 6) + cc4;
        kd = *(const float4*)(base + 768);
        vd = *(const float4*)(base + 1536);
      }
      int off = (r << 6) + (cc4 ^ ((r & 7) << 3));
      ushort4 k4; k4.x = f2bf(kd.x); k4.y = f2bf(kd.y); k4.z = f2bf(kd.z); k4.w = f2bf(kd.w);
      ushort4 v4; v4.x = f2bf(vd.x); v4.y = f2bf(vd.y); v4.z = f2bf(vd.z); v4.w = f2bf(vd.w);
      *(ushort4*)&Ks[off] = k4;
      *(ushort4*)&Vs[off] = v4;
    }
    __syncthreads();

    // ---- scores: lane covers j = jg + 16t, t = 0..17 ----
    float4 qreg[16];
#pragma unroll
    for (int cc = 0; cc < 16; ++cc) qreg[cc] = *(const float4*)&Qs[qi][cc << 2];
    float sreg[18];
    for (int t = 0; t < 18; ++t) {
      const int j = jg + (t << 4);
      const unsigned short* kr = &Ks[j << 6];
      const int sw = (j & 7) << 3;
      float acc = 0.0f;
#pragma unroll
      for (int cc = 0; cc < 16; ++cc) {
        ushort4 kk = *(const ushort4*)(kr + ((cc << 2) ^ sw));
        float4 q = qreg[cc];
        acc += q.x * bf2f(kk.x) + q.y * bf2f(kk.y) + q.z * bf2f(kk.z) + q.w * bf2f(kk.w);
      }
      bool valid = kvalid[j] && (j >= qi) && (j <= qi + 256);
      sreg[t] = valid ? acc : NEG_INF;
    }

    // ---- softmax over the 18*16 = 288 slots (invalid -> exp 0) ----
    float m = sreg[0];
#pragma unroll
    for (int t = 1; t < 18; ++t) m = fmaxf(m, sreg[t]);
#pragma unroll
    for (int o = 8; o; o >>= 1) m = fmaxf(m, __shfl_xor(m, o, 64));
    float z = 0.0f;
#pragma unroll
    for (int t = 0; t < 18; ++t) { sreg[t] = expf(sreg[t] - m); z += sreg[t]; }
#pragma unroll
    for (int o = 8; o; o >>= 1) z += __shfl_xor(z, o, 64);
    const float inv = 1.0f / z;
#pragma unroll
    for (int t = 0; t < 18; ++t) {
      const int j = jg + (t << 4);
      float pv = sreg[t] * inv;
      Ps[qi][j] = pv;
      Pm[qi][j] += pv;
    }
    // no barrier needed: P rows are produced and consumed within the same wave

    // ---- PV: lane owns output dims d0..d0+3 for its qi ----
    {
      const int d0 = jg << 2;
      const float* prow = Ps[qi];
      const int jlo = wave << 2;
      const int jhi = (jlo + 260 < KB) ? jlo + 260 : KB;
      float4 acc = {0, 0, 0, 0};
      for (int j = jlo; j < jhi; ++j) {
        float pv = prow[j];
        ushort4 vv = *(const ushort4*)&Vs[(j << 6) + (d0 ^ ((j & 7) << 3))];
        acc.x += pv * bf2f(vv.x); acc.y += pv * bf2f(vv.y);
        acc.z += pv * bf2f(vv.z); acc.w += pv * bf2f(vv.w);
      }
      *(float4*)&attn_out[((size_t)(b * S_LEN + qt0 + qi)) * D_MODEL + (h << 6) + d0] = acc;
    }
    __syncthreads();  // protect Ks/Vs/Qs/Ps before next head's staging
  }

  // ---- head-averaged weights -> d_out band (outside band stays memset-0) ----
  for (int idx = tid; idx < QT * 257; idx += 512) {
    int qi2 = idx / 257;
    int jj = idx - qi2 * 257;
    int j = qi2 + jj;
    int key = k0 + j;
    if ((unsigned)key < (unsigned)S_LEN)
      allw[((size_t)(b * S_LEN) + qt0 + qi2) * S_LEN + key] = Pm[qi2][j] * (1.0f / 12.0f);
  }
}

// ---------------- attention pooling + classifier head: one block per batch -------
__global__ __launch_bounds__(256) void cls_kernel(
    const float* __restrict__ X, const int* __restrict__ mask,
    const float* __restrict__ pool_w, const float* __restrict__ pool_b,
    const float* __restrict__ ln_s, const float* __restrict__ ln_b,
    const float* __restrict__ w1, const float* __restrict__ b1,
    const float* __restrict__ w2, const float* __restrict__ b2,
    float* __restrict__ out) {
  const int b = blockIdx.x;
  const int tid = threadIdx.x;
  __shared__ float scratch[4];
  __shared__ __align__(16) float sc[S_LEN];
  __shared__ __align__(16) float pbuf[D_MODEL];
  __shared__ __align__(16) float cbuf[D_MODEL];
  const float* xb = X + (size_t)b * S_LEN * D_MODEL;
  for (int d = tid; d < D_MODEL; d += 256) pbuf[d] = pool_w[d];
  __syncthreads();
  for (int s = tid; s < S_LEN; s += 256) {
    const float* xr = xb + (size_t)s * D_MODEL;
    float acc = 0.0f;
    for (int d = 0; d < D_MODEL; d += 4) {
      float4 xv = *(const float4*)(xr + d);
      float4 wv = *(const float4*)(&pbuf[d]);
      acc += xv.x * wv.x + xv.y * wv.y + xv.z * wv.z + xv.w * wv.w;
    }
    acc += pool_b[0];
    sc[s] = (mask[b * S_LEN + s] == 0) ? NEG_INF : acc;
  }
  __syncthreads();
  float m = NEG_INF;
  for (int s = tid; s < S_LEN; s += 256) m = fmaxf(m, sc[s]);
#pragma unroll
  for (int o = 32; o; o >>= 1) m = fmaxf(m, __shfl_xor(m, o, 64));
  if ((tid & 63) == 0) scratch[tid >> 6] = m;
  __syncthreads();
  m = fmaxf(fmaxf(scratch[0], scratch[1]), fmaxf(scratch[2], scratch[3]));
  __syncthreads();
  float zs = 0.0f;
  for (int s = tid; s < S_LEN; s += 256) { float e = expf(sc[s] - m); sc[s] = e; zs += e; }
#pragma unroll
  for (int o = 32; o; o >>= 1) zs += __shfl_xor(zs, o, 64);
  if ((tid & 63) == 0) scratch[tid >> 6] = zs;
  __syncthreads();
  float Z = scratch[0] + scratch[1] + scratch[2] + scratch[3];
  __syncthreads();
  const float invZ = 1.0f / Z;
  for (int s = tid; s < S_LEN; s += 256) sc[s] *= invZ;
  __syncthreads();
  for (int d = tid; d < D_MODEL; d += 256) {
    float acc = 0.0f;
    for (int s = 0; s < S_LEN; ++s) acc += sc[s] * xb[(size_t)s * D_MODEL + d];
    pbuf[d] = tanhf(acc);
  }
  __syncthreads();
  float ls = 0.0f;
  for (int d = tid; d < D_MODEL; d += 256) ls += pbuf[d];
#pragma unroll
  for (int o = 32; o; o >>= 1) ls += __shfl_xor(ls, o, 64);
  if ((tid & 63) == 0) scratch[tid >> 6] = ls;
  __syncthreads();
  float mean = (scratch[0] + scratch[1] + scratch[2] + scratch[3]) * (1.0f / 768.0f);
  __syncthreads();
  float vs = 0.0f;
  for (int d = tid; d < D_MODEL; d += 256) { float dd = pbuf[d] - mean; vs += dd * dd; }
#pragma unroll
  for (int o = 32; o; o >>= 1) vs += __shfl_xor(vs, o, 64);
  if ((tid & 63) == 0) scratch[tid >> 6] = vs;
  __syncthreads();
  float var = (scratch[0] + scratch[1] + scratch[2] + scratch[3]) * (1.0f / 768.0f);
  float rstd = rsqrtf(var + 1e-5f);
  __syncthreads();
  for (int d = tid; d < D_MODEL; d += 256)
    cbuf[d] = (pbuf[d] - mean) * rstd * ln_s[d] + ln_b[d];
  __syncthreads();
  for (int i = tid; i < D_MODEL; i += 256) {
    const float* wr = w1 + (size_t)i * D_MODEL;
    float acc = 0.0f;
    for (int d = 0; d < D_MODEL; d += 4) {
      float4 wv = *(const float4*)(wr + d);
      float4 cv = *(const float4*)(&cbuf[d]);
      acc += wv.x * cv.x + wv.y * cv.y + wv.z * cv.z + wv.w * cv.w;
    }
    sc[i] = tanhf(acc + b1[i]);
  }
  __syncthreads();
#pragma unroll
  for (int jc = 0; jc < 2; ++jc) {
    float acc = 0.0f;
    for (int i = tid; i < D_MODEL; i += 256) acc += sc[i] * w2[jc * D_MODEL + i];
#pragma unroll
    for (int o = 32; o; o >>= 1) acc += __shfl_xor(acc, o, 64);
    if ((tid & 63) == 0) scratch[tid >> 6] = acc;
    __syncthreads();
    if (tid == 0) out[b * 2 + jc] = scratch[0] + scratch[1] + scratch[2] + scratch[3] + b2[jc];
    __syncthreads();
  }
}

extern "C" void kernel_launch(void* const* d_in, const int* in_sizes, int n_in,
                              void* d_out, int out_size, void* d_ws, size_t ws_size,
                              hipStream_t stream) {
  const int*   tokens  = (const int*)d_in[0];
  const int*   mask    = (const int*)d_in[1];
  const float* emb     = (const float*)d_in[2];
  const float* in_w    = (const float*)d_in[3];
  const float* in_b    = (const float*)d_in[4];
  const float* out_w   = (const float*)d_in[5];
  const float* out_b   = (const float*)d_in[6];
  const float* ln1_s   = (const float*)d_in[7];
  const float* ln1_b   = (const float*)d_in[8];
  const float* ln2_s   = (const float*)d_in[9];
  const float* ln2_b   = (const float*)d_in[10];
  const float* ff_w1   = (const float*)d_in[11];
  const float* ff_b1   = (const float*)d_in[12];
  const float* ff_w2   = (const float*)d_in[13];
  const float* ff_b2   = (const float*)d_in[14];
  const float* pool_w  = (const float*)d_in[15];
  const float* pool_b  = (const float*)d_in[16];
  const float* cls_ln_s = (const float*)d_in[17];
  const float* cls_ln_b = (const float*)d_in[18];
  const float* cls_w1  = (const float*)d_in[19];
  const float* cls_b1  = (const float*)d_in[20];
  const float* cls_w2  = (const float*)d_in[21];
  const float* cls_b2  = (const float*)d_in[22];

  float* outp = (float*)d_out;
  float* ws = (float*)d_ws;
  const size_t XN = (size_t)8 * 1024 * 768;
  float* x   = ws;
  float* h   = ws + XN;
  float* big = ws + 2 * XN;
  float* allw = outp + 16;

  hipMemsetAsync(d_out, 0, (size_t)out_size * sizeof(float), stream);

  const int total = (int)XN;
  embed_kernel<<<(total + 255) / 256, 256, 0, stream>>>(tokens, emb, x, total);

  for (int l = 0; l < 4; ++l) {
    ln_kernel<<<8192, 256, 0, stream>>>(x, ln1_s + l * 768, ln1_b + l * 768, h);
    gemm_nt<0><<<dim3(36, 128), 256, 0, stream>>>(h, in_w + (size_t)l * 2304 * 768,
                                                  in_b + l * 2304, big, 8192, 2304, 768);
    attn_kernel<<<dim3(S_LEN / QT, 8), 512, 0, stream>>>(big, mask, h,
                                                         allw + (size_t)l * 8 * 1024 * 1024);
    gemm_nt<2><<<dim3(12, 128), 256, 0, stream>>>(h, out_w + (size_t)l * 768 * 768,
                                                  out_b + l * 768, x, 8192, 768, 768);
    ln_kernel<<<8192, 256, 0, stream>>>(x, ln2_s + l * 768, ln2_b + l * 768, h);
    gemm_nt<1><<<dim3(48, 128), 256, 0, stream>>>(h, ff_w1 + (size_t)l * 3072 * 768,
                                                  ff_b1 + l * 3072, big, 8192, 3072, 768);
    gemm_nt<2><<<dim3(12, 128), 256, 0, stream>>>(big, ff_w2 + (size_t)l * 768 * 3072,
                                                  ff_b2 + l * 768, x, 8192, 768, 3072);
  }

  cls_kernel<<<8, 256, 0, stream>>>(x, mask, pool_w, pool_b, cls_ln_s, cls_ln_b,
                                    cls_w1, cls_b1, cls_w2, cls_b2, outp);
}

// Round 3
// 3306.510 us; speedup vs baseline: 4.7316x; 2.5374x over previous
//
#include <hip/hip_runtime.h>
#include <math.h>

#define S_LEN 1024
#define D_MODEL 768
#define NHEAD 12
#define NEG_INF -3.4028234663852886e38f

#define QT 32           // queries per attention block
#define KB 288          // key band per block = QT + 2*128
#define SMS 304         // P/Pm row stride

typedef __attribute__((ext_vector_type(8))) short bf16x8;
typedef __attribute__((ext_vector_type(4))) float f32x4;

__device__ __forceinline__ float gelu_exact(float v) {
  return 0.5f * v * (1.0f + erff(v * 0.7071067811865475f));
}
__device__ __forceinline__ float bf2f(unsigned short u) {
  union { unsigned int i; float f; } x; x.i = ((unsigned int)u) << 16; return x.f;
}
__device__ __forceinline__ unsigned short f2bf(float f) {
  union { float f; unsigned int i; } x; x.f = f;
  unsigned int u = x.i;
  u += 0x7fffu + ((u >> 16) & 1u);
  return (unsigned short)(u >> 16);
}

// ---------------- embedding + sinusoidal positional encoding ----------------
__global__ __launch_bounds__(256) void embed_kernel(
    const int* __restrict__ tok, const float* __restrict__ emb,
    float* __restrict__ X, int total) {
  int i = blockIdx.x * 256 + threadIdx.x;
  if (i >= total) return;
  int d = i % D_MODEL;
  int bs = i / D_MODEL;
  int s = bs & (S_LEN - 1);
  int t = tok[bs];
  float div = expf((float)(d & ~1) * (-9.210340371976184f / 768.0f));
  float ang = (float)s * div;
  float pe = (d & 1) ? cosf(ang) : sinf(ang);
  X[i] = emb[(size_t)t * D_MODEL + d] + pe;
}

// ---------------- weight split: W -> Whi + Wlo (bf16 pair) ----------------
__global__ __launch_bounds__(256) void cvt_w(
    const float* __restrict__ W, unsigned short* __restrict__ hi,
    unsigned short* __restrict__ lo, int n4) {
  int i = blockIdx.x * 256 + threadIdx.x;
  if (i >= n4) return;
  float4 w = ((const float4*)W)[i];
  ushort4 h, l;
  h.x = f2bf(w.x); h.y = f2bf(w.y); h.z = f2bf(w.z); h.w = f2bf(w.w);
  l.x = f2bf(w.x - bf2f(h.x)); l.y = f2bf(w.y - bf2f(h.y));
  l.z = f2bf(w.z - bf2f(h.z)); l.w = f2bf(w.w - bf2f(h.w));
  ((ushort4*)hi)[i] = h;
  ((ushort4*)lo)[i] = l;
}

// ---------------- LayerNorm over D=768 -> bf16 output ----------------
__global__ __launch_bounds__(256) void ln_kernel(
    const float* __restrict__ X, const float* __restrict__ gam,
    const float* __restrict__ bet, unsigned short* __restrict__ Y) {
  __shared__ float scratch[4];
  const int row = blockIdx.x;
  const int tid = threadIdx.x;
  const float* xr = X + (size_t)row * D_MODEL;
  float v0 = xr[tid], v1 = xr[tid + 256], v2 = xr[tid + 512];
  float s = v0 + v1 + v2;
#pragma unroll
  for (int o = 32; o; o >>= 1) s += __shfl_xor(s, o, 64);
  if ((tid & 63) == 0) scratch[tid >> 6] = s;
  __syncthreads();
  float mean = (scratch[0] + scratch[1] + scratch[2] + scratch[3]) * (1.0f / 768.0f);
  __syncthreads();
  float d0 = v0 - mean, d1 = v1 - mean, d2 = v2 - mean;
  float ss = d0 * d0 + d1 * d1 + d2 * d2;
#pragma unroll
  for (int o = 32; o; o >>= 1) ss += __shfl_xor(ss, o, 64);
  if ((tid & 63) == 0) scratch[tid >> 6] = ss;
  __syncthreads();
  float var = (scratch[0] + scratch[1] + scratch[2] + scratch[3]) * (1.0f / 768.0f);
  float rstd = rsqrtf(var + 1e-5f);
  unsigned short* yr = Y + (size_t)row * D_MODEL;
  yr[tid]       = f2bf(d0 * rstd * gam[tid]       + bet[tid]);
  yr[tid + 256] = f2bf(d1 * rstd * gam[tid + 256] + bet[tid + 256]);
  yr[tid + 512] = f2bf(d2 * rstd * gam[tid + 512] + bet[tid + 512]);
}

// ---------------- MFMA GEMM: C[m,n] = sum_k A[m,k]*(Whi+Wlo)[n,k] (+bias, epi) ----
// A bf16 [M,K]; Whi/Wlo bf16 [N,K]; C fp32 (OB=0) or bf16 (OB=1).
// EPI 0: C = acc+bias   1: C = gelu(acc+bias)   2: C += acc+bias (residual, fp32)
// 128x128 tile, BK=32, 4 waves (2x2), wave tile 64x64 = 4x4 frags of 16x16x32.
template <int EPI, int OB>
__global__ __launch_bounds__(256) void gemm_mfma(
    const unsigned short* __restrict__ A, const unsigned short* __restrict__ Whi,
    const unsigned short* __restrict__ Wlo, const float* __restrict__ bias,
    void* __restrict__ Cv, int N, int K, int NX) {
  __shared__ __align__(16) unsigned short As[128 * 32];
  __shared__ __align__(16) unsigned short Hs[128 * 32];
  __shared__ __align__(16) unsigned short Ls[128 * 32];
  const int tid = threadIdx.x;
  // bijective XCD swizzle (grid sizes all % 8 == 0)
  const int nwg = gridDim.x;
  const int wg = ((blockIdx.x & 7) * (nwg >> 3)) + (blockIdx.x >> 3);
  const int ty = wg / NX, tx = wg - ty * NX;
  const int m0 = ty << 7, n0 = tx << 7;
  const int wave = tid >> 6, lane = tid & 63;
  const int wr = (wave >> 1) << 6;
  const int wc = (wave & 1) << 6;
  const int lq = lane >> 4;      // k-quarter: k = lq*8 + e
  const int lr = lane & 15;
  // staging map: thread covers (row = tid>>1, k = (tid&1)*16 .. +15)
  const int srow = tid >> 1;
  const int skh = (tid & 1) << 4;
  const size_t Abase = (size_t)(m0 + srow) * K + skh;
  const size_t Wbase = (size_t)(n0 + srow) * K + skh;
  const int sw = (srow >> 1) & 3;
  const int ss0 = skh >> 3;  // 16B-slot index (0 or 2)
  const int wi0 = srow * 32 + (((ss0 + 0) ^ sw) << 3);
  const int wi1 = srow * 32 + (((ss0 + 1) ^ sw) << 3);

  f32x4 acc[4][4] = {};
  for (int k0 = 0; k0 < K; k0 += 32) {
    uint4 a0 = *(const uint4*)(A + Abase + k0);
    uint4 a1 = *(const uint4*)(A + Abase + k0 + 8);
    uint4 h0 = *(const uint4*)(Whi + Wbase + k0);
    uint4 h1 = *(const uint4*)(Whi + Wbase + k0 + 8);
    uint4 l0 = *(const uint4*)(Wlo + Wbase + k0);
    uint4 l1 = *(const uint4*)(Wlo + Wbase + k0 + 8);
    __syncthreads();
    *(uint4*)&As[wi0] = a0; *(uint4*)&As[wi1] = a1;
    *(uint4*)&Hs[wi0] = h0; *(uint4*)&Hs[wi1] = h1;
    *(uint4*)&Ls[wi0] = l0; *(uint4*)&Ls[wi1] = l1;
    __syncthreads();
    bf16x8 af[4], bh[4], bl[4];
#pragma unroll
    for (int i = 0; i < 4; ++i) {
      int r = wr + (i << 4) + lr;
      af[i] = *(bf16x8*)&As[r * 32 + ((lq ^ ((r >> 1) & 3)) << 3)];
    }
#pragma unroll
    for (int j = 0; j < 4; ++j) {
      int r = wc + (j << 4) + lr;
      int idx = r * 32 + ((lq ^ ((r >> 1) & 3)) << 3);
      bh[j] = *(bf16x8*)&Hs[idx];
      bl[j] = *(bf16x8*)&Ls[idx];
    }
#pragma unroll
    for (int i = 0; i < 4; ++i)
#pragma unroll
      for (int j = 0; j < 4; ++j) {
        acc[i][j] = __builtin_amdgcn_mfma_f32_16x16x32_bf16(af[i], bh[j], acc[i][j], 0, 0, 0);
        acc[i][j] = __builtin_amdgcn_mfma_f32_16x16x32_bf16(af[i], bl[j], acc[i][j], 0, 0, 0);
      }
  }
  // epilogue: D frag layout col = lane&15, row = (lane>>4)*4 + reg  [m89]
#pragma unroll
  for (int j = 0; j < 4; ++j) {
    const int gcol = n0 + wc + (j << 4) + lr;
    const float bval = bias[gcol];
#pragma unroll
    for (int i = 0; i < 4; ++i) {
      const int grow0 = m0 + wr + (i << 4) + (lq << 2);
#pragma unroll
      for (int r = 0; r < 4; ++r) {
        float v = acc[i][j][r] + bval;
        size_t off = (size_t)(grow0 + r) * N + gcol;
        if (EPI == 1) v = gelu_exact(v);
        if (EPI == 2) v += ((float*)Cv)[off];
        if (OB) ((unsigned short*)Cv)[off] = f2bf(v);
        else    ((float*)Cv)[off] = v;
      }
    }
  }
}

// ---------------- banded attention, q-tiled, LDS-resident, bf16 K/V -----------------
__global__ __launch_bounds__(512) void attn_kernel(
    const float* __restrict__ qkv, const int* __restrict__ mask,
    unsigned short* __restrict__ attn_out, float* __restrict__ allw) {
  __shared__ __align__(16) unsigned short Ks[KB * 64];
  __shared__ __align__(16) unsigned short Vs[KB * 64];
  __shared__ __align__(16) float Qs[QT][68];
  __shared__ __align__(16) float Pm[QT][SMS];
  __shared__ __align__(16) float Ps[QT][SMS];
  __shared__ int kvalid[KB];

  const int qt0 = blockIdx.x * QT;
  const int b = blockIdx.y;
  const int tid = threadIdx.x;
  const int wave = tid >> 6, lane = tid & 63;
  const int qsub = lane >> 4, jg = lane & 15;
  const int qi = (wave << 2) + qsub;
  const int k0 = qt0 - 128;

  for (int idx = tid; idx < QT * SMS; idx += 512) ((float*)Pm)[idx] = 0.0f;
  for (int j = tid; j < KB; j += 512) {
    int key = k0 + j;
    kvalid[j] = (key >= 0 && key < S_LEN && mask[b * S_LEN + key] != 0) ? 1 : 0;
  }

  const int r0 = tid >> 4;
  const int cc4 = (tid & 15) << 2;

  for (int h = 0; h < NHEAD; ++h) {
    {
      const float* qb = qkv + ((size_t)(b * S_LEN + qt0 + r0)) * 2304 + (h << 6) + cc4;
      float4 qd = *(const float4*)qb;
      Qs[r0][cc4 + 0] = qd.x * 0.125f; Qs[r0][cc4 + 1] = qd.y * 0.125f;
      Qs[r0][cc4 + 2] = qd.z * 0.125f; Qs[r0][cc4 + 3] = qd.w * 0.125f;
    }
#pragma unroll
    for (int p = 0; p < 9; ++p) {
      int r = p * 32 + r0;
      int key = k0 + r;
      float4 kd = {0, 0, 0, 0}, vd = {0, 0, 0, 0};
      if (key >= 0 && key < S_LEN) {
        const float* base = qkv + ((size_t)(b * S_LEN + key)) * 2304 + (h << 6) + cc4;
        kd = *(const float4*)(base + 768);
        vd = *(const float4*)(base + 1536);
      }
      int off = (r << 6) + (cc4 ^ ((r & 7) << 3));
      ushort4 k4; k4.x = f2bf(kd.x); k4.y = f2bf(kd.y); k4.z = f2bf(kd.z); k4.w = f2bf(kd.w);
      ushort4 v4; v4.x = f2bf(vd.x); v4.y = f2bf(vd.y); v4.z = f2bf(vd.z); v4.w = f2bf(vd.w);
      *(ushort4*)&Ks[off] = k4;
      *(ushort4*)&Vs[off] = v4;
    }
    __syncthreads();

    float4 qreg[16];
#pragma unroll
    for (int cc = 0; cc < 16; ++cc) qreg[cc] = *(const float4*)&Qs[qi][cc << 2];
    float sreg[18];
    for (int t = 0; t < 18; ++t) {
      const int j = jg + (t << 4);
      const unsigned short* kr = &Ks[j << 6];
      const int sw = (j & 7) << 3;
      float acc = 0.0f;
#pragma unroll
      for (int cc = 0; cc < 16; ++cc) {
        ushort4 kk = *(const ushort4*)(kr + ((cc << 2) ^ sw));
        float4 q = qreg[cc];
        acc += q.x * bf2f(kk.x) + q.y * bf2f(kk.y) + q.z * bf2f(kk.z) + q.w * bf2f(kk.w);
      }
      bool valid = kvalid[j] && (j >= qi) && (j <= qi + 256);
      sreg[t] = valid ? acc : NEG_INF;
    }

    float m = sreg[0];
#pragma unroll
    for (int t = 1; t < 18; ++t) m = fmaxf(m, sreg[t]);
#pragma unroll
    for (int o = 8; o; o >>= 1) m = fmaxf(m, __shfl_xor(m, o, 64));
    float z = 0.0f;
#pragma unroll
    for (int t = 0; t < 18; ++t) { sreg[t] = expf(sreg[t] - m); z += sreg[t]; }
#pragma unroll
    for (int o = 8; o; o >>= 1) z += __shfl_xor(z, o, 64);
    const float inv = 1.0f / z;
#pragma unroll
    for (int t = 0; t < 18; ++t) {
      const int j = jg + (t << 4);
      float pv = sreg[t] * inv;
      Ps[qi][j] = pv;
      Pm[qi][j] += pv;
    }

    {
      const int d0 = jg << 2;
      const float* prow = Ps[qi];
      const int jlo = wave << 2;
      const int jhi = (jlo + 260 < KB) ? jlo + 260 : KB;
      float4 acc = {0, 0, 0, 0};
      for (int j = jlo; j < jhi; ++j) {
        float pv = prow[j];
        ushort4 vv = *(const ushort4*)&Vs[(j << 6) + (d0 ^ ((j & 7) << 3))];
        acc.x += pv * bf2f(vv.x); acc.y += pv * bf2f(vv.y);
        acc.z += pv * bf2f(vv.z); acc.w += pv * bf2f(vv.w);
      }
      ushort4 o4; o4.x = f2bf(acc.x); o4.y = f2bf(acc.y);
      o4.z = f2bf(acc.z); o4.w = f2bf(acc.w);
      *(ushort4*)&attn_out[((size_t)(b * S_LEN + qt0 + qi)) * D_MODEL + (h << 6) + d0] = o4;
    }
    __syncthreads();
  }

  for (int idx = tid; idx < QT * 257; idx += 512) {
    int qi2 = idx / 257;
    int jj = idx - qi2 * 257;
    int j = qi2 + jj;
    int key = k0 + j;
    if ((unsigned)key < (unsigned)S_LEN)
      allw[((size_t)(b * S_LEN) + qt0 + qi2) * S_LEN + key] = Pm[qi2][j] * (1.0f / 12.0f);
  }
}

// ---------------- attention pooling + classifier head ----------------
__global__ __launch_bounds__(256) void cls_kernel(
    const float* __restrict__ X, const int* __restrict__ mask,
    const float* __restrict__ pool_w, const float* __restrict__ pool_b,
    const float* __restrict__ ln_s, const float* __restrict__ ln_b,
    const float* __restrict__ w1, const float* __restrict__ b1,
    const float* __restrict__ w2, const float* __restrict__ b2,
    float* __restrict__ out) {
  const int b = blockIdx.x;
  const int tid = threadIdx.x;
  __shared__ float scratch[4];
  __shared__ __align__(16) float sc[S_LEN];
  __shared__ __align__(16) float pbuf[D_MODEL];
  __shared__ __align__(16) float cbuf[D_MODEL];
  const float* xb = X + (size_t)b * S_LEN * D_MODEL;
  for (int d = tid; d < D_MODEL; d += 256) pbuf[d] = pool_w[d];
  __syncthreads();
  for (int s = tid; s < S_LEN; s += 256) {
    const float* xr = xb + (size_t)s * D_MODEL;
    float acc = 0.0f;
    for (int d = 0; d < D_MODEL; d += 4) {
      float4 xv = *(const float4*)(xr + d);
      float4 wv = *(const float4*)(&pbuf[d]);
      acc += xv.x * wv.x + xv.y * wv.y + xv.z * wv.z + xv.w * wv.w;
    }
    acc += pool_b[0];
    sc[s] = (mask[b * S_LEN + s] == 0) ? NEG_INF : acc;
  }
  __syncthreads();
  float m = NEG_INF;
  for (int s = tid; s < S_LEN; s += 256) m = fmaxf(m, sc[s]);
#pragma unroll
  for (int o = 32; o; o >>= 1) m = fmaxf(m, __shfl_xor(m, o, 64));
  if ((tid & 63) == 0) scratch[tid >> 6] = m;
  __syncthreads();
  m = fmaxf(fmaxf(scratch[0], scratch[1]), fmaxf(scratch[2], scratch[3]));
  __syncthreads();
  float zs = 0.0f;
  for (int s = tid; s < S_LEN; s += 256) { float e = expf(sc[s] - m); sc[s] = e; zs += e; }
#pragma unroll
  for (int o = 32; o; o >>= 1) zs += __shfl_xor(zs, o, 64);
  if ((tid & 63) == 0) scratch[tid >> 6] = zs;
  __syncthreads();
  float Z = scratch[0] + scratch[1] + scratch[2] + scratch[3];
  __syncthreads();
  const float invZ = 1.0f / Z;
  for (int s = tid; s < S_LEN; s += 256) sc[s] *= invZ;
  __syncthreads();
  for (int d = tid; d < D_MODEL; d += 256) {
    float acc = 0.0f;
    for (int s = 0; s < S_LEN; ++s) acc += sc[s] * xb[(size_t)s * D_MODEL + d];
    pbuf[d] = tanhf(acc);
  }
  __syncthreads();
  float ls = 0.0f;
  for (int d = tid; d < D_MODEL; d += 256) ls += pbuf[d];
#pragma unroll
  for (int o = 32; o; o >>= 1) ls += __shfl_xor(ls, o, 64);
  if ((tid & 63) == 0) scratch[tid >> 6] = ls;
  __syncthreads();
  float mean = (scratch[0] + scratch[1] + scratch[2] + scratch[3]) * (1.0f / 768.0f);
  __syncthreads();
  float vs = 0.0f;
  for (int d = tid; d < D_MODEL; d += 256) { float dd = pbuf[d] - mean; vs += dd * dd; }
#pragma unroll
  for (int o = 32; o; o >>= 1) vs += __shfl_xor(vs, o, 64);
  if ((tid & 63) == 0) scratch[tid >> 6] = vs;
  __syncthreads();
  float var = (scratch[0] + scratch[1] + scratch[2] + scratch[3]) * (1.0f / 768.0f);
  float rstd = rsqrtf(var + 1e-5f);
  __syncthreads();
  for (int d = tid; d < D_MODEL; d += 256)
    cbuf[d] = (pbuf[d] - mean) * rstd * ln_s[d] + ln_b[d];
  __syncthreads();
  for (int i = tid; i < D_MODEL; i += 256) {
    const float* wr = w1 + (size_t)i * D_MODEL;
    float acc = 0.0f;
    for (int d = 0; d < D_MODEL; d += 4) {
      float4 wv = *(const float4*)(wr + d);
      float4 cv = *(const float4*)(&cbuf[d]);
      acc += wv.x * cv.x + wv.y * cv.y + wv.z * cv.z + wv.w * cv.w;
    }
    sc[i] = tanhf(acc + b1[i]);
  }
  __syncthreads();
#pragma unroll
  for (int jc = 0; jc < 2; ++jc) {
    float acc = 0.0f;
    for (int i = tid; i < D_MODEL; i += 256) acc += sc[i] * w2[jc * D_MODEL + i];
#pragma unroll
    for (int o = 32; o; o >>= 1) acc += __shfl_xor(acc, o, 64);
    if ((tid & 63) == 0) scratch[tid >> 6] = acc;
    __syncthreads();
    if (tid == 0) out[b * 2 + jc] = scratch[0] + scratch[1] + scratch[2] + scratch[3] + b2[jc];
    __syncthreads();
  }
}

extern "C" void kernel_launch(void* const* d_in, const int* in_sizes, int n_in,
                              void* d_out, int out_size, void* d_ws, size_t ws_size,
                              hipStream_t stream) {
  const int*   tokens  = (const int*)d_in[0];
  const int*   mask    = (const int*)d_in[1];
  const float* emb     = (const float*)d_in[2];
  const float* in_w    = (const float*)d_in[3];
  const float* in_b    = (const float*)d_in[4];
  const float* out_w   = (const float*)d_in[5];
  const float* out_b   = (const float*)d_in[6];
  const float* ln1_s   = (const float*)d_in[7];
  const float* ln1_b   = (const float*)d_in[8];
  const float* ln2_s   = (const float*)d_in[9];
  const float* ln2_b   = (const float*)d_in[10];
  const float* ff_w1   = (const float*)d_in[11];
  const float* ff_b1   = (const float*)d_in[12];
  const float* ff_w2   = (const float*)d_in[13];
  const float* ff_b2   = (const float*)d_in[14];
  const float* pool_w  = (const float*)d_in[15];
  const float* pool_b  = (const float*)d_in[16];
  const float* cls_ln_s = (const float*)d_in[17];
  const float* cls_ln_b = (const float*)d_in[18];
  const float* cls_w1  = (const float*)d_in[19];
  const float* cls_b1  = (const float*)d_in[20];
  const float* cls_w2  = (const float*)d_in[21];
  const float* cls_b2  = (const float*)d_in[22];

  float* outp = (float*)d_out;
  float* ws = (float*)d_ws;
  const size_t XN = (size_t)8 * 1024 * 768;        // 6,291,456
  const size_t BIGN = (size_t)8192 * 2304;         // 18,874,368
  float* x   = ws;                                  // fp32 residual stream
  float* big = ws + XN;                             // qkv fp32 (also hosts gelu bf16)
  unsigned short* h_bf = (unsigned short*)(ws + XN + BIGN);  // bf16 activations
  unsigned short* wbuf = h_bf + XN;
  unsigned short* whi = wbuf;
  unsigned short* wlo = wbuf + (size_t)3072 * 768;
  unsigned short* gelu_bf = (unsigned short*)big;
  float* allw = outp + 16;

  hipMemsetAsync(d_out, 0, (size_t)out_size * sizeof(float), stream);

  const int total = (int)XN;
  embed_kernel<<<(total + 255) / 256, 256, 0, stream>>>(tokens, emb, x, total);

  for (int l = 0; l < 4; ++l) {
    // qkv: [2304,768]
    cvt_w<<<(442368 + 255) / 256, 256, 0, stream>>>(in_w + (size_t)l * 2304 * 768, whi, wlo, 442368);
    ln_kernel<<<8192, 256, 0, stream>>>(x, ln1_s + l * 768, ln1_b + l * 768, h_bf);
    gemm_mfma<0, 0><<<1152, 256, 0, stream>>>(h_bf, whi, wlo, in_b + l * 2304, big, 2304, 768, 18);
    attn_kernel<<<dim3(S_LEN / QT, 8), 512, 0, stream>>>(big, mask, h_bf,
                                                         allw + (size_t)l * 8 * 1024 * 1024);
    // out-proj: [768,768], residual into x
    cvt_w<<<(147456 + 255) / 256, 256, 0, stream>>>(out_w + (size_t)l * 768 * 768, whi, wlo, 147456);
    gemm_mfma<2, 0><<<384, 256, 0, stream>>>(h_bf, whi, wlo, out_b + l * 768, x, 768, 768, 6);
    // ff1: [3072,768], gelu -> bf16
    ln_kernel<<<8192, 256, 0, stream>>>(x, ln2_s + l * 768, ln2_b + l * 768, h_bf);
    cvt_w<<<(589824 + 255) / 256, 256, 0, stream>>>(ff_w1 + (size_t)l * 3072 * 768, whi, wlo, 589824);
    gemm_mfma<1, 1><<<1536, 256, 0, stream>>>(h_bf, whi, wlo, ff_b1 + l * 3072, gelu_bf, 3072, 768, 24);
    // ff2: [768,3072], residual into x
    cvt_w<<<(589824 + 255) / 256, 256, 0, stream>>>(ff_w2 + (size_t)l * 768 * 3072, whi, wlo, 589824);
    gemm_mfma<2, 0><<<384, 256, 0, stream>>>(gelu_bf, whi, wlo, ff_b2 + l * 768, x, 768, 3072, 6);
  }

  cls_kernel<<<8, 256, 0, stream>>>(x, mask, pool_w, pool_b, cls_ln_s, cls_ln_b,
                                    cls_w1, cls_b1, cls_w2, cls_b2, outp);
}

// Round 5
// 2102.538 us; speedup vs baseline: 7.4410x; 1.5726x over previous
//
#include <hip/hip_runtime.h>
#include <math.h>

#define S_LEN 1024
#define D_MODEL 768
#define NHEAD 12
#define NEG_INF -3.4028234663852886e38f

#define QT 32           // queries per attention block
#define KB 288          // key band per block = QT + 2*128

typedef __attribute__((ext_vector_type(8))) short bf16x8;
typedef __attribute__((ext_vector_type(4))) float f32x4;

__device__ __forceinline__ float gelu_exact(float v) {
  return 0.5f * v * (1.0f + erff(v * 0.7071067811865475f));
}
__device__ __forceinline__ float bf2f(unsigned short u) {
  union { unsigned int i; float f; } x; x.i = ((unsigned int)u) << 16; return x.f;
}
__device__ __forceinline__ unsigned short f2bf(float f) {
  union { float f; unsigned int i; } x; x.f = f;
  unsigned int u = x.i;
  u += 0x7fffu + ((u >> 16) & 1u);
  return (unsigned short)(u >> 16);
}

// ---------------- embedding + sinusoidal positional encoding ----------------
__global__ __launch_bounds__(256) void embed_kernel(
    const int* __restrict__ tok, const float* __restrict__ emb,
    float* __restrict__ X, int total) {
  int i = blockIdx.x * 256 + threadIdx.x;
  if (i >= total) return;
  int d = i % D_MODEL;
  int bs = i / D_MODEL;
  int s = bs & (S_LEN - 1);
  int t = tok[bs];
  float div = expf((float)(d & ~1) * (-9.210340371976184f / 768.0f));
  float ang = (float)s * div;
  float pe = (d & 1) ? cosf(ang) : sinf(ang);
  X[i] = emb[(size_t)t * D_MODEL + d] + pe;
}

// ---------------- weight split: W -> Whi + Wlo (bf16 pair) ----------------
__global__ __launch_bounds__(256) void cvt_w(
    const float* __restrict__ W, unsigned short* __restrict__ hi,
    unsigned short* __restrict__ lo, int n4) {
  int i = blockIdx.x * 256 + threadIdx.x;
  if (i >= n4) return;
  float4 w = ((const float4*)W)[i];
  ushort4 h, l;
  h.x = f2bf(w.x); h.y = f2bf(w.y); h.z = f2bf(w.z); h.w = f2bf(w.w);
  l.x = f2bf(w.x - bf2f(h.x)); l.y = f2bf(w.y - bf2f(h.y));
  l.z = f2bf(w.z - bf2f(h.z)); l.w = f2bf(w.w - bf2f(h.w));
  ((ushort4*)hi)[i] = h;
  ((ushort4*)lo)[i] = l;
}

// ---------------- LayerNorm over D=768 -> bf16 output ----------------
__global__ __launch_bounds__(256) void ln_kernel(
    const float* __restrict__ X, const float* __restrict__ gam,
    const float* __restrict__ bet, unsigned short* __restrict__ Y) {
  __shared__ float scratch[4];
  const int row = blockIdx.x;
  const int tid = threadIdx.x;
  const float* xr = X + (size_t)row * D_MODEL;
  float v0 = xr[tid], v1 = xr[tid + 256], v2 = xr[tid + 512];
  float s = v0 + v1 + v2;
#pragma unroll
  for (int o = 32; o; o >>= 1) s += __shfl_xor(s, o, 64);
  if ((tid & 63) == 0) scratch[tid >> 6] = s;
  __syncthreads();
  float mean = (scratch[0] + scratch[1] + scratch[2] + scratch[3]) * (1.0f / 768.0f);
  __syncthreads();
  float d0 = v0 - mean, d1 = v1 - mean, d2 = v2 - mean;
  float ss = d0 * d0 + d1 * d1 + d2 * d2;
#pragma unroll
  for (int o = 32; o; o >>= 1) ss += __shfl_xor(ss, o, 64);
  if ((tid & 63) == 0) scratch[tid >> 6] = ss;
  __syncthreads();
  float var = (scratch[0] + scratch[1] + scratch[2] + scratch[3]) * (1.0f / 768.0f);
  float rstd = rsqrtf(var + 1e-5f);
  unsigned short* yr = Y + (size_t)row * D_MODEL;
  yr[tid]       = f2bf(d0 * rstd * gam[tid]       + bet[tid]);
  yr[tid + 256] = f2bf(d1 * rstd * gam[tid + 256] + bet[tid + 256]);
  yr[tid + 512] = f2bf(d2 * rstd * gam[tid + 512] + bet[tid + 512]);
}

// ---------------- MFMA GEMM: C[m,n] = sum_k A[m,k]*(Whi+Wlo)[n,k] (+bias, epi) ----
// EPI 0: C = acc+bias   1: C = gelu(acc+bias)   2: C += acc+bias (residual, fp32)
// OB: 0 -> fp32 out, 1 -> bf16 out
template <int EPI, int OB>
__global__ __launch_bounds__(256) void gemm_mfma(
    const unsigned short* __restrict__ A, const unsigned short* __restrict__ Whi,
    const unsigned short* __restrict__ Wlo, const float* __restrict__ bias,
    void* __restrict__ Cv, int N, int K, int NX) {
  __shared__ __align__(16) unsigned short As[128 * 32];
  __shared__ __align__(16) unsigned short Hs[128 * 32];
  __shared__ __align__(16) unsigned short Ls[128 * 32];
  const int tid = threadIdx.x;
  const int nwg = gridDim.x;
  const int wg = ((blockIdx.x & 7) * (nwg >> 3)) + (blockIdx.x >> 3);
  const int ty = wg / NX, tx = wg - ty * NX;
  const int m0 = ty << 7, n0 = tx << 7;
  const int wave = tid >> 6, lane = tid & 63;
  const int wr = (wave >> 1) << 6;
  const int wc = (wave & 1) << 6;
  const int lq = lane >> 4;
  const int lr = lane & 15;
  const int srow = tid >> 1;
  const int skh = (tid & 1) << 4;
  const size_t Abase = (size_t)(m0 + srow) * K + skh;
  const size_t Wbase = (size_t)(n0 + srow) * K + skh;
  const int sw = (srow >> 1) & 3;
  const int ss0 = skh >> 3;
  const int wi0 = srow * 32 + (((ss0 + 0) ^ sw) << 3);
  const int wi1 = srow * 32 + (((ss0 + 1) ^ sw) << 3);

  f32x4 acc[4][4] = {};
  for (int k0 = 0; k0 < K; k0 += 32) {
    uint4 a0 = *(const uint4*)(A + Abase + k0);
    uint4 a1 = *(const uint4*)(A + Abase + k0 + 8);
    uint4 h0 = *(const uint4*)(Whi + Wbase + k0);
    uint4 h1 = *(const uint4*)(Whi + Wbase + k0 + 8);
    uint4 l0 = *(const uint4*)(Wlo + Wbase + k0);
    uint4 l1 = *(const uint4*)(Wlo + Wbase + k0 + 8);
    __syncthreads();
    *(uint4*)&As[wi0] = a0; *(uint4*)&As[wi1] = a1;
    *(uint4*)&Hs[wi0] = h0; *(uint4*)&Hs[wi1] = h1;
    *(uint4*)&Ls[wi0] = l0; *(uint4*)&Ls[wi1] = l1;
    __syncthreads();
    bf16x8 af[4], bh[4], bl[4];
#pragma unroll
    for (int i = 0; i < 4; ++i) {
      int r = wr + (i << 4) + lr;
      af[i] = *(bf16x8*)&As[r * 32 + ((lq ^ ((r >> 1) & 3)) << 3)];
    }
#pragma unroll
    for (int j = 0; j < 4; ++j) {
      int r = wc + (j << 4) + lr;
      int idx = r * 32 + ((lq ^ ((r >> 1) & 3)) << 3);
      bh[j] = *(bf16x8*)&Hs[idx];
      bl[j] = *(bf16x8*)&Ls[idx];
    }
#pragma unroll
    for (int i = 0; i < 4; ++i)
#pragma unroll
      for (int j = 0; j < 4; ++j) {
        acc[i][j] = __builtin_amdgcn_mfma_f32_16x16x32_bf16(af[i], bh[j], acc[i][j], 0, 0, 0);
        acc[i][j] = __builtin_amdgcn_mfma_f32_16x16x32_bf16(af[i], bl[j], acc[i][j], 0, 0, 0);
      }
  }
#pragma unroll
  for (int j = 0; j < 4; ++j) {
    const int gcol = n0 + wc + (j << 4) + lr;
    const float bval = bias[gcol];
#pragma unroll
    for (int i = 0; i < 4; ++i) {
      const int grow0 = m0 + wr + (i << 4) + (lq << 2);
#pragma unroll
      for (int r = 0; r < 4; ++r) {
        float v = acc[i][j][r] + bval;
        size_t off = (size_t)(grow0 + r) * N + gcol;
        if (EPI == 1) v = gelu_exact(v);
        if (EPI == 2) v += ((float*)Cv)[off];
        if (OB) ((unsigned short*)Cv)[off] = f2bf(v);
        else    ((float*)Cv)[off] = v;
      }
    }
  }
}

// ---------------- banded attention: MFMA QK^T + softmax + MFMA PV -----------------
// block = (qtile 32, b), 512 thr = 8 waves, loop 12 heads. qkv is bf16 [B*S][2304].
// QK: 36 tiles (2 qhalf x 18 ktile) over 8 waves; wave w: qh=w&1, kt = wq+4t (wq=w>>1).
// PV: 8 tiles (2 qtile x 4 dtile); wave w: qt=w>>2, dt=w&3.
__global__ __launch_bounds__(512) void attn_kernel(
    const unsigned short* __restrict__ qkv, const int* __restrict__ mask,
    unsigned short* __restrict__ attn_out, float* __restrict__ allw) {
  __shared__ __align__(16) unsigned short Ks[KB * 72];     // pad 64->72, chunk-XOR
  __shared__ __align__(16) unsigned short Vt[64 * 328];    // V transposed [d][key]
  __shared__ __align__(16) unsigned short Qs[32 * 72];
  __shared__ __align__(16) unsigned short Ps[32 * 328];    // normalized P bf16
  __shared__ __align__(16) float redmax[2][16][4];         // [qh][row-in-half][wq]
  __shared__ __align__(16) float redsum[2][16][4];
  __shared__ int kvalid[KB];

  const int qt0 = blockIdx.x * QT;
  const int b = blockIdx.y;
  const int tid = threadIdx.x;
  const int w = tid >> 6, lane = tid & 63;
  const int lr = lane & 15, lg = lane >> 4;
  const int k0 = qt0 - 128;
  const int qh = w & 1, wq = w >> 1;
  const int nkt = (wq < 2) ? 5 : 4;        // k-tiles: kt = wq + 4t <= 17

  for (int j = tid; j < KB; j += 512) {
    int key = k0 + j;
    kvalid[j] = (key >= 0 && key < S_LEN && mask[b * S_LEN + key] != 0) ? 1 : 0;
  }

  f32x4 pm[5] = {};                         // head-sum of P for this wave's tiles
  const size_t rowbase = (size_t)(b * S_LEN) * 2304;
  const int qloc = lg << 2;                 // row within 16-row half (for red bufs)
  const int qbase = (qh << 4) + qloc;       // full row within 32 (for mask/Ps/allw)

  for (int h = 0; h < NHEAD; ++h) {
    const int hoff = h << 6;
    // ---- stage Q ----
    if (tid < 256) {
      int r = tid >> 3, c = tid & 7;
      uint4 v = *(const uint4*)(qkv + rowbase + (size_t)(qt0 + r) * 2304 + hoff + (c << 3));
      *(uint4*)&Qs[r * 72 + ((c ^ (r & 7)) << 3)] = v;
    }
    // ---- stage K rows + V transposed ----
    for (int idx = tid; idx < 2304; idx += 512) {
      int r = idx >> 3, c = idx & 7;
      int key = k0 + r;
      uint4 kv = {0, 0, 0, 0}, vv = {0, 0, 0, 0};
      if ((unsigned)key < (unsigned)S_LEN) {
        const unsigned short* base = qkv + rowbase + (size_t)key * 2304 + hoff + (c << 3);
        kv = *(const uint4*)(base + 768);
        vv = *(const uint4*)(base + 1536);
      }
      *(uint4*)&Ks[r * 72 + ((c ^ (r & 7)) << 3)] = kv;
      const unsigned short* ve = (const unsigned short*)&vv;
      int jc = r >> 3, jw = r & 7;
#pragma unroll
      for (int e = 0; e < 8; ++e) {
        int d = (c << 3) + e;
        Vt[d * 328 + ((jc ^ ((d >> 2) & 7)) << 3) + jw] = ve[e];
      }
    }
    __syncthreads();

    // ---- QK^T MFMAs: A=Q (row=q), B=K (row=key), k = head dim ----
    bf16x8 aq[2];
#pragma unroll
    for (int kc = 0; kc < 2; ++kc) {
      int r = (qh << 4) + lr;
      aq[kc] = *(bf16x8*)&Qs[r * 72 + ((((kc << 2) + lg) ^ (r & 7)) << 3)];
    }
    f32x4 sc[5];
#pragma unroll
    for (int t = 0; t < 5; ++t) {
      sc[t] = (f32x4){0.0f, 0.0f, 0.0f, 0.0f};
      if (t < nkt) {
        int r = ((wq + (t << 2)) << 4) + lr;
#pragma unroll
        for (int kc = 0; kc < 2; ++kc) {
          bf16x8 bk = *(bf16x8*)&Ks[r * 72 + ((((kc << 2) + lg) ^ (r & 7)) << 3)];
          sc[t] = __builtin_amdgcn_mfma_f32_16x16x32_bf16(aq[kc], bk, sc[t], 0, 0, 0);
        }
      }
    }
    // ---- scale + band/key mask (C-frag: col j = lane&15, row q = lg*4+reg) ----
#pragma unroll
    for (int t = 0; t < 5; ++t) if (t < nkt) {
      int j = ((wq + (t << 2)) << 4) + lr;
      int okk = kvalid[j];
#pragma unroll
      for (int rg = 0; rg < 4; ++rg) {
        int q = qbase + rg;
        float s = sc[t][rg] * 0.125f;
        sc[t][rg] = (okk && j >= q && j <= q + 256) ? s : NEG_INF;
      }
    }
    // ---- softmax: in-lane + shfl(1,2,4,8) + cross-wave LDS combine ----
    float mx[4], zs[4];
#pragma unroll
    for (int rg = 0; rg < 4; ++rg) {
      float m = NEG_INF;
#pragma unroll
      for (int t = 0; t < 5; ++t) if (t < nkt) m = fmaxf(m, sc[t][rg]);
      mx[rg] = m;
    }
#pragma unroll
    for (int o = 1; o < 16; o <<= 1)
#pragma unroll
      for (int rg = 0; rg < 4; ++rg) mx[rg] = fmaxf(mx[rg], __shfl_xor(mx[rg], o, 64));
    if (lr == 0)
#pragma unroll
      for (int rg = 0; rg < 4; ++rg) redmax[qh][qloc + rg][wq] = mx[rg];
    __syncthreads();
#pragma unroll
    for (int rg = 0; rg < 4; ++rg) {
      f32x4 v = *(f32x4*)&redmax[qh][qloc + rg][0];
      mx[rg] = fmaxf(fmaxf(v[0], v[1]), fmaxf(v[2], v[3]));
      zs[rg] = 0.0f;
    }
#pragma unroll
    for (int t = 0; t < 5; ++t) if (t < nkt)
#pragma unroll
      for (int rg = 0; rg < 4; ++rg) {
        float e = expf(sc[t][rg] - mx[rg]);
        sc[t][rg] = e;
        zs[rg] += e;
      }
#pragma unroll
    for (int o = 1; o < 16; o <<= 1)
#pragma unroll
      for (int rg = 0; rg < 4; ++rg) zs[rg] += __shfl_xor(zs[rg], o, 64);
    if (lr == 0)
#pragma unroll
      for (int rg = 0; rg < 4; ++rg) redsum[qh][qloc + rg][wq] = zs[rg];
    __syncthreads();
#pragma unroll
    for (int rg = 0; rg < 4; ++rg) {
      f32x4 v = *(f32x4*)&redsum[qh][qloc + rg][0];
      zs[rg] = 1.0f / (v[0] + v[1] + v[2] + v[3]);
    }
    // ---- normalize -> Ps (bf16, A-operand layout), accumulate head-mean ----
#pragma unroll
    for (int t = 0; t < 5; ++t) if (t < nkt) {
      int j = ((wq + (t << 2)) << 4) + lr;
      int pc = j >> 3, pw = j & 7;
#pragma unroll
      for (int rg = 0; rg < 4; ++rg) {
        float p = sc[t][rg] * zs[rg];
        pm[t][rg] += p;
        int row = qbase + rg;
        Ps[row * 328 + ((pc ^ (row & 7)) << 3) + pw] = f2bf(p);
      }
    }
    __syncthreads();
    // ---- PV MFMAs: A=P (row=q, k=key), B=Vt (row=d, k=key) ----
    {
      const int qt = w >> 2, dt = w & 3;
      const int ra = (qt << 4) + lr;
      const int rd = (dt << 4) + lr;
      f32x4 o4 = {0.0f, 0.0f, 0.0f, 0.0f};
#pragma unroll
      for (int ks = 0; ks < 9; ++ks) {
        bf16x8 pa = *(bf16x8*)&Ps[ra * 328 + ((((ks << 2) + lg) ^ (ra & 7)) << 3)];
        bf16x8 vb = *(bf16x8*)&Vt[rd * 328 + ((((ks << 2) + lg) ^ ((rd >> 2) & 7)) << 3)];
        o4 = __builtin_amdgcn_mfma_f32_16x16x32_bf16(pa, vb, o4, 0, 0, 0);
      }
      unsigned short* op = attn_out +
          ((size_t)(b * S_LEN + qt0 + (qt << 4) + (lg << 2))) * D_MODEL + hoff + (dt << 4) + lr;
#pragma unroll
      for (int rg = 0; rg < 4; ++rg) op[(size_t)rg * D_MODEL] = f2bf(o4[rg]);
    }
    __syncthreads();
  }

  // ---- head-averaged weights -> d_out band (outside band stays memset-0) ----
#pragma unroll
  for (int t = 0; t < 5; ++t) if (t < nkt) {
    int j = ((wq + (t << 2)) << 4) + lr;
    int key = k0 + j;
    if ((unsigned)key < (unsigned)S_LEN) {
      float* ap = allw + ((size_t)(b * S_LEN) + qt0 + qbase) * S_LEN + key;
#pragma unroll
      for (int rg = 0; rg < 4; ++rg) ap[(size_t)rg * S_LEN] = pm[t][rg] * (1.0f / 12.0f);
    }
  }
}

// ---------------- attention pooling + classifier head ----------------
__global__ __launch_bounds__(256) void cls_kernel(
    const float* __restrict__ X, const int* __restrict__ mask,
    const float* __restrict__ pool_w, const float* __restrict__ pool_b,
    const float* __restrict__ ln_s, const float* __restrict__ ln_b,
    const float* __restrict__ w1, const float* __restrict__ b1,
    const float* __restrict__ w2, const float* __restrict__ b2,
    float* __restrict__ out) {
  const int b = blockIdx.x;
  const int tid = threadIdx.x;
  __shared__ float scratch[4];
  __shared__ __align__(16) float sc[S_LEN];
  __shared__ __align__(16) float pbuf[D_MODEL];
  __shared__ __align__(16) float cbuf[D_MODEL];
  const float* xb = X + (size_t)b * S_LEN * D_MODEL;
  for (int d = tid; d < D_MODEL; d += 256) pbuf[d] = pool_w[d];
  __syncthreads();
  for (int s = tid; s < S_LEN; s += 256) {
    const float* xr = xb + (size_t)s * D_MODEL;
    float acc = 0.0f;
    for (int d = 0; d < D_MODEL; d += 4) {
      float4 xv = *(const float4*)(xr + d);
      float4 wv = *(const float4*)(&pbuf[d]);
      acc += xv.x * wv.x + xv.y * wv.y + xv.z * wv.z + xv.w * wv.w;
    }
    acc += pool_b[0];
    sc[s] = (mask[b * S_LEN + s] == 0) ? NEG_INF : acc;
  }
  __syncthreads();
  float m = NEG_INF;
  for (int s = tid; s < S_LEN; s += 256) m = fmaxf(m, sc[s]);
#pragma unroll
  for (int o = 32; o; o >>= 1) m = fmaxf(m, __shfl_xor(m, o, 64));
  if ((tid & 63) == 0) scratch[tid >> 6] = m;
  __syncthreads();
  m = fmaxf(fmaxf(scratch[0], scratch[1]), fmaxf(scratch[2], scratch[3]));
  __syncthreads();
  float zs = 0.0f;
  for (int s = tid; s < S_LEN; s += 256) { float e = expf(sc[s] - m); sc[s] = e; zs += e; }
#pragma unroll
  for (int o = 32; o; o >>= 1) zs += __shfl_xor(zs, o, 64);
  if ((tid & 63) == 0) scratch[tid >> 6] = zs;
  __syncthreads();
  float Z = scratch[0] + scratch[1] + scratch[2] + scratch[3];
  __syncthreads();
  const float invZ = 1.0f / Z;
  for (int s = tid; s < S_LEN; s += 256) sc[s] *= invZ;
  __syncthreads();
  for (int d = tid; d < D_MODEL; d += 256) {
    float acc = 0.0f;
    for (int s = 0; s < S_LEN; ++s) acc += sc[s] * xb[(size_t)s * D_MODEL + d];
    pbuf[d] = tanhf(acc);
  }
  __syncthreads();
  float ls = 0.0f;
  for (int d = tid; d < D_MODEL; d += 256) ls += pbuf[d];
#pragma unroll
  for (int o = 32; o; o >>= 1) ls += __shfl_xor(ls, o, 64);
  if ((tid & 63) == 0) scratch[tid >> 6] = ls;
  __syncthreads();
  float mean = (scratch[0] + scratch[1] + scratch[2] + scratch[3]) * (1.0f / 768.0f);
  __syncthreads();
  float vs = 0.0f;
  for (int d = tid; d < D_MODEL; d += 256) { float dd = pbuf[d] - mean; vs += dd * dd; }
#pragma unroll
  for (int o = 32; o; o >>= 1) vs += __shfl_xor(vs, o, 64);
  if ((tid & 63) == 0) scratch[tid >> 6] = vs;
  __syncthreads();
  float var = (scratch[0] + scratch[1] + scratch[2] + scratch[3]) * (1.0f / 768.0f);
  float rstd = rsqrtf(var + 1e-5f);
  __syncthreads();
  for (int d = tid; d < D_MODEL; d += 256)
    cbuf[d] = (pbuf[d] - mean) * rstd * ln_s[d] + ln_b[d];
  __syncthreads();
  for (int i = tid; i < D_MODEL; i += 256) {
    const float* wr = w1 + (size_t)i * D_MODEL;
    float acc = 0.0f;
    for (int d = 0; d < D_MODEL; d += 4) {
      float4 wv = *(const float4*)(wr + d);
      float4 cv = *(const float4*)(&cbuf[d]);
      acc += wv.x * cv.x + wv.y * cv.y + wv.z * cv.z + wv.w * cv.w;
    }
    sc[i] = tanhf(acc + b1[i]);
  }
  __syncthreads();
#pragma unroll
  for (int jc = 0; jc < 2; ++jc) {
    float acc = 0.0f;
    for (int i = tid; i < D_MODEL; i += 256) acc += sc[i] * w2[jc * D_MODEL + i];
#pragma unroll
    for (int o = 32; o; o >>= 1) acc += __shfl_xor(acc, o, 64);
    if ((tid & 63) == 0) scratch[tid >> 6] = acc;
    __syncthreads();
    if (tid == 0) out[b * 2 + jc] = scratch[0] + scratch[1] + scratch[2] + scratch[3] + b2[jc];
    __syncthreads();
  }
}

extern "C" void kernel_launch(void* const* d_in, const int* in_sizes, int n_in,
                              void* d_out, int out_size, void* d_ws, size_t ws_size,
                              hipStream_t stream) {
  const int*   tokens  = (const int*)d_in[0];
  const int*   mask    = (const int*)d_in[1];
  const float* emb     = (const float*)d_in[2];
  const float* in_w    = (const float*)d_in[3];
  const float* in_b    = (const float*)d_in[4];
  const float* out_w   = (const float*)d_in[5];
  const float* out_b   = (const float*)d_in[6];
  const float* ln1_s   = (const float*)d_in[7];
  const float* ln1_b   = (const float*)d_in[8];
  const float* ln2_s   = (const float*)d_in[9];
  const float* ln2_b   = (const float*)d_in[10];
  const float* ff_w1   = (const float*)d_in[11];
  const float* ff_b1   = (const float*)d_in[12];
  const float* ff_w2   = (const float*)d_in[13];
  const float* ff_b2   = (const float*)d_in[14];
  const float* pool_w  = (const float*)d_in[15];
  const float* pool_b  = (const float*)d_in[16];
  const float* cls_ln_s = (const float*)d_in[17];
  const float* cls_ln_b = (const float*)d_in[18];
  const float* cls_w1  = (const float*)d_in[19];
  const float* cls_b1  = (const float*)d_in[20];
  const float* cls_w2  = (const float*)d_in[21];
  const float* cls_b2  = (const float*)d_in[22];

  float* outp = (float*)d_out;
  float* ws = (float*)d_ws;
  const size_t XN = (size_t)8 * 1024 * 768;        // 6,291,456
  const size_t BIGN = (size_t)8192 * 2304;         // 18,874,368
  float* x   = ws;                                  // fp32 residual stream
  float* big = ws + XN;                             // qkv bf16 / gelu bf16 region
  unsigned short* h_bf = (unsigned short*)(ws + XN + BIGN);  // bf16 activations
  unsigned short* wbuf = h_bf + XN;
  unsigned short* whi = wbuf;
  unsigned short* wlo = wbuf + (size_t)3072 * 768;
  unsigned short* qkv_bf = (unsigned short*)big;
  unsigned short* gelu_bf = (unsigned short*)big;
  float* allw = outp + 16;

  hipMemsetAsync(d_out, 0, (size_t)out_size * sizeof(float), stream);

  const int total = (int)XN;
  embed_kernel<<<(total + 255) / 256, 256, 0, stream>>>(tokens, emb, x, total);

  for (int l = 0; l < 4; ++l) {
    // qkv: [2304,768] -> bf16 output
    cvt_w<<<(442368 + 255) / 256, 256, 0, stream>>>(in_w + (size_t)l * 2304 * 768, whi, wlo, 442368);
    ln_kernel<<<8192, 256, 0, stream>>>(x, ln1_s + l * 768, ln1_b + l * 768, h_bf);
    gemm_mfma<0, 1><<<1152, 256, 0, stream>>>(h_bf, whi, wlo, in_b + l * 2304, qkv_bf, 2304, 768, 18);
    attn_kernel<<<dim3(S_LEN / QT, 8), 512, 0, stream>>>(qkv_bf, mask, h_bf,
                                                         allw + (size_t)l * 8 * 1024 * 1024);
    // out-proj: [768,768], residual into x
    cvt_w<<<(147456 + 255) / 256, 256, 0, stream>>>(out_w + (size_t)l * 768 * 768, whi, wlo, 147456);
    gemm_mfma<2, 0><<<384, 256, 0, stream>>>(h_bf, whi, wlo, out_b + l * 768, x, 768, 768, 6);
    // ff1: [3072,768], gelu -> bf16
    ln_kernel<<<8192, 256, 0, stream>>>(x, ln2_s + l * 768, ln2_b + l * 768, h_bf);
    cvt_w<<<(589824 + 255) / 256, 256, 0, stream>>>(ff_w1 + (size_t)l * 3072 * 768, whi, wlo, 589824);
    gemm_mfma<1, 1><<<1536, 256, 0, stream>>>(h_bf, whi, wlo, ff_b1 + l * 3072, gelu_bf, 3072, 768, 24);
    // ff2: [768,3072], residual into x
    cvt_w<<<(589824 + 255) / 256, 256, 0, stream>>>(ff_w2 + (size_t)l * 768 * 3072, whi, wlo, 589824);
    gemm_mfma<2, 0><<<384, 256, 0, stream>>>(gelu_bf, whi, wlo, ff_b2 + l * 768, x, 768, 3072, 6);
  }

  cls_kernel<<<8, 256, 0, stream>>>(x, mask, pool_w, pool_b, cls_ln_s, cls_ln_b,
                                    cls_w1, cls_b1, cls_w2, cls_b2, outp);
}

// Round 7
// 1559.138 us; speedup vs baseline: 10.0344x; 1.3485x over previous
//
#include <hip/hip_runtime.h>
#include <math.h>

#define S_LEN 1024
#define D_MODEL 768
#define NHEAD 12
#define NEG_INF -3.4028234663852886e38f

#define QT 32           // queries per attention block
#define KB 288          // key band per block = QT + 2*128

typedef _Float16 f16x8 __attribute__((ext_vector_type(8)));
typedef __attribute__((ext_vector_type(4))) float f32x4;

typedef const __attribute__((address_space(1))) unsigned int ga_u32;
typedef __attribute__((address_space(3))) unsigned int ls_u32;
__device__ __forceinline__ void gload16(const void* g, void* l) {
  __builtin_amdgcn_global_load_lds((ga_u32*)g, (ls_u32*)l, 16, 0, 0);
}

__device__ __forceinline__ float gelu_exact(float v) {
  return 0.5f * v * (1.0f + erff(v * 0.7071067811865475f));
}
__device__ __forceinline__ unsigned short f2h(float f) {
  union { _Float16 h; unsigned short u; } x; x.h = (_Float16)f; return x.u;
}
__device__ __forceinline__ float h2f(unsigned short u) {
  union { unsigned short u; _Float16 h; } x; x.u = u; return (float)x.h;
}

// ---------------- embedding + sinusoidal positional encoding ----------------
__global__ __launch_bounds__(256) void embed_kernel(
    const int* __restrict__ tok, const float* __restrict__ emb,
    float* __restrict__ X, int total) {
  int i = blockIdx.x * 256 + threadIdx.x;
  if (i >= total) return;
  int d = i % D_MODEL;
  int bs = i / D_MODEL;
  int s = bs & (S_LEN - 1);
  int t = tok[bs];
  float div = expf((float)(d & ~1) * (-9.210340371976184f / 768.0f));
  float ang = (float)s * div;
  float pe = (d & 1) ? cosf(ang) : sinf(ang);
  X[i] = emb[(size_t)t * D_MODEL + d] + pe;
}

// ---------------- weight convert: fp32 -> fp16 ----------------
__global__ __launch_bounds__(256) void cvt_w_h(
    const float* __restrict__ W, unsigned short* __restrict__ H, int n4) {
  int i = blockIdx.x * 256 + threadIdx.x;
  if (i >= n4) return;
  float4 w = ((const float4*)W)[i];
  ushort4 h;
  h.x = f2h(w.x); h.y = f2h(w.y); h.z = f2h(w.z); h.w = f2h(w.w);
  ((ushort4*)H)[i] = h;
}

// ---------------- LayerNorm over D=768 -> fp16 output ----------------
__global__ __launch_bounds__(256) void ln_kernel(
    const float* __restrict__ X, const float* __restrict__ gam,
    const float* __restrict__ bet, unsigned short* __restrict__ Y) {
  __shared__ float scratch[4];
  const int row = blockIdx.x;
  const int tid = threadIdx.x;
  const float* xr = X + (size_t)row * D_MODEL;
  float v0 = xr[tid], v1 = xr[tid + 256], v2 = xr[tid + 512];
  float s = v0 + v1 + v2;
#pragma unroll
  for (int o = 32; o; o >>= 1) s += __shfl_xor(s, o, 64);
  if ((tid & 63) == 0) scratch[tid >> 6] = s;
  __syncthreads();
  float mean = (scratch[0] + scratch[1] + scratch[2] + scratch[3]) * (1.0f / 768.0f);
  __syncthreads();
  float d0 = v0 - mean, d1 = v1 - mean, d2 = v2 - mean;
  float ss = d0 * d0 + d1 * d1 + d2 * d2;
#pragma unroll
  for (int o = 32; o; o >>= 1) ss += __shfl_xor(ss, o, 64);
  if ((tid & 63) == 0) scratch[tid >> 6] = ss;
  __syncthreads();
  float var = (scratch[0] + scratch[1] + scratch[2] + scratch[3]) * (1.0f / 768.0f);
  float rstd = rsqrtf(var + 1e-5f);
  unsigned short* yr = Y + (size_t)row * D_MODEL;
  yr[tid]       = f2h(d0 * rstd * gam[tid]       + bet[tid]);
  yr[tid + 256] = f2h(d1 * rstd * gam[tid + 256] + bet[tid + 256]);
  yr[tid + 512] = f2h(d2 * rstd * gam[tid + 512] + bet[tid + 512]);
}

// ---------------- MFMA GEMM: C[m,n] = sum_k A[m,k]*W[n,k] (+bias, epilogue) ----
// A fp16 [M,K]; W fp16 [N,K]; EPI 0: +bias  1: gelu  2: residual add (fp32 C)
// OB: 0 fp32 out, 1 fp16 out. 128x128 tile, BK=32, 4 waves, global_load_lds staging.
template <int EPI, int OB>
__global__ __launch_bounds__(256) void gemm_mfma(
    const unsigned short* __restrict__ A, const unsigned short* __restrict__ W,
    const float* __restrict__ bias, void* __restrict__ Cv, int N, int K, int NX) {
  __shared__ __align__(16) unsigned short As[128 * 32];
  __shared__ __align__(16) unsigned short Bs[128 * 32];
  const int tid = threadIdx.x;
  const int nwg = gridDim.x;
  const int wg = ((blockIdx.x & 7) * (nwg >> 3)) + (blockIdx.x >> 3);
  const int ty = wg / NX, tx = wg - ty * NX;
  const int m0 = ty << 7, n0 = tx << 7;
  const int wave = tid >> 6, lane = tid & 63;
  const int wr = (wave >> 1) << 6, wc = (wave & 1) << 6;
  const int lq = lane >> 4, lr = lane & 15;
  // async staging: wave w fills rows 32w..32w+31; LDS linear, global pre-swizzled.
  const int rA0 = (wave << 5) + (lane >> 2);
  const int rA1 = rA0 + 16;
  const int sl = lane & 3;
  const size_t gA0 = (size_t)(m0 + rA0) * K + ((sl ^ ((rA0 >> 1) & 3)) << 3);
  const size_t gA1 = (size_t)(m0 + rA1) * K + ((sl ^ ((rA1 >> 1) & 3)) << 3);
  const size_t gB0 = (size_t)(n0 + rA0) * K + ((sl ^ ((rA0 >> 1) & 3)) << 3);
  const size_t gB1 = (size_t)(n0 + rA1) * K + ((sl ^ ((rA1 >> 1) & 3)) << 3);
  unsigned short* lA0 = &As[wave << 10];
  unsigned short* lA1 = &As[(wave << 10) + 512];
  unsigned short* lB0 = &Bs[wave << 10];
  unsigned short* lB1 = &Bs[(wave << 10) + 512];

  f32x4 acc[4][4] = {};
  for (int k0 = 0; k0 < K; k0 += 32) {
    __syncthreads();                    // prior iteration's LDS reads complete
    gload16(A + gA0 + k0, lA0);
    gload16(A + gA1 + k0, lA1);
    gload16(W + gB0 + k0, lB0);
    gload16(W + gB1 + k0, lB1);
    __syncthreads();                    // loads drained before reads
    f16x8 af[4], bq[4];
#pragma unroll
    for (int i = 0; i < 4; ++i) {
      int r = wr + (i << 4) + lr;
      af[i] = *(f16x8*)&As[r * 32 + ((lq ^ ((r >> 1) & 3)) << 3)];
    }
#pragma unroll
    for (int j = 0; j < 4; ++j) {
      int r = wc + (j << 4) + lr;
      bq[j] = *(f16x8*)&Bs[r * 32 + ((lq ^ ((r >> 1) & 3)) << 3)];
    }
#pragma unroll
    for (int i = 0; i < 4; ++i)
#pragma unroll
      for (int j = 0; j < 4; ++j)
        acc[i][j] = __builtin_amdgcn_mfma_f32_16x16x32_f16(af[i], bq[j], acc[i][j], 0, 0, 0);
  }
  // epilogue: D frag layout col = lane&15, row = (lane>>4)*4 + reg  [m89]
#pragma unroll
  for (int j = 0; j < 4; ++j) {
    const int gcol = n0 + wc + (j << 4) + lr;
    const float bval = bias[gcol];
#pragma unroll
    for (int i = 0; i < 4; ++i) {
      const int grow0 = m0 + wr + (i << 4) + (lq << 2);
#pragma unroll
      for (int r = 0; r < 4; ++r) {
        float v = acc[i][j][r] + bval;
        size_t off = (size_t)(grow0 + r) * N + gcol;
        if (EPI == 1) v = gelu_exact(v);
        if (EPI == 2) v += ((float*)Cv)[off];
        if (OB) ((unsigned short*)Cv)[off] = f2h(v);
        else    ((float*)Cv)[off] = v;
      }
    }
  }
}

// ---------------- banded attention: MFMA QK^T + softmax + MFMA PV (fp16) ---------
__global__ __launch_bounds__(512) void attn_kernel(
    const unsigned short* __restrict__ qkv, const int* __restrict__ mask,
    unsigned short* __restrict__ attn_out, float* __restrict__ allw) {
  __shared__ __align__(16) unsigned short Ks[KB * 72];
  __shared__ __align__(16) unsigned short Vt[64 * 328];
  __shared__ __align__(16) unsigned short Qs[32 * 72];
  __shared__ __align__(16) unsigned short Ps[32 * 328];
  __shared__ __align__(16) float redmax[2][16][4];
  __shared__ __align__(16) float redsum[2][16][4];
  __shared__ int kvalid[KB];

  const int qt0 = blockIdx.x * QT;
  const int b = blockIdx.y;
  const int tid = threadIdx.x;
  const int w = tid >> 6, lane = tid & 63;
  const int lr = lane & 15, lg = lane >> 4;
  const int k0 = qt0 - 128;
  const int qh = w & 1, wq = w >> 1;
  const int nkt = (wq < 2) ? 5 : 4;

  for (int j = tid; j < KB; j += 512) {
    int key = k0 + j;
    kvalid[j] = (key >= 0 && key < S_LEN && mask[b * S_LEN + key] != 0) ? 1 : 0;
  }

  f32x4 pm[5] = {};
  const size_t rowbase = (size_t)(b * S_LEN) * 2304;
  const int qloc = lg << 2;
  const int qbase = (qh << 4) + qloc;

  for (int h = 0; h < NHEAD; ++h) {
    const int hoff = h << 6;
    if (tid < 256) {
      int r = tid >> 3, c = tid & 7;
      uint4 v = *(const uint4*)(qkv + rowbase + (size_t)(qt0 + r) * 2304 + hoff + (c << 3));
      *(uint4*)&Qs[r * 72 + ((c ^ (r & 7)) << 3)] = v;
    }
    for (int idx = tid; idx < 2304; idx += 512) {
      int r = idx >> 3, c = idx & 7;
      int key = k0 + r;
      uint4 kv = {0, 0, 0, 0}, vv = {0, 0, 0, 0};
      if ((unsigned)key < (unsigned)S_LEN) {
        const unsigned short* base = qkv + rowbase + (size_t)key * 2304 + hoff + (c << 3);
        kv = *(const uint4*)(base + 768);
        vv = *(const uint4*)(base + 1536);
      }
      *(uint4*)&Ks[r * 72 + ((c ^ (r & 7)) << 3)] = kv;
      const unsigned short* ve = (const unsigned short*)&vv;
      int jc = r >> 3, jw = r & 7;
#pragma unroll
      for (int e = 0; e < 8; ++e) {
        int d = (c << 3) + e;
        Vt[d * 328 + ((jc ^ ((d >> 2) & 7)) << 3) + jw] = ve[e];
      }
    }
    __syncthreads();

    f16x8 aq[2];
#pragma unroll
    for (int kc = 0; kc < 2; ++kc) {
      int r = (qh << 4) + lr;
      aq[kc] = *(f16x8*)&Qs[r * 72 + ((((kc << 2) + lg) ^ (r & 7)) << 3)];
    }
    f32x4 sc[5];
#pragma unroll
    for (int t = 0; t < 5; ++t) {
      sc[t] = (f32x4){0.0f, 0.0f, 0.0f, 0.0f};
      if (t < nkt) {
        int r = ((wq + (t << 2)) << 4) + lr;
#pragma unroll
        for (int kc = 0; kc < 2; ++kc) {
          f16x8 bk = *(f16x8*)&Ks[r * 72 + ((((kc << 2) + lg) ^ (r & 7)) << 3)];
          sc[t] = __builtin_amdgcn_mfma_f32_16x16x32_f16(aq[kc], bk, sc[t], 0, 0, 0);
        }
      }
    }
#pragma unroll
    for (int t = 0; t < 5; ++t) if (t < nkt) {
      int j = ((wq + (t << 2)) << 4) + lr;
      int okk = kvalid[j];
#pragma unroll
      for (int rg = 0; rg < 4; ++rg) {
        int q = qbase + rg;
        float s = sc[t][rg] * 0.125f;
        sc[t][rg] = (okk && j >= q && j <= q + 256) ? s : NEG_INF;
      }
    }
    float mx[4], zs[4];
#pragma unroll
    for (int rg = 0; rg < 4; ++rg) {
      float m = NEG_INF;
#pragma unroll
      for (int t = 0; t < 5; ++t) if (t < nkt) m = fmaxf(m, sc[t][rg]);
      mx[rg] = m;
    }
#pragma unroll
    for (int o = 1; o < 16; o <<= 1)
#pragma unroll
      for (int rg = 0; rg < 4; ++rg) mx[rg] = fmaxf(mx[rg], __shfl_xor(mx[rg], o, 64));
    if (lr == 0)
#pragma unroll
      for (int rg = 0; rg < 4; ++rg) redmax[qh][qloc + rg][wq] = mx[rg];
    __syncthreads();
#pragma unroll
    for (int rg = 0; rg < 4; ++rg) {
      f32x4 v = *(f32x4*)&redmax[qh][qloc + rg][0];
      mx[rg] = fmaxf(fmaxf(v[0], v[1]), fmaxf(v[2], v[3]));
      zs[rg] = 0.0f;
    }
#pragma unroll
    for (int t = 0; t < 5; ++t) if (t < nkt)
#pragma unroll
      for (int rg = 0; rg < 4; ++rg) {
        float e = expf(sc[t][rg] - mx[rg]);
        sc[t][rg] = e;
        zs[rg] += e;
      }
#pragma unroll
    for (int o = 1; o < 16; o <<= 1)
#pragma unroll
      for (int rg = 0; rg < 4; ++rg) zs[rg] += __shfl_xor(zs[rg], o, 64);
    if (lr == 0)
#pragma unroll
      for (int rg = 0; rg < 4; ++rg) redsum[qh][qloc + rg][wq] = zs[rg];
    __syncthreads();
#pragma unroll
    for (int rg = 0; rg < 4; ++rg) {
      f32x4 v = *(f32x4*)&redsum[qh][qloc + rg][0];
      zs[rg] = 1.0f / (v[0] + v[1] + v[2] + v[3]);
    }
#pragma unroll
    for (int t = 0; t < 5; ++t) if (t < nkt) {
      int j = ((wq + (t << 2)) << 4) + lr;
      int pc = j >> 3, pw = j & 7;
#pragma unroll
      for (int rg = 0; rg < 4; ++rg) {
        float p = sc[t][rg] * zs[rg];
        pm[t][rg] += p;
        int row = qbase + rg;
        Ps[row * 328 + ((pc ^ (row & 7)) << 3) + pw] = f2h(p);
      }
    }
    __syncthreads();
    {
      const int qt = w >> 2, dt = w & 3;
      const int ra = (qt << 4) + lr;
      const int rd = (dt << 4) + lr;
      f32x4 o4 = {0.0f, 0.0f, 0.0f, 0.0f};
#pragma unroll
      for (int ks = 0; ks < 9; ++ks) {
        f16x8 pa = *(f16x8*)&Ps[ra * 328 + ((((ks << 2) + lg) ^ (ra & 7)) << 3)];
        f16x8 vb = *(f16x8*)&Vt[rd * 328 + ((((ks << 2) + lg) ^ ((rd >> 2) & 7)) << 3)];
        o4 = __builtin_amdgcn_mfma_f32_16x16x32_f16(pa, vb, o4, 0, 0, 0);
      }
      unsigned short* op = attn_out +
          ((size_t)(b * S_LEN + qt0 + (qt << 4) + (lg << 2))) * D_MODEL + hoff + (dt << 4) + lr;
#pragma unroll
      for (int rg = 0; rg < 4; ++rg) op[(size_t)rg * D_MODEL] = f2h(o4[rg]);
    }
    __syncthreads();
  }

#pragma unroll
  for (int t = 0; t < 5; ++t) if (t < nkt) {
    int j = ((wq + (t << 2)) << 4) + lr;
    int key = k0 + j;
    if ((unsigned)key < (unsigned)S_LEN) {
      float* ap = allw + ((size_t)(b * S_LEN) + qt0 + qbase) * S_LEN + key;
#pragma unroll
      for (int rg = 0; rg < 4; ++rg) ap[(size_t)rg * S_LEN] = pm[t][rg] * (1.0f / 12.0f);
    }
  }
}

// ---------------- pooling stage 1: scores sc[b,s] = x·pool_w + pool_b ----------
__global__ __launch_bounds__(256) void pool_score(
    const float* __restrict__ X, const int* __restrict__ mask,
    const float* __restrict__ pool_w, const float* __restrict__ pool_b,
    float* __restrict__ sc) {
  const int tid = threadIdx.x;
  const int wave = tid >> 6, lane = tid & 63;
  const int row = blockIdx.x * 4 + wave;
  const float* xr = X + (size_t)row * D_MODEL;
  float acc = 0.0f;
#pragma unroll
  for (int c = 0; c < 3; ++c) {
    int d = (lane << 2) + (c << 8);
    float4 xv = *(const float4*)(xr + d);
    float4 wv = *(const float4*)(pool_w + d);
    acc += xv.x * wv.x + xv.y * wv.y + xv.z * wv.z + xv.w * wv.w;
  }
#pragma unroll
  for (int o = 32; o; o >>= 1) acc += __shfl_xor(acc, o, 64);
  if (lane == 0)
    sc[row] = (mask[row] == 0) ? NEG_INF : (acc + pool_b[0]);
}

// ---------------- pooling stage 2: softmax over S per batch (in-place) ---------
__global__ __launch_bounds__(256) void pool_softmax(float* __restrict__ sc) {
  __shared__ float scratch[4];
  __shared__ float buf[S_LEN];
  const int b = blockIdx.x;
  const int tid = threadIdx.x;
  float* sb = sc + b * S_LEN;
  float m = NEG_INF;
  for (int s = tid; s < S_LEN; s += 256) { buf[s] = sb[s]; m = fmaxf(m, buf[s]); }
#pragma unroll
  for (int o = 32; o; o >>= 1) m = fmaxf(m, __shfl_xor(m, o, 64));
  if ((tid & 63) == 0) scratch[tid >> 6] = m;
  __syncthreads();
  m = fmaxf(fmaxf(scratch[0], scratch[1]), fmaxf(scratch[2], scratch[3]));
  __syncthreads();
  float z = 0.0f;
  for (int s = tid; s < S_LEN; s += 256) { float e = expf(buf[s] - m); buf[s] = e; z += e; }
#pragma unroll
  for (int o = 32; o; o >>= 1) z += __shfl_xor(z, o, 64);
  if ((tid & 63) == 0) scratch[tid >> 6] = z;
  __syncthreads();
  float Z = scratch[0] + scratch[1] + scratch[2] + scratch[3];
  const float inv = 1.0f / Z;
  for (int s = tid; s < S_LEN; s += 256) sb[s] = buf[s] * inv;
}

// ---------------- pooling stage 3: partial weighted sums over s-chunks ---------
__global__ __launch_bounds__(256) void pool_sum(
    const float* __restrict__ X, const float* __restrict__ wgt,
    float* __restrict__ partial) {
  const int bx = blockIdx.x;            // dchunk*8 + schunk
  const int b = blockIdx.y;
  const int dchunk = bx >> 3, schunk = bx & 7;
  const int d = (dchunk << 8) + threadIdx.x;
  const int s0 = schunk << 7;
  const float* xb = X + ((size_t)(b << 10) + s0) * D_MODEL + d;
  const float* wb = wgt + (b << 10) + s0;
  float acc = 0.0f;
  for (int s = 0; s < 128; ++s) acc += wb[s] * xb[(size_t)s * D_MODEL];
  partial[((size_t)((b << 3) + schunk)) * D_MODEL + d] = acc;
}

// ---------------- classifier finish: reduce partials, tanh, LN, MLP ------------
__global__ __launch_bounds__(256) void cls_finish(
    const float* __restrict__ partial,
    const float* __restrict__ ln_s, const float* __restrict__ ln_b,
    const float* __restrict__ w1, const float* __restrict__ b1,
    const float* __restrict__ w2, const float* __restrict__ b2,
    float* __restrict__ out) {
  const int b = blockIdx.x;
  const int tid = threadIdx.x;
  __shared__ float scratch[4];
  __shared__ __align__(16) float pbuf[D_MODEL];
  __shared__ __align__(16) float cbuf[D_MODEL];
  __shared__ __align__(16) float c1[D_MODEL];
  for (int d = tid; d < D_MODEL; d += 256) {
    float acc = 0.0f;
#pragma unroll
    for (int p = 0; p < 8; ++p) acc += partial[((size_t)((b << 3) + p)) * D_MODEL + d];
    pbuf[d] = tanhf(acc);
  }
  __syncthreads();
  float ls = 0.0f;
  for (int d = tid; d < D_MODEL; d += 256) ls += pbuf[d];
#pragma unroll
  for (int o = 32; o; o >>= 1) ls += __shfl_xor(ls, o, 64);
  if ((tid & 63) == 0) scratch[tid >> 6] = ls;
  __syncthreads();
  float mean = (scratch[0] + scratch[1] + scratch[2] + scratch[3]) * (1.0f / 768.0f);
  __syncthreads();
  float vs = 0.0f;
  for (int d = tid; d < D_MODEL; d += 256) { float dd = pbuf[d] - mean; vs += dd * dd; }
#pragma unroll
  for (int o = 32; o; o >>= 1) vs += __shfl_xor(vs, o, 64);
  if ((tid & 63) == 0) scratch[tid >> 6] = vs;
  __syncthreads();
  float var = (scratch[0] + scratch[1] + scratch[2] + scratch[3]) * (1.0f / 768.0f);
  float rstd = rsqrtf(var + 1e-5f);
  __syncthreads();
  for (int d = tid; d < D_MODEL; d += 256)
    cbuf[d] = (pbuf[d] - mean) * rstd * ln_s[d] + ln_b[d];
  __syncthreads();
  for (int i = tid; i < D_MODEL; i += 256) {
    const float* wr = w1 + (size_t)i * D_MODEL;
    float acc = 0.0f;
    for (int d = 0; d < D_MODEL; d += 4) {
      float4 wv = *(const float4*)(wr + d);
      float4 cv = *(const float4*)(&cbuf[d]);
      acc += wv.x * cv.x + wv.y * cv.y + wv.z * cv.z + wv.w * cv.w;
    }
    c1[i] = tanhf(acc + b1[i]);
  }
  __syncthreads();
#pragma unroll
  for (int jc = 0; jc < 2; ++jc) {
    float acc = 0.0f;
    for (int i = tid; i < D_MODEL; i += 256) acc += c1[i] * w2[jc * D_MODEL + i];
#pragma unroll
    for (int o = 32; o; o >>= 1) acc += __shfl_xor(acc, o, 64);
    if ((tid & 63) == 0) scratch[tid >> 6] = acc;
    __syncthreads();
    if (tid == 0) out[b * 2 + jc] = scratch[0] + scratch[1] + scratch[2] + scratch[3] + b2[jc];
    __syncthreads();
  }
}

extern "C" void kernel_launch(void* const* d_in, const int* in_sizes, int n_in,
                              void* d_out, int out_size, void* d_ws, size_t ws_size,
                              hipStream_t stream) {
  const int*   tokens  = (const int*)d_in[0];
  const int*   mask    = (const int*)d_in[1];
  const float* emb     = (const float*)d_in[2];
  const float* in_w    = (const float*)d_in[3];
  const float* in_b    = (const float*)d_in[4];
  const float* out_w   = (const float*)d_in[5];
  const float* out_b   = (const float*)d_in[6];
  const float* ln1_s   = (const float*)d_in[7];
  const float* ln1_b   = (const float*)d_in[8];
  const float* ln2_s   = (const float*)d_in[9];
  const float* ln2_b   = (const float*)d_in[10];
  const float* ff_w1   = (const float*)d_in[11];
  const float* ff_b1   = (const float*)d_in[12];
  const float* ff_w2   = (const float*)d_in[13];
  const float* ff_b2   = (const float*)d_in[14];
  const float* pool_w  = (const float*)d_in[15];
  const float* pool_b  = (const float*)d_in[16];
  const float* cls_ln_s = (const float*)d_in[17];
  const float* cls_ln_b = (const float*)d_in[18];
  const float* cls_w1  = (const float*)d_in[19];
  const float* cls_b1  = (const float*)d_in[20];
  const float* cls_w2  = (const float*)d_in[21];
  const float* cls_b2  = (const float*)d_in[22];

  float* outp = (float*)d_out;
  float* ws = (float*)d_ws;
  const size_t XN = (size_t)8 * 1024 * 768;        // 6,291,456
  const size_t BIGN = (size_t)8192 * 2304;         // 18,874,368
  float* x   = ws;                                  // fp32 residual stream
  float* big = ws + XN;                             // fp16 qkv / fp16 gelu region
  unsigned short* h_f16 = (unsigned short*)(ws + XN + BIGN);  // fp16 activations
  unsigned short* wbuf = h_f16 + XN;                // fp16 weights (3072*768 ushorts)
  float* clsbuf = (float*)(wbuf + (size_t)3072 * 768);
  float* sc_ws = clsbuf;                            // 8192 floats
  float* partial = clsbuf + 8192;                   // 8*8*768 floats
  unsigned short* qkv_h = (unsigned short*)big;
  unsigned short* gelu_h = (unsigned short*)big;
  float* allw = outp + 16;

  hipMemsetAsync(d_out, 0, (size_t)out_size * sizeof(float), stream);

  const int total = (int)XN;
  embed_kernel<<<(total + 255) / 256, 256, 0, stream>>>(tokens, emb, x, total);

  for (int l = 0; l < 4; ++l) {
    // qkv: [2304,768] -> fp16 output
    cvt_w_h<<<(442368 + 255) / 256, 256, 0, stream>>>(in_w + (size_t)l * 2304 * 768, wbuf, 442368);
    ln_kernel<<<8192, 256, 0, stream>>>(x, ln1_s + l * 768, ln1_b + l * 768, h_f16);
    gemm_mfma<0, 1><<<1152, 256, 0, stream>>>(h_f16, wbuf, in_b + l * 2304, qkv_h, 2304, 768, 18);
    attn_kernel<<<dim3(S_LEN / QT, 8), 512, 0, stream>>>(qkv_h, mask, h_f16,
                                                         allw + (size_t)l * 8 * 1024 * 1024);
    // out-proj: [768,768], residual into x
    cvt_w_h<<<(147456 + 255) / 256, 256, 0, stream>>>(out_w + (size_t)l * 768 * 768, wbuf, 147456);
    gemm_mfma<2, 0><<<384, 256, 0, stream>>>(h_f16, wbuf, out_b + l * 768, x, 768, 768, 6);
    // ff1: [3072,768], gelu -> fp16
    ln_kernel<<<8192, 256, 0, stream>>>(x, ln2_s + l * 768, ln2_b + l * 768, h_f16);
    cvt_w_h<<<(589824 + 255) / 256, 256, 0, stream>>>(ff_w1 + (size_t)l * 3072 * 768, wbuf, 589824);
    gemm_mfma<1, 1><<<1536, 256, 0, stream>>>(h_f16, wbuf, ff_b1 + l * 3072, gelu_h, 3072, 768, 24);
    // ff2: [768,3072], residual into x
    cvt_w_h<<<(589824 + 255) / 256, 256, 0, stream>>>(ff_w2 + (size_t)l * 768 * 3072, wbuf, 589824);
    gemm_mfma<2, 0><<<384, 256, 0, stream>>>(gelu_h, wbuf, ff_b2 + l * 768, x, 768, 3072, 6);
  }

  pool_score<<<2048, 256, 0, stream>>>(x, mask, pool_w, pool_b, sc_ws);
  pool_softmax<<<8, 256, 0, stream>>>(sc_ws);
  pool_sum<<<dim3(24, 8), 256, 0, stream>>>(x, sc_ws, partial);
  cls_finish<<<8, 256, 0, stream>>>(partial, cls_ln_s, cls_ln_b,
                                    cls_w1, cls_b1, cls_w2, cls_b2, outp);
}

// Round 8
// 1541.697 us; speedup vs baseline: 10.1479x; 1.0113x over previous
//
#include <hip/hip_runtime.h>
#include <math.h>

#define S_LEN 1024
#define D_MODEL 768
#define NHEAD 12
#define NEG_INF -3.4028234663852886e38f

#define QT 32           // queries per attention block
#define KB 288          // key band per block = QT + 2*128

typedef _Float16 f16x8 __attribute__((ext_vector_type(8)));
typedef __attribute__((ext_vector_type(4))) float f32x4;

typedef const __attribute__((address_space(1))) unsigned int ga_u32;
typedef __attribute__((address_space(3))) unsigned int ls_u32;
__device__ __forceinline__ void gload16(const void* g, void* l) {
  __builtin_amdgcn_global_load_lds((ga_u32*)g, (ls_u32*)l, 16, 0, 0);
}

__device__ __forceinline__ float gelu_exact(float v) {
  return 0.5f * v * (1.0f + erff(v * 0.7071067811865475f));
}
__device__ __forceinline__ unsigned short f2h(float f) {
  union { _Float16 h; unsigned short u; } x; x.h = (_Float16)f; return x.u;
}

// ---------------- embedding + sinusoidal positional encoding ----------------
__global__ __launch_bounds__(256) void embed_kernel(
    const int* __restrict__ tok, const float* __restrict__ emb,
    float* __restrict__ X, int total) {
  int i = blockIdx.x * 256 + threadIdx.x;
  if (i >= total) return;
  int d = i % D_MODEL;
  int bs = i / D_MODEL;
  int s = bs & (S_LEN - 1);
  int t = tok[bs];
  float div = expf((float)(d & ~1) * (-9.210340371976184f / 768.0f));
  float ang = (float)s * div;
  float pe = (d & 1) ? cosf(ang) : sinf(ang);
  X[i] = emb[(size_t)t * D_MODEL + d] + pe;
}

// ---------------- weight convert: fp32 -> fp16 ----------------
__global__ __launch_bounds__(256) void cvt_w_h(
    const float* __restrict__ W, unsigned short* __restrict__ H, int n4) {
  int i = blockIdx.x * 256 + threadIdx.x;
  if (i >= n4) return;
  float4 w = ((const float4*)W)[i];
  ushort4 h;
  h.x = f2h(w.x); h.y = f2h(w.y); h.z = f2h(w.z); h.w = f2h(w.w);
  ((ushort4*)H)[i] = h;
}

// ---------------- LayerNorm over D=768 -> fp16 output ----------------
__global__ __launch_bounds__(256) void ln_kernel(
    const float* __restrict__ X, const float* __restrict__ gam,
    const float* __restrict__ bet, unsigned short* __restrict__ Y) {
  __shared__ float scratch[4];
  const int row = blockIdx.x;
  const int tid = threadIdx.x;
  const float* xr = X + (size_t)row * D_MODEL;
  float v0 = xr[tid], v1 = xr[tid + 256], v2 = xr[tid + 512];
  float s = v0 + v1 + v2;
#pragma unroll
  for (int o = 32; o; o >>= 1) s += __shfl_xor(s, o, 64);
  if ((tid & 63) == 0) scratch[tid >> 6] = s;
  __syncthreads();
  float mean = (scratch[0] + scratch[1] + scratch[2] + scratch[3]) * (1.0f / 768.0f);
  __syncthreads();
  float d0 = v0 - mean, d1 = v1 - mean, d2 = v2 - mean;
  float ss = d0 * d0 + d1 * d1 + d2 * d2;
#pragma unroll
  for (int o = 32; o; o >>= 1) ss += __shfl_xor(ss, o, 64);
  if ((tid & 63) == 0) scratch[tid >> 6] = ss;
  __syncthreads();
  float var = (scratch[0] + scratch[1] + scratch[2] + scratch[3]) * (1.0f / 768.0f);
  float rstd = rsqrtf(var + 1e-5f);
  unsigned short* yr = Y + (size_t)row * D_MODEL;
  yr[tid]       = f2h(d0 * rstd * gam[tid]       + bet[tid]);
  yr[tid + 256] = f2h(d1 * rstd * gam[tid + 256] + bet[tid + 256]);
  yr[tid + 512] = f2h(d2 * rstd * gam[tid + 512] + bet[tid + 512]);
}

// ---------------- gemm128: C_f16[m,n] = A*W^T + bias (EPI1: gelu) ----------------
// 128x128 tile, BK=32, 4 waves, global_load_lds staging, LDS-repacked epilogue.
template <int EPI>
__global__ __launch_bounds__(256) void gemm128(
    const unsigned short* __restrict__ A, const unsigned short* __restrict__ W,
    const float* __restrict__ bias, unsigned short* __restrict__ C,
    int N, int K, int NX) {
  __shared__ __align__(16) unsigned short SH[8192];   // staging 16KB / repack half
  unsigned short* As = SH;
  unsigned short* Bs = SH + 4096;
  const int tid = threadIdx.x;
  const int nwg = gridDim.x;
  const int wg = ((blockIdx.x & 7) * (nwg >> 3)) + (blockIdx.x >> 3);
  const int ty = wg / NX, tx = wg - ty * NX;
  const int m0 = ty << 7, n0 = tx << 7;
  const int wave = tid >> 6, lane = tid & 63;
  const int wr = (wave >> 1) << 6, wc = (wave & 1) << 6;
  const int lq = lane >> 4, lr = lane & 15;
  const int rA0 = (wave << 5) + (lane >> 2);
  const int rA1 = rA0 + 16;
  const int sl = lane & 3;
  const size_t gA0 = (size_t)(m0 + rA0) * K + ((sl ^ ((rA0 >> 1) & 3)) << 3);
  const size_t gA1 = (size_t)(m0 + rA1) * K + ((sl ^ ((rA1 >> 1) & 3)) << 3);
  const size_t gB0 = (size_t)(n0 + rA0) * K + ((sl ^ ((rA0 >> 1) & 3)) << 3);
  const size_t gB1 = (size_t)(n0 + rA1) * K + ((sl ^ ((rA1 >> 1) & 3)) << 3);
  unsigned short* lA0 = &As[wave << 10];
  unsigned short* lA1 = &As[(wave << 10) + 512];
  unsigned short* lB0 = &Bs[wave << 10];
  unsigned short* lB1 = &Bs[(wave << 10) + 512];

  f32x4 acc[4][4] = {};
  for (int k0 = 0; k0 < K; k0 += 32) {
    __syncthreads();
    gload16(A + gA0 + k0, lA0);
    gload16(A + gA1 + k0, lA1);
    gload16(W + gB0 + k0, lB0);
    gload16(W + gB1 + k0, lB1);
    __syncthreads();
    f16x8 af[4], bq[4];
#pragma unroll
    for (int i = 0; i < 4; ++i) {
      int r = wr + (i << 4) + lr;
      af[i] = *(f16x8*)&As[r * 32 + ((lq ^ ((r >> 1) & 3)) << 3)];
    }
#pragma unroll
    for (int j = 0; j < 4; ++j) {
      int r = wc + (j << 4) + lr;
      bq[j] = *(f16x8*)&Bs[r * 32 + ((lq ^ ((r >> 1) & 3)) << 3)];
    }
#pragma unroll
    for (int i = 0; i < 4; ++i)
#pragma unroll
      for (int j = 0; j < 4; ++j)
        acc[i][j] = __builtin_amdgcn_mfma_f32_16x16x32_f16(af[i], bq[j], acc[i][j], 0, 0, 0);
  }
  // bias per j-fragment column
  float bval[4];
#pragma unroll
  for (int j = 0; j < 4; ++j) bval[j] = bias[n0 + wc + (j << 4) + lr];
  __syncthreads();   // K-loop LDS reads complete everywhere
  // repacked epilogue: two 64-row halves through LDS, 16B/lane coalesced stores
#pragma unroll
  for (int hh = 0; hh < 2; ++hh) {
    if ((wave >> 1) == hh) {
#pragma unroll
      for (int i = 0; i < 4; ++i)
#pragma unroll
        for (int j = 0; j < 4; ++j) {
          const int colb = wc + (j << 4) + lr;
#pragma unroll
          for (int r = 0; r < 4; ++r) {
            const int rowl = (i << 4) + (lq << 2) + r;
            float v = acc[i][j][r] + bval[j];
            if (EPI == 1) v = gelu_exact(v);
            const int ch = (colb >> 3) ^ (rowl & 7);
            SH[rowl * 128 + (ch << 3) + (colb & 7)] = f2h(v);
          }
        }
    }
    __syncthreads();
#pragma unroll
    for (int it = 0; it < 4; ++it) {
      const int cid = tid + (it << 8);
      const int row = cid >> 4, ch = cid & 15;
      uint4 v8 = *(uint4*)&SH[row * 128 + ((ch ^ (row & 7)) << 3)];
      *(uint4*)&C[(size_t)(m0 + (hh << 6) + row) * N + n0 + (ch << 3)] = v8;
    }
    __syncthreads();
  }
}

// ---------------- gemm64r: x_f32[m,n] += A*W^T + bias (residual) ----------------
// 64x128 tile, BK=32, 4 waves (wave tile 32x64), for N=768 GEMMs (balanced grid).
__global__ __launch_bounds__(256) void gemm64r(
    const unsigned short* __restrict__ A, const unsigned short* __restrict__ W,
    const float* __restrict__ bias, float* __restrict__ C, int N, int K, int NX) {
  __shared__ __align__(16) unsigned short As[64 * 32];
  __shared__ __align__(16) unsigned short Bs[128 * 32];
  const int tid = threadIdx.x;
  const int nwg = gridDim.x;
  const int wg = ((blockIdx.x & 7) * (nwg >> 3)) + (blockIdx.x >> 3);
  const int ty = wg / NX, tx = wg - ty * NX;
  const int m0 = ty << 6, n0 = tx << 7;
  const int wave = tid >> 6, lane = tid & 63;
  const int wr = (wave >> 1) << 5, wc = (wave & 1) << 6;
  const int lq = lane >> 4, lr = lane & 15;
  const int rA = (wave << 4) + (lane >> 2);          // 0..63
  const int rB0 = (wave << 5) + (lane >> 2);         // 0..127 (+16)
  const int rB1 = rB0 + 16;
  const int sl = lane & 3;
  const size_t gA  = (size_t)(m0 + rA) * K + ((sl ^ ((rA >> 1) & 3)) << 3);
  const size_t gB0 = (size_t)(n0 + rB0) * K + ((sl ^ ((rB0 >> 1) & 3)) << 3);
  const size_t gB1 = (size_t)(n0 + rB1) * K + ((sl ^ ((rB1 >> 1) & 3)) << 3);
  unsigned short* lA  = &As[wave << 9];
  unsigned short* lB0 = &Bs[wave << 10];
  unsigned short* lB1 = &Bs[(wave << 10) + 512];

  f32x4 acc[2][4] = {};
  for (int k0 = 0; k0 < K; k0 += 32) {
    __syncthreads();
    gload16(A + gA + k0, lA);
    gload16(W + gB0 + k0, lB0);
    gload16(W + gB1 + k0, lB1);
    __syncthreads();
    f16x8 af[2], bq[4];
#pragma unroll
    for (int i = 0; i < 2; ++i) {
      int r = wr + (i << 4) + lr;
      af[i] = *(f16x8*)&As[r * 32 + ((lq ^ ((r >> 1) & 3)) << 3)];
    }
#pragma unroll
    for (int j = 0; j < 4; ++j) {
      int r = wc + (j << 4) + lr;
      bq[j] = *(f16x8*)&Bs[r * 32 + ((lq ^ ((r >> 1) & 3)) << 3)];
    }
#pragma unroll
    for (int i = 0; i < 2; ++i)
#pragma unroll
      for (int j = 0; j < 4; ++j)
        acc[i][j] = __builtin_amdgcn_mfma_f32_16x16x32_f16(af[i], bq[j], acc[i][j], 0, 0, 0);
  }
#pragma unroll
  for (int j = 0; j < 4; ++j) {
    const int gcol = n0 + wc + (j << 4) + lr;
    const float bv = bias[gcol];
#pragma unroll
    for (int i = 0; i < 2; ++i) {
      const int grow0 = m0 + wr + (i << 4) + (lq << 2);
#pragma unroll
      for (int r = 0; r < 4; ++r) {
        size_t off = (size_t)(grow0 + r) * N + gcol;
        C[off] += acc[i][j][r] + bv;
      }
    }
  }
}

// ---------------- banded attention: MFMA QK^T + softmax + MFMA PV (fp16) ---------
__global__ __launch_bounds__(512) void attn_kernel(
    const unsigned short* __restrict__ qkv, const int* __restrict__ mask,
    unsigned short* __restrict__ attn_out, float* __restrict__ allw) {
  __shared__ __align__(16) unsigned short Ks[KB * 72];
  __shared__ __align__(16) unsigned short Vt[64 * 328];
  __shared__ __align__(16) unsigned short Qs[32 * 72];
  __shared__ __align__(16) unsigned short Ps[32 * 328];
  __shared__ __align__(16) float redmax[2][16][4];
  __shared__ __align__(16) float redsum[2][16][4];
  __shared__ int kvalid[KB];

  const int qt0 = blockIdx.x * QT;
  const int b = blockIdx.y;
  const int tid = threadIdx.x;
  const int w = tid >> 6, lane = tid & 63;
  const int lr = lane & 15, lg = lane >> 4;
  const int k0 = qt0 - 128;
  const int qh = w & 1, wq = w >> 1;
  const int nkt = (wq < 2) ? 5 : 4;

  for (int j = tid; j < KB; j += 512) {
    int key = k0 + j;
    kvalid[j] = (key >= 0 && key < S_LEN && mask[b * S_LEN + key] != 0) ? 1 : 0;
  }

  f32x4 pm[5] = {};
  const size_t rowbase = (size_t)(b * S_LEN) * 2304;
  const int qloc = lg << 2;
  const int qbase = (qh << 4) + qloc;

  for (int h = 0; h < NHEAD; ++h) {
    const int hoff = h << 6;
    if (tid < 256) {
      int r = tid >> 3, c = tid & 7;
      uint4 v = *(const uint4*)(qkv + rowbase + (size_t)(qt0 + r) * 2304 + hoff + (c << 3));
      *(uint4*)&Qs[r * 72 + ((c ^ (r & 7)) << 3)] = v;
    }
    for (int idx = tid; idx < 2304; idx += 512) {
      int r = idx >> 3, c = idx & 7;
      int key = k0 + r;
      uint4 kv = {0, 0, 0, 0}, vv = {0, 0, 0, 0};
      if ((unsigned)key < (unsigned)S_LEN) {
        const unsigned short* base = qkv + rowbase + (size_t)key * 2304 + hoff + (c << 3);
        kv = *(const uint4*)(base + 768);
        vv = *(const uint4*)(base + 1536);
      }
      *(uint4*)&Ks[r * 72 + ((c ^ (r & 7)) << 3)] = kv;
      const unsigned short* ve = (const unsigned short*)&vv;
      int jc = r >> 3, jw = r & 7;
#pragma unroll
      for (int e = 0; e < 8; ++e) {
        int d = (c << 3) + e;
        Vt[d * 328 + ((jc ^ ((d >> 2) & 7)) << 3) + jw] = ve[e];
      }
    }
    __syncthreads();

    f16x8 aq[2];
#pragma unroll
    for (int kc = 0; kc < 2; ++kc) {
      int r = (qh << 4) + lr;
      aq[kc] = *(f16x8*)&Qs[r * 72 + ((((kc << 2) + lg) ^ (r & 7)) << 3)];
    }
    f32x4 sc[5];
#pragma unroll
    for (int t = 0; t < 5; ++t) {
      sc[t] = (f32x4){0.0f, 0.0f, 0.0f, 0.0f};
      if (t < nkt) {
        int r = ((wq + (t << 2)) << 4) + lr;
#pragma unroll
        for (int kc = 0; kc < 2; ++kc) {
          f16x8 bk = *(f16x8*)&Ks[r * 72 + ((((kc << 2) + lg) ^ (r & 7)) << 3)];
          sc[t] = __builtin_amdgcn_mfma_f32_16x16x32_f16(aq[kc], bk, sc[t], 0, 0, 0);
        }
      }
    }
#pragma unroll
    for (int t = 0; t < 5; ++t) if (t < nkt) {
      int j = ((wq + (t << 2)) << 4) + lr;
      int okk = kvalid[j];
#pragma unroll
      for (int rg = 0; rg < 4; ++rg) {
        int q = qbase + rg;
        float s = sc[t][rg] * 0.125f;
        sc[t][rg] = (okk && j >= q && j <= q + 256) ? s : NEG_INF;
      }
    }
    float mx[4], zs[4];
#pragma unroll
    for (int rg = 0; rg < 4; ++rg) {
      float m = NEG_INF;
#pragma unroll
      for (int t = 0; t < 5; ++t) if (t < nkt) m = fmaxf(m, sc[t][rg]);
      mx[rg] = m;
    }
#pragma unroll
    for (int o = 1; o < 16; o <<= 1)
#pragma unroll
      for (int rg = 0; rg < 4; ++rg) mx[rg] = fmaxf(mx[rg], __shfl_xor(mx[rg], o, 64));
    if (lr == 0)
#pragma unroll
      for (int rg = 0; rg < 4; ++rg) redmax[qh][qloc + rg][wq] = mx[rg];
    __syncthreads();
#pragma unroll
    for (int rg = 0; rg < 4; ++rg) {
      f32x4 v = *(f32x4*)&redmax[qh][qloc + rg][0];
      mx[rg] = fmaxf(fmaxf(v[0], v[1]), fmaxf(v[2], v[3]));
      zs[rg] = 0.0f;
    }
#pragma unroll
    for (int t = 0; t < 5; ++t) if (t < nkt)
#pragma unroll
      for (int rg = 0; rg < 4; ++rg) {
        float e = expf(sc[t][rg] - mx[rg]);
        sc[t][rg] = e;
        zs[rg] += e;
      }
#pragma unroll
    for (int o = 1; o < 16; o <<= 1)
#pragma unroll
      for (int rg = 0; rg < 4; ++rg) zs[rg] += __shfl_xor(zs[rg], o, 64);
    if (lr == 0)
#pragma unroll
      for (int rg = 0; rg < 4; ++rg) redsum[qh][qloc + rg][wq] = zs[rg];
    __syncthreads();
#pragma unroll
    for (int rg = 0; rg < 4; ++rg) {
      f32x4 v = *(f32x4*)&redsum[qh][qloc + rg][0];
      zs[rg] = 1.0f / (v[0] + v[1] + v[2] + v[3]);
    }
#pragma unroll
    for (int t = 0; t < 5; ++t) if (t < nkt) {
      int j = ((wq + (t << 2)) << 4) + lr;
      int pc = j >> 3, pw = j & 7;
#pragma unroll
      for (int rg = 0; rg < 4; ++rg) {
        float p = sc[t][rg] * zs[rg];
        pm[t][rg] += p;
        int row = qbase + rg;
        Ps[row * 328 + ((pc ^ (row & 7)) << 3) + pw] = f2h(p);
      }
    }
    __syncthreads();
    {
      const int qt = w >> 2, dt = w & 3;
      const int ra = (qt << 4) + lr;
      const int rd = (dt << 4) + lr;
      f32x4 o4 = {0.0f, 0.0f, 0.0f, 0.0f};
#pragma unroll
      for (int ks = 0; ks < 9; ++ks) {
        f16x8 pa = *(f16x8*)&Ps[ra * 328 + ((((ks << 2) + lg) ^ (ra & 7)) << 3)];
        f16x8 vb = *(f16x8*)&Vt[rd * 328 + ((((ks << 2) + lg) ^ ((rd >> 2) & 7)) << 3)];
        o4 = __builtin_amdgcn_mfma_f32_16x16x32_f16(pa, vb, o4, 0, 0, 0);
      }
      unsigned short* op = attn_out +
          ((size_t)(b * S_LEN + qt0 + (qt << 4) + (lg << 2))) * D_MODEL + hoff + (dt << 4) + lr;
#pragma unroll
      for (int rg = 0; rg < 4; ++rg) op[(size_t)rg * D_MODEL] = f2h(o4[rg]);
    }
    __syncthreads();
  }

#pragma unroll
  for (int t = 0; t < 5; ++t) if (t < nkt) {
    int j = ((wq + (t << 2)) << 4) + lr;
    int key = k0 + j;
    if ((unsigned)key < (unsigned)S_LEN) {
      float* ap = allw + ((size_t)(b * S_LEN) + qt0 + qbase) * S_LEN + key;
#pragma unroll
      for (int rg = 0; rg < 4; ++rg) ap[(size_t)rg * S_LEN] = pm[t][rg] * (1.0f / 12.0f);
    }
  }
}

// ---------------- pooling stage 1: scores sc[b,s] = x·pool_w + pool_b ----------
__global__ __launch_bounds__(256) void pool_score(
    const float* __restrict__ X, const int* __restrict__ mask,
    const float* __restrict__ pool_w, const float* __restrict__ pool_b,
    float* __restrict__ sc) {
  const int tid = threadIdx.x;
  const int wave = tid >> 6, lane = tid & 63;
  const int row = blockIdx.x * 4 + wave;
  const float* xr = X + (size_t)row * D_MODEL;
  float acc = 0.0f;
#pragma unroll
  for (int c = 0; c < 3; ++c) {
    int d = (lane << 2) + (c << 8);
    float4 xv = *(const float4*)(xr + d);
    float4 wv = *(const float4*)(pool_w + d);
    acc += xv.x * wv.x + xv.y * wv.y + xv.z * wv.z + xv.w * wv.w;
  }
#pragma unroll
  for (int o = 32; o; o >>= 1) acc += __shfl_xor(acc, o, 64);
  if (lane == 0)
    sc[row] = (mask[row] == 0) ? NEG_INF : (acc + pool_b[0]);
}

// ---------------- pooling stage 2: softmax over S per batch (in-place) ---------
__global__ __launch_bounds__(256) void pool_softmax(float* __restrict__ sc) {
  __shared__ float scratch[4];
  __shared__ float buf[S_LEN];
  const int b = blockIdx.x;
  const int tid = threadIdx.x;
  float* sb = sc + b * S_LEN;
  float m = NEG_INF;
  for (int s = tid; s < S_LEN; s += 256) { buf[s] = sb[s]; m = fmaxf(m, buf[s]); }
#pragma unroll
  for (int o = 32; o; o >>= 1) m = fmaxf(m, __shfl_xor(m, o, 64));
  if ((tid & 63) == 0) scratch[tid >> 6] = m;
  __syncthreads();
  m = fmaxf(fmaxf(scratch[0], scratch[1]), fmaxf(scratch[2], scratch[3]));
  __syncthreads();
  float z = 0.0f;
  for (int s = tid; s < S_LEN; s += 256) { float e = expf(buf[s] - m); buf[s] = e; z += e; }
#pragma unroll
  for (int o = 32; o; o >>= 1) z += __shfl_xor(z, o, 64);
  if ((tid & 63) == 0) scratch[tid >> 6] = z;
  __syncthreads();
  float Z = scratch[0] + scratch[1] + scratch[2] + scratch[3];
  const float inv = 1.0f / Z;
  for (int s = tid; s < S_LEN; s += 256) sb[s] = buf[s] * inv;
}

// ---------------- pooling stage 3: partial weighted sums over s-chunks ---------
__global__ __launch_bounds__(256) void pool_sum(
    const float* __restrict__ X, const float* __restrict__ wgt,
    float* __restrict__ partial) {
  const int bx = blockIdx.x;            // dchunk*8 + schunk
  const int b = blockIdx.y;
  const int dchunk = bx >> 3, schunk = bx & 7;
  const int d = (dchunk << 8) + threadIdx.x;
  const int s0 = schunk << 7;
  const float* xb = X + ((size_t)(b << 10) + s0) * D_MODEL + d;
  const float* wb = wgt + (b << 10) + s0;
  float acc = 0.0f;
  for (int s = 0; s < 128; ++s) acc += wb[s] * xb[(size_t)s * D_MODEL];
  partial[((size_t)((b << 3) + schunk)) * D_MODEL + d] = acc;
}

// ---------------- classifier finish: reduce partials, tanh, LN, MLP ------------
__global__ __launch_bounds__(256) void cls_finish(
    const float* __restrict__ partial,
    const float* __restrict__ ln_s, const float* __restrict__ ln_b,
    const float* __restrict__ w1, const float* __restrict__ b1,
    const float* __restrict__ w2, const float* __restrict__ b2,
    float* __restrict__ out) {
  const int b = blockIdx.x;
  const int tid = threadIdx.x;
  __shared__ float scratch[4];
  __shared__ __align__(16) float pbuf[D_MODEL];
  __shared__ __align__(16) float cbuf[D_MODEL];
  __shared__ __align__(16) float c1[D_MODEL];
  for (int d = tid; d < D_MODEL; d += 256) {
    float acc = 0.0f;
#pragma unroll
    for (int p = 0; p < 8; ++p) acc += partial[((size_t)((b << 3) + p)) * D_MODEL + d];
    pbuf[d] = tanhf(acc);
  }
  __syncthreads();
  float ls = 0.0f;
  for (int d = tid; d < D_MODEL; d += 256) ls += pbuf[d];
#pragma unroll
  for (int o = 32; o; o >>= 1) ls += __shfl_xor(ls, o, 64);
  if ((tid & 63) == 0) scratch[tid >> 6] = ls;
  __syncthreads();
  float mean = (scratch[0] + scratch[1] + scratch[2] + scratch[3]) * (1.0f / 768.0f);
  __syncthreads();
  float vs = 0.0f;
  for (int d = tid; d < D_MODEL; d += 256) { float dd = pbuf[d] - mean; vs += dd * dd; }
#pragma unroll
  for (int o = 32; o; o >>= 1) vs += __shfl_xor(vs, o, 64);
  if ((tid & 63) == 0) scratch[tid >> 6] = vs;
  __syncthreads();
  float var = (scratch[0] + scratch[1] + scratch[2] + scratch[3]) * (1.0f / 768.0f);
  float rstd = rsqrtf(var + 1e-5f);
  __syncthreads();
  for (int d = tid; d < D_MODEL; d += 256)
    cbuf[d] = (pbuf[d] - mean) * rstd * ln_s[d] + ln_b[d];
  __syncthreads();
  for (int i = tid; i < D_MODEL; i += 256) {
    const float* wr = w1 + (size_t)i * D_MODEL;
    float acc = 0.0f;
    for (int d = 0; d < D_MODEL; d += 4) {
      float4 wv = *(const float4*)(wr + d);
      float4 cv = *(const float4*)(&cbuf[d]);
      acc += wv.x * cv.x + wv.y * cv.y + wv.z * cv.z + wv.w * cv.w;
    }
    c1[i] = tanhf(acc + b1[i]);
  }
  __syncthreads();
#pragma unroll
  for (int jc = 0; jc < 2; ++jc) {
    float acc = 0.0f;
    for (int i = tid; i < D_MODEL; i += 256) acc += c1[i] * w2[jc * D_MODEL + i];
#pragma unroll
    for (int o = 32; o; o >>= 1) acc += __shfl_xor(acc, o, 64);
    if ((tid & 63) == 0) scratch[tid >> 6] = acc;
    __syncthreads();
    if (tid == 0) out[b * 2 + jc] = scratch[0] + scratch[1] + scratch[2] + scratch[3] + b2[jc];
    __syncthreads();
  }
}

extern "C" void kernel_launch(void* const* d_in, const int* in_sizes, int n_in,
                              void* d_out, int out_size, void* d_ws, size_t ws_size,
                              hipStream_t stream) {
  const int*   tokens  = (const int*)d_in[0];
  const int*   mask    = (const int*)d_in[1];
  const float* emb     = (const float*)d_in[2];
  const float* in_w    = (const float*)d_in[3];
  const float* in_b    = (const float*)d_in[4];
  const float* out_w   = (const float*)d_in[5];
  const float* out_b   = (const float*)d_in[6];
  const float* ln1_s   = (const float*)d_in[7];
  const float* ln1_b   = (const float*)d_in[8];
  const float* ln2_s   = (const float*)d_in[9];
  const float* ln2_b   = (const float*)d_in[10];
  const float* ff_w1   = (const float*)d_in[11];
  const float* ff_b1   = (const float*)d_in[12];
  const float* ff_w2   = (const float*)d_in[13];
  const float* ff_b2   = (const float*)d_in[14];
  const float* pool_w  = (const float*)d_in[15];
  const float* pool_b  = (const float*)d_in[16];
  const float* cls_ln_s = (const float*)d_in[17];
  const float* cls_ln_b = (const float*)d_in[18];
  const float* cls_w1  = (const float*)d_in[19];
  const float* cls_b1  = (const float*)d_in[20];
  const float* cls_w2  = (const float*)d_in[21];
  const float* cls_b2  = (const float*)d_in[22];

  float* outp = (float*)d_out;
  float* ws = (float*)d_ws;
  const size_t XN = (size_t)8 * 1024 * 768;          // 6,291,456
  const size_t BIGU = (size_t)8192 * 3072;           // 25,165,824 ushorts (12,582,912 f)
  float* x = ws;
  unsigned short* bigu = (unsigned short*)(ws + XN);             // fp16 qkv / gelu
  unsigned short* h_f16 = (unsigned short*)(ws + XN + BIGU / 2); // fp16 activations
  unsigned short* wall = h_f16 + XN;                             // fp16 weight arena
  unsigned short* wall_in  = wall;                               // 4*2304*768
  unsigned short* wall_out = wall + (size_t)7077888;             // 4*768*768
  unsigned short* wall_ff1 = wall + (size_t)9437184;             // 4*3072*768
  unsigned short* wall_ff2 = wall + (size_t)18874368;            // 4*768*3072
  float* clsbuf = (float*)(wall + (size_t)28311552);
  float* sc_ws = clsbuf;                                         // 8192 floats
  float* partial = clsbuf + 8192;                                // 49152 floats
  float* allw = outp + 16;

  hipMemsetAsync(d_out, 0, (size_t)out_size * sizeof(float), stream);

  // upfront weight conversion (all layers)
  cvt_w_h<<<6912, 256, 0, stream>>>(in_w,  wall_in,  1769472);
  cvt_w_h<<<2304, 256, 0, stream>>>(out_w, wall_out,  589824);
  cvt_w_h<<<9216, 256, 0, stream>>>(ff_w1, wall_ff1, 2359296);
  cvt_w_h<<<9216, 256, 0, stream>>>(ff_w2, wall_ff2, 2359296);

  const int total = (int)XN;
  embed_kernel<<<(total + 255) / 256, 256, 0, stream>>>(tokens, emb, x, total);

  for (int l = 0; l < 4; ++l) {
    ln_kernel<<<8192, 256, 0, stream>>>(x, ln1_s + l * 768, ln1_b + l * 768, h_f16);
    gemm128<0><<<1152, 256, 0, stream>>>(h_f16, wall_in + (size_t)l * 1769472,
                                         in_b + l * 2304, bigu, 2304, 768, 18);
    attn_kernel<<<dim3(S_LEN / QT, 8), 512, 0, stream>>>(bigu, mask, h_f16,
                                                         allw + (size_t)l * 8 * 1024 * 1024);
    gemm64r<<<768, 256, 0, stream>>>(h_f16, wall_out + (size_t)l * 589824,
                                     out_b + l * 768, x, 768, 768, 6);
    ln_kernel<<<8192, 256, 0, stream>>>(x, ln2_s + l * 768, ln2_b + l * 768, h_f16);
    gemm128<1><<<1536, 256, 0, stream>>>(h_f16, wall_ff1 + (size_t)l * 2359296,
                                         ff_b1 + l * 3072, bigu, 3072, 768, 24);
    gemm64r<<<768, 256, 0, stream>>>(bigu, wall_ff2 + (size_t)l * 2359296,
                                     ff_b2 + l * 768, x, 768, 3072, 6);
  }

  pool_score<<<2048, 256, 0, stream>>>(x, mask, pool_w, pool_b, sc_ws);
  pool_softmax<<<8, 256, 0, stream>>>(sc_ws);
  pool_sum<<<dim3(24, 8), 256, 0, stream>>>(x, sc_ws, partial);
  cls_finish<<<8, 256, 0, stream>>>(partial, cls_ln_s, cls_ln_b,
                                    cls_w1, cls_b1, cls_w2, cls_b2, outp);
}

// Round 9
// 1502.997 us; speedup vs baseline: 10.4092x; 1.0257x over previous
//
#include <hip/hip_runtime.h>
#include <math.h>

#define S_LEN 1024
#define D_MODEL 768
#define NHEAD 12
#define NEG_INF -3.4028234663852886e38f

#define QT 32           // queries per attention block
#define KB 288          // key band per block = QT + 2*128

typedef _Float16 f16x8 __attribute__((ext_vector_type(8)));
typedef __attribute__((ext_vector_type(4))) float f32x4;

typedef const __attribute__((address_space(1))) unsigned int ga_u32;
typedef __attribute__((address_space(3))) unsigned int ls_u32;
__device__ __forceinline__ void gload16(const void* g, void* l) {
  __builtin_amdgcn_global_load_lds((ga_u32*)g, (ls_u32*)l, 16, 0, 0);
}

__device__ __forceinline__ float gelu_exact(float v) {
  return 0.5f * v * (1.0f + erff(v * 0.7071067811865475f));
}
__device__ __forceinline__ unsigned short f2h(float f) {
  union { _Float16 h; unsigned short u; } x; x.h = (_Float16)f; return x.u;
}

// ---------------- embedding + sinusoidal positional encoding ----------------
__global__ __launch_bounds__(256) void embed_kernel(
    const int* __restrict__ tok, const float* __restrict__ emb,
    float* __restrict__ X, int total) {
  int i = blockIdx.x * 256 + threadIdx.x;
  if (i >= total) return;
  int d = i % D_MODEL;
  int bs = i / D_MODEL;
  int s = bs & (S_LEN - 1);
  int t = tok[bs];
  float div = expf((float)(d & ~1) * (-9.210340371976184f / 768.0f));
  float ang = (float)s * div;
  float pe = (d & 1) ? cosf(ang) : sinf(ang);
  X[i] = emb[(size_t)t * D_MODEL + d] + pe;
}

// ---------------- weight convert: fp32 -> fp16 ----------------
__global__ __launch_bounds__(256) void cvt_w_h(
    const float* __restrict__ W, unsigned short* __restrict__ H, int n4) {
  int i = blockIdx.x * 256 + threadIdx.x;
  if (i >= n4) return;
  float4 w = ((const float4*)W)[i];
  ushort4 h;
  h.x = f2h(w.x); h.y = f2h(w.y); h.z = f2h(w.z); h.w = f2h(w.w);
  ((ushort4*)H)[i] = h;
}

// ---------------- LayerNorm over D=768 -> fp16 output ----------------
__global__ __launch_bounds__(256) void ln_kernel(
    const float* __restrict__ X, const float* __restrict__ gam,
    const float* __restrict__ bet, unsigned short* __restrict__ Y) {
  __shared__ float scratch[4];
  const int row = blockIdx.x;
  const int tid = threadIdx.x;
  const float* xr = X + (size_t)row * D_MODEL;
  float v0 = xr[tid], v1 = xr[tid + 256], v2 = xr[tid + 512];
  float s = v0 + v1 + v2;
#pragma unroll
  for (int o = 32; o; o >>= 1) s += __shfl_xor(s, o, 64);
  if ((tid & 63) == 0) scratch[tid >> 6] = s;
  __syncthreads();
  float mean = (scratch[0] + scratch[1] + scratch[2] + scratch[3]) * (1.0f / 768.0f);
  __syncthreads();
  float d0 = v0 - mean, d1 = v1 - mean, d2 = v2 - mean;
  float ss = d0 * d0 + d1 * d1 + d2 * d2;
#pragma unroll
  for (int o = 32; o; o >>= 1) ss += __shfl_xor(ss, o, 64);
  if ((tid & 63) == 0) scratch[tid >> 6] = ss;
  __syncthreads();
  float var = (scratch[0] + scratch[1] + scratch[2] + scratch[3]) * (1.0f / 768.0f);
  float rstd = rsqrtf(var + 1e-5f);
  unsigned short* yr = Y + (size_t)row * D_MODEL;
  yr[tid]       = f2h(d0 * rstd * gam[tid]       + bet[tid]);
  yr[tid + 256] = f2h(d1 * rstd * gam[tid + 256] + bet[tid + 256]);
  yr[tid + 512] = f2h(d2 * rstd * gam[tid + 512] + bet[tid + 512]);
}

// ---------------- gemm128: C_f16[m,n] = A*W^T + bias (EPI1: gelu) ----------------
// 128x128 tile, BK=32, 4 waves, 2-deep double-buffered global_load_lds pipeline,
// LDS-repacked coalesced epilogue.
template <int EPI>
__global__ __launch_bounds__(256) void gemm128(
    const unsigned short* __restrict__ A, const unsigned short* __restrict__ W,
    const float* __restrict__ bias, unsigned short* __restrict__ C,
    int N, int K, int NX) {
  __shared__ __align__(16) unsigned short SH[16384];  // 2 buffers x (A 8KB + B 8KB)
  const int tid = threadIdx.x;
  const int nwg = gridDim.x;
  const int wg = ((blockIdx.x & 7) * (nwg >> 3)) + (blockIdx.x >> 3);
  const int ty = wg / NX, tx = wg - ty * NX;
  const int m0 = ty << 7, n0 = tx << 7;
  const int wave = tid >> 6, lane = tid & 63;
  const int wr = (wave >> 1) << 6, wc = (wave & 1) << 6;
  const int lq = lane >> 4, lr = lane & 15;
  const int rA0 = (wave << 5) + (lane >> 2);
  const int rA1 = rA0 + 16;
  const int sl = lane & 3;
  const size_t gA0 = (size_t)(m0 + rA0) * K + ((sl ^ ((rA0 >> 1) & 3)) << 3);
  const size_t gA1 = (size_t)(m0 + rA1) * K + ((sl ^ ((rA1 >> 1) & 3)) << 3);
  const size_t gB0 = (size_t)(n0 + rA0) * K + ((sl ^ ((rA0 >> 1) & 3)) << 3);
  const size_t gB1 = (size_t)(n0 + rA1) * K + ((sl ^ ((rA1 >> 1) & 3)) << 3);
  const int lws = wave << 10;

  const int nt = K >> 5;
  // prologue: stage tile 0 into buffer 0
  {
    unsigned short* base = SH;
    gload16(A + gA0, base + lws);
    gload16(A + gA1, base + lws + 512);
    gload16(W + gB0, base + 4096 + lws);
    gload16(W + gB1, base + 4096 + lws + 512);
  }
  __syncthreads();

  f32x4 acc[4][4] = {};
  int cur = 0;
  for (int t = 0; t < nt; ++t) {
    if (t + 1 < nt) {                 // issue next tile's loads into other buffer
      const int kk = (t + 1) << 5;
      unsigned short* base = SH + ((cur ^ 1) << 13);
      gload16(A + gA0 + kk, base + lws);
      gload16(A + gA1 + kk, base + lws + 512);
      gload16(W + gB0 + kk, base + 4096 + lws);
      gload16(W + gB1 + kk, base + 4096 + lws + 512);
    }
    const unsigned short* As = SH + (cur << 13);
    const unsigned short* Bs = As + 4096;
    f16x8 af[4], bq[4];
#pragma unroll
    for (int i = 0; i < 4; ++i) {
      int r = wr + (i << 4) + lr;
      af[i] = *(const f16x8*)&As[r * 32 + ((lq ^ ((r >> 1) & 3)) << 3)];
    }
#pragma unroll
    for (int j = 0; j < 4; ++j) {
      int r = wc + (j << 4) + lr;
      bq[j] = *(const f16x8*)&Bs[r * 32 + ((lq ^ ((r >> 1) & 3)) << 3)];
    }
#pragma unroll
    for (int i = 0; i < 4; ++i)
#pragma unroll
      for (int j = 0; j < 4; ++j)
        acc[i][j] = __builtin_amdgcn_mfma_f32_16x16x32_f16(af[i], bq[j], acc[i][j], 0, 0, 0);
    if (t + 1 < nt) { __syncthreads(); cur ^= 1; }
  }
  // bias per j-fragment column
  float bval[4];
#pragma unroll
  for (int j = 0; j < 4; ++j) bval[j] = bias[n0 + wc + (j << 4) + lr];
  __syncthreads();   // all K-loop LDS reads complete everywhere
  // repacked epilogue: two 64-row halves through LDS buffer 0, 16B/lane stores
#pragma unroll
  for (int hh = 0; hh < 2; ++hh) {
    if ((wave >> 1) == hh) {
#pragma unroll
      for (int i = 0; i < 4; ++i)
#pragma unroll
        for (int j = 0; j < 4; ++j) {
          const int colb = wc + (j << 4) + lr;
#pragma unroll
          for (int r = 0; r < 4; ++r) {
            const int rowl = (i << 4) + (lq << 2) + r;
            float v = acc[i][j][r] + bval[j];
            if (EPI == 1) v = gelu_exact(v);
            const int ch = (colb >> 3) ^ (rowl & 7);
            SH[rowl * 128 + (ch << 3) + (colb & 7)] = f2h(v);
          }
        }
    }
    __syncthreads();
#pragma unroll
    for (int it = 0; it < 4; ++it) {
      const int cid = tid + (it << 8);
      const int row = cid >> 4, ch = cid & 15;
      uint4 v8 = *(uint4*)&SH[row * 128 + ((ch ^ (row & 7)) << 3)];
      *(uint4*)&C[(size_t)(m0 + (hh << 6) + row) * N + n0 + (ch << 3)] = v8;
    }
    __syncthreads();
  }
}

// ---------------- gemm64r: x_f32[m,n] += A*W^T + bias (residual) ----------------
// 64x128 tile, BK=32, 4 waves, 2-deep double-buffered pipeline.
__global__ __launch_bounds__(256) void gemm64r(
    const unsigned short* __restrict__ A, const unsigned short* __restrict__ W,
    const float* __restrict__ bias, float* __restrict__ C, int N, int K, int NX) {
  __shared__ __align__(16) unsigned short SH[12288];  // 2 x (A 4KB + B 8KB)
  const int tid = threadIdx.x;
  const int nwg = gridDim.x;
  const int wg = ((blockIdx.x & 7) * (nwg >> 3)) + (blockIdx.x >> 3);
  const int ty = wg / NX, tx = wg - ty * NX;
  const int m0 = ty << 6, n0 = tx << 7;
  const int wave = tid >> 6, lane = tid & 63;
  const int wr = (wave >> 1) << 5, wc = (wave & 1) << 6;
  const int lq = lane >> 4, lr = lane & 15;
  const int rA = (wave << 4) + (lane >> 2);          // 0..63
  const int rB0 = (wave << 5) + (lane >> 2);         // 0..127 (+16)
  const int rB1 = rB0 + 16;
  const int sl = lane & 3;
  const size_t gA  = (size_t)(m0 + rA) * K + ((sl ^ ((rA >> 1) & 3)) << 3);
  const size_t gB0 = (size_t)(n0 + rB0) * K + ((sl ^ ((rB0 >> 1) & 3)) << 3);
  const size_t gB1 = (size_t)(n0 + rB1) * K + ((sl ^ ((rB1 >> 1) & 3)) << 3);
  const int lwA = wave << 9;
  const int lwB = wave << 10;

  const int nt = K >> 5;
  {
    unsigned short* base = SH;
    gload16(A + gA, base + lwA);
    gload16(W + gB0, base + 2048 + lwB);
    gload16(W + gB1, base + 2048 + lwB + 512);
  }
  __syncthreads();

  f32x4 acc[2][4] = {};
  int cur = 0;
  for (int t = 0; t < nt; ++t) {
    if (t + 1 < nt) {
      const int kk = (t + 1) << 5;
      unsigned short* base = SH + (cur ^ 1) * 6144;
      gload16(A + gA + kk, base + lwA);
      gload16(W + gB0 + kk, base + 2048 + lwB);
      gload16(W + gB1 + kk, base + 2048 + lwB + 512);
    }
    const unsigned short* As = SH + cur * 6144;
    const unsigned short* Bs = As + 2048;
    f16x8 af[2], bq[4];
#pragma unroll
    for (int i = 0; i < 2; ++i) {
      int r = wr + (i << 4) + lr;
      af[i] = *(const f16x8*)&As[r * 32 + ((lq ^ ((r >> 1) & 3)) << 3)];
    }
#pragma unroll
    for (int j = 0; j < 4; ++j) {
      int r = wc + (j << 4) + lr;
      bq[j] = *(const f16x8*)&Bs[r * 32 + ((lq ^ ((r >> 1) & 3)) << 3)];
    }
#pragma unroll
    for (int i = 0; i < 2; ++i)
#pragma unroll
      for (int j = 0; j < 4; ++j)
        acc[i][j] = __builtin_amdgcn_mfma_f32_16x16x32_f16(af[i], bq[j], acc[i][j], 0, 0, 0);
    if (t + 1 < nt) { __syncthreads(); cur ^= 1; }
  }
#pragma unroll
  for (int j = 0; j < 4; ++j) {
    const int gcol = n0 + wc + (j << 4) + lr;
    const float bv = bias[gcol];
#pragma unroll
    for (int i = 0; i < 2; ++i) {
      const int grow0 = m0 + wr + (i << 4) + (lq << 2);
#pragma unroll
      for (int r = 0; r < 4; ++r) {
        size_t off = (size_t)(grow0 + r) * N + gcol;
        C[off] += acc[i][j][r] + bv;
      }
    }
  }
}

// ---------------- banded attention: MFMA QK^T + softmax + MFMA PV (fp16) ---------
__global__ __launch_bounds__(512) void attn_kernel(
    const unsigned short* __restrict__ qkv, const int* __restrict__ mask,
    unsigned short* __restrict__ attn_out, float* __restrict__ allw) {
  __shared__ __align__(16) unsigned short Ks[KB * 72];
  __shared__ __align__(16) unsigned short Vt[64 * 328];
  __shared__ __align__(16) unsigned short Qs[32 * 72];
  __shared__ __align__(16) unsigned short Ps[32 * 328];
  __shared__ __align__(16) float redmax[2][16][4];
  __shared__ __align__(16) float redsum[2][16][4];
  __shared__ int kvalid[KB];

  const int qt0 = blockIdx.x * QT;
  const int b = blockIdx.y;
  const int tid = threadIdx.x;
  const int w = tid >> 6, lane = tid & 63;
  const int lr = lane & 15, lg = lane >> 4;
  const int k0 = qt0 - 128;
  const int qh = w & 1, wq = w >> 1;
  const int nkt = (wq < 2) ? 5 : 4;

  for (int j = tid; j < KB; j += 512) {
    int key = k0 + j;
    kvalid[j] = (key >= 0 && key < S_LEN && mask[b * S_LEN + key] != 0) ? 1 : 0;
  }

  f32x4 pm[5] = {};
  const size_t rowbase = (size_t)(b * S_LEN) * 2304;
  const int qloc = lg << 2;
  const int qbase = (qh << 4) + qloc;

  for (int h = 0; h < NHEAD; ++h) {
    const int hoff = h << 6;
    if (tid < 256) {
      int r = tid >> 3, c = tid & 7;
      uint4 v = *(const uint4*)(qkv + rowbase + (size_t)(qt0 + r) * 2304 + hoff + (c << 3));
      *(uint4*)&Qs[r * 72 + ((c ^ (r & 7)) << 3)] = v;
    }
    for (int idx = tid; idx < 2304; idx += 512) {
      int r = idx >> 3, c = idx & 7;
      int key = k0 + r;
      uint4 kv = {0, 0, 0, 0}, vv = {0, 0, 0, 0};
      if ((unsigned)key < (unsigned)S_LEN) {
        const unsigned short* base = qkv + rowbase + (size_t)key * 2304 + hoff + (c << 3);
        kv = *(const uint4*)(base + 768);
        vv = *(const uint4*)(base + 1536);
      }
      *(uint4*)&Ks[r * 72 + ((c ^ (r & 7)) << 3)] = kv;
      const unsigned short* ve = (const unsigned short*)&vv;
      int jc = r >> 3, jw = r & 7;
#pragma unroll
      for (int e = 0; e < 8; ++e) {
        int d = (c << 3) + e;
        Vt[d * 328 + ((jc ^ ((d >> 2) & 7)) << 3) + jw] = ve[e];
      }
    }
    __syncthreads();

    f16x8 aq[2];
#pragma unroll
    for (int kc = 0; kc < 2; ++kc) {
      int r = (qh << 4) + lr;
      aq[kc] = *(f16x8*)&Qs[r * 72 + ((((kc << 2) + lg) ^ (r & 7)) << 3)];
    }
    f32x4 sc[5];
#pragma unroll
    for (int t = 0; t < 5; ++t) {
      sc[t] = (f32x4){0.0f, 0.0f, 0.0f, 0.0f};
      if (t < nkt) {
        int r = ((wq + (t << 2)) << 4) + lr;
#pragma unroll
        for (int kc = 0; kc < 2; ++kc) {
          f16x8 bk = *(f16x8*)&Ks[r * 72 + ((((kc << 2) + lg) ^ (r & 7)) << 3)];
          sc[t] = __builtin_amdgcn_mfma_f32_16x16x32_f16(aq[kc], bk, sc[t], 0, 0, 0);
        }
      }
    }
#pragma unroll
    for (int t = 0; t < 5; ++t) if (t < nkt) {
      int j = ((wq + (t << 2)) << 4) + lr;
      int okk = kvalid[j];
#pragma unroll
      for (int rg = 0; rg < 4; ++rg) {
        int q = qbase + rg;
        float s = sc[t][rg] * 0.125f;
        sc[t][rg] = (okk && j >= q && j <= q + 256) ? s : NEG_INF;
      }
    }
    float mx[4], zs[4];
#pragma unroll
    for (int rg = 0; rg < 4; ++rg) {
      float m = NEG_INF;
#pragma unroll
      for (int t = 0; t < 5; ++t) if (t < nkt) m = fmaxf(m, sc[t][rg]);
      mx[rg] = m;
    }
#pragma unroll
    for (int o = 1; o < 16; o <<= 1)
#pragma unroll
      for (int rg = 0; rg < 4; ++rg) mx[rg] = fmaxf(mx[rg], __shfl_xor(mx[rg], o, 64));
    if (lr == 0)
#pragma unroll
      for (int rg = 0; rg < 4; ++rg) redmax[qh][qloc + rg][wq] = mx[rg];
    __syncthreads();
#pragma unroll
    for (int rg = 0; rg < 4; ++rg) {
      f32x4 v = *(f32x4*)&redmax[qh][qloc + rg][0];
      mx[rg] = fmaxf(fmaxf(v[0], v[1]), fmaxf(v[2], v[3]));
      zs[rg] = 0.0f;
    }
#pragma unroll
    for (int t = 0; t < 5; ++t) if (t < nkt)
#pragma unroll
      for (int rg = 0; rg < 4; ++rg) {
        float e = expf(sc[t][rg] - mx[rg]);
        sc[t][rg] = e;
        zs[rg] += e;
      }
#pragma unroll
    for (int o = 1; o < 16; o <<= 1)
#pragma unroll
      for (int rg = 0; rg < 4; ++rg) zs[rg] += __shfl_xor(zs[rg], o, 64);
    if (lr == 0)
#pragma unroll
      for (int rg = 0; rg < 4; ++rg) redsum[qh][qloc + rg][wq] = zs[rg];
    __syncthreads();
#pragma unroll
    for (int rg = 0; rg < 4; ++rg) {
      f32x4 v = *(f32x4*)&redsum[qh][qloc + rg][0];
      zs[rg] = 1.0f / (v[0] + v[1] + v[2] + v[3]);
    }
#pragma unroll
    for (int t = 0; t < 5; ++t) if (t < nkt) {
      int j = ((wq + (t << 2)) << 4) + lr;
      int pc = j >> 3, pw = j & 7;
#pragma unroll
      for (int rg = 0; rg < 4; ++rg) {
        float p = sc[t][rg] * zs[rg];
        pm[t][rg] += p;
        int row = qbase + rg;
        Ps[row * 328 + ((pc ^ (row & 7)) << 3) + pw] = f2h(p);
      }
    }
    __syncthreads();
    {
      const int qt = w >> 2, dt = w & 3;
      const int ra = (qt << 4) + lr;
      const int rd = (dt << 4) + lr;
      f32x4 o4 = {0.0f, 0.0f, 0.0f, 0.0f};
#pragma unroll
      for (int ks = 0; ks < 9; ++ks) {
        f16x8 pa = *(f16x8*)&Ps[ra * 328 + ((((ks << 2) + lg) ^ (ra & 7)) << 3)];
        f16x8 vb = *(f16x8*)&Vt[rd * 328 + ((((ks << 2) + lg) ^ ((rd >> 2) & 7)) << 3)];
        o4 = __builtin_amdgcn_mfma_f32_16x16x32_f16(pa, vb, o4, 0, 0, 0);
      }
      unsigned short* op = attn_out +
          ((size_t)(b * S_LEN + qt0 + (qt << 4) + (lg << 2))) * D_MODEL + hoff + (dt << 4) + lr;
#pragma unroll
      for (int rg = 0; rg < 4; ++rg) op[(size_t)rg * D_MODEL] = f2h(o4[rg]);
    }
    __syncthreads();
  }

#pragma unroll
  for (int t = 0; t < 5; ++t) if (t < nkt) {
    int j = ((wq + (t << 2)) << 4) + lr;
    int key = k0 + j;
    if ((unsigned)key < (unsigned)S_LEN) {
      float* ap = allw + ((size_t)(b * S_LEN) + qt0 + qbase) * S_LEN + key;
#pragma unroll
      for (int rg = 0; rg < 4; ++rg) ap[(size_t)rg * S_LEN] = pm[t][rg] * (1.0f / 12.0f);
    }
  }
}

// ---------------- pooling stage 1: scores sc[b,s] = x·pool_w + pool_b ----------
__global__ __launch_bounds__(256) void pool_score(
    const float* __restrict__ X, const int* __restrict__ mask,
    const float* __restrict__ pool_w, const float* __restrict__ pool_b,
    float* __restrict__ sc) {
  const int tid = threadIdx.x;
  const int wave = tid >> 6, lane = tid & 63;
  const int row = blockIdx.x * 4 + wave;
  const float* xr = X + (size_t)row * D_MODEL;
  float acc = 0.0f;
#pragma unroll
  for (int c = 0; c < 3; ++c) {
    int d = (lane << 2) + (c << 8);
    float4 xv = *(const float4*)(xr + d);
    float4 wv = *(const float4*)(pool_w + d);
    acc += xv.x * wv.x + xv.y * wv.y + xv.z * wv.z + xv.w * wv.w;
  }
#pragma unroll
  for (int o = 32; o; o >>= 1) acc += __shfl_xor(acc, o, 64);
  if (lane == 0)
    sc[row] = (mask[row] == 0) ? NEG_INF : (acc + pool_b[0]);
}

// ---------------- pooling stage 2: softmax over S per batch (in-place) ---------
__global__ __launch_bounds__(256) void pool_softmax(float* __restrict__ sc) {
  __shared__ float scratch[4];
  __shared__ float buf[S_LEN];
  const int b = blockIdx.x;
  const int tid = threadIdx.x;
  float* sb = sc + b * S_LEN;
  float m = NEG_INF;
  for (int s = tid; s < S_LEN; s += 256) { buf[s] = sb[s]; m = fmaxf(m, buf[s]); }
#pragma unroll
  for (int o = 32; o; o >>= 1) m = fmaxf(m, __shfl_xor(m, o, 64));
  if ((tid & 63) == 0) scratch[tid >> 6] = m;
  __syncthreads();
  m = fmaxf(fmaxf(scratch[0], scratch[1]), fmaxf(scratch[2], scratch[3]));
  __syncthreads();
  float z = 0.0f;
  for (int s = tid; s < S_LEN; s += 256) { float e = expf(buf[s] - m); buf[s] = e; z += e; }
#pragma unroll
  for (int o = 32; o; o >>= 1) z += __shfl_xor(z, o, 64);
  if ((tid & 63) == 0) scratch[tid >> 6] = z;
  __syncthreads();
  float Z = scratch[0] + scratch[1] + scratch[2] + scratch[3];
  const float inv = 1.0f / Z;
  for (int s = tid; s < S_LEN; s += 256) sb[s] = buf[s] * inv;
}

// ---------------- pooling stage 3: partial weighted sums over s-chunks ---------
__global__ __launch_bounds__(256) void pool_sum(
    const float* __restrict__ X, const float* __restrict__ wgt,
    float* __restrict__ partial) {
  const int bx = blockIdx.x;            // dchunk*8 + schunk
  const int b = blockIdx.y;
  const int dchunk = bx >> 3, schunk = bx & 7;
  const int d = (dchunk << 8) + threadIdx.x;
  const int s0 = schunk << 7;
  const float* xb = X + ((size_t)(b << 10) + s0) * D_MODEL + d;
  const float* wb = wgt + (b << 10) + s0;
  float acc = 0.0f;
  for (int s = 0; s < 128; ++s) acc += wb[s] * xb[(size_t)s * D_MODEL];
  partial[((size_t)((b << 3) + schunk)) * D_MODEL + d] = acc;
}

// ---------------- classifier finish: reduce partials, tanh, LN, MLP ------------
__global__ __launch_bounds__(256) void cls_finish(
    const float* __restrict__ partial,
    const float* __restrict__ ln_s, const float* __restrict__ ln_b,
    const float* __restrict__ w1, const float* __restrict__ b1,
    const float* __restrict__ w2, const float* __restrict__ b2,
    float* __restrict__ out) {
  const int b = blockIdx.x;
  const int tid = threadIdx.x;
  __shared__ float scratch[4];
  __shared__ __align__(16) float pbuf[D_MODEL];
  __shared__ __align__(16) float cbuf[D_MODEL];
  __shared__ __align__(16) float c1[D_MODEL];
  for (int d = tid; d < D_MODEL; d += 256) {
    float acc = 0.0f;
#pragma unroll
    for (int p = 0; p < 8; ++p) acc += partial[((size_t)((b << 3) + p)) * D_MODEL + d];
    pbuf[d] = tanhf(acc);
  }
  __syncthreads();
  float ls = 0.0f;
  for (int d = tid; d < D_MODEL; d += 256) ls += pbuf[d];
#pragma unroll
  for (int o = 32; o; o >>= 1) ls += __shfl_xor(ls, o, 64);
  if ((tid & 63) == 0) scratch[tid >> 6] = ls;
  __syncthreads();
  float mean = (scratch[0] + scratch[1] + scratch[2] + scratch[3]) * (1.0f / 768.0f);
  __syncthreads();
  float vs = 0.0f;
  for (int d = tid; d < D_MODEL; d += 256) { float dd = pbuf[d] - mean; vs += dd * dd; }
#pragma unroll
  for (int o = 32; o; o >>= 1) vs += __shfl_xor(vs, o, 64);
  if ((tid & 63) == 0) scratch[tid >> 6] = vs;
  __syncthreads();
  float var = (scratch[0] + scratch[1] + scratch[2] + scratch[3]) * (1.0f / 768.0f);
  float rstd = rsqrtf(var + 1e-5f);
  __syncthreads();
  for (int d = tid; d < D_MODEL; d += 256)
    cbuf[d] = (pbuf[d] - mean) * rstd * ln_s[d] + ln_b[d];
  __syncthreads();
  for (int i = tid; i < D_MODEL; i += 256) {
    const float* wr = w1 + (size_t)i * D_MODEL;
    float acc = 0.0f;
    for (int d = 0; d < D_MODEL; d += 4) {
      float4 wv = *(const float4*)(wr + d);
      float4 cv = *(const float4*)(&cbuf[d]);
      acc += wv.x * cv.x + wv.y * cv.y + wv.z * cv.z + wv.w * cv.w;
    }
    c1[i] = tanhf(acc + b1[i]);
  }
  __syncthreads();
#pragma unroll
  for (int jc = 0; jc < 2; ++jc) {
    float acc = 0.0f;
    for (int i = tid; i < D_MODEL; i += 256) acc += c1[i] * w2[jc * D_MODEL + i];
#pragma unroll
    for (int o = 32; o; o >>= 1) acc += __shfl_xor(acc, o, 64);
    if ((tid & 63) == 0) scratch[tid >> 6] = acc;
    __syncthreads();
    if (tid == 0) out[b * 2 + jc] = scratch[0] + scratch[1] + scratch[2] + scratch[3] + b2[jc];
    __syncthreads();
  }
}

extern "C" void kernel_launch(void* const* d_in, const int* in_sizes, int n_in,
                              void* d_out, int out_size, void* d_ws, size_t ws_size,
                              hipStream_t stream) {
  const int*   tokens  = (const int*)d_in[0];
  const int*   mask    = (const int*)d_in[1];
  const float* emb     = (const float*)d_in[2];
  const float* in_w    = (const float*)d_in[3];
  const float* in_b    = (const float*)d_in[4];
  const float* out_w   = (const float*)d_in[5];
  const float* out_b   = (const float*)d_in[6];
  const float* ln1_s   = (const float*)d_in[7];
  const float* ln1_b   = (const float*)d_in[8];
  const float* ln2_s   = (const float*)d_in[9];
  const float* ln2_b   = (const float*)d_in[10];
  const float* ff_w1   = (const float*)d_in[11];
  const float* ff_b1   = (const float*)d_in[12];
  const float* ff_w2   = (const float*)d_in[13];
  const float* ff_b2   = (const float*)d_in[14];
  const float* pool_w  = (const float*)d_in[15];
  const float* pool_b  = (const float*)d_in[16];
  const float* cls_ln_s = (const float*)d_in[17];
  const float* cls_ln_b = (const float*)d_in[18];
  const float* cls_w1  = (const float*)d_in[19];
  const float* cls_b1  = (const float*)d_in[20];
  const float* cls_w2  = (const float*)d_in[21];
  const float* cls_b2  = (const float*)d_in[22];

  float* outp = (float*)d_out;
  float* ws = (float*)d_ws;
  const size_t XN = (size_t)8 * 1024 * 768;          // 6,291,456
  const size_t BIGU = (size_t)8192 * 3072;           // 25,165,824 ushorts
  float* x = ws;
  unsigned short* bigu = (unsigned short*)(ws + XN);             // fp16 qkv / gelu
  unsigned short* h_f16 = (unsigned short*)(ws + XN + BIGU / 2); // fp16 activations
  unsigned short* wall = h_f16 + XN;                             // fp16 weight arena
  unsigned short* wall_in  = wall;                               // 4*2304*768
  unsigned short* wall_out = wall + (size_t)7077888;             // 4*768*768
  unsigned short* wall_ff1 = wall + (size_t)9437184;             // 4*3072*768
  unsigned short* wall_ff2 = wall + (size_t)18874368;            // 4*768*3072
  float* clsbuf = (float*)(wall + (size_t)28311552);
  float* sc_ws = clsbuf;                                         // 8192 floats
  float* partial = clsbuf + 8192;                                // 49152 floats
  float* allw = outp + 16;

  hipMemsetAsync(d_out, 0, (size_t)out_size * sizeof(float), stream);

  // upfront weight conversion (all layers)
  cvt_w_h<<<6912, 256, 0, stream>>>(in_w,  wall_in,  1769472);
  cvt_w_h<<<2304, 256, 0, stream>>>(out_w, wall_out,  589824);
  cvt_w_h<<<9216, 256, 0, stream>>>(ff_w1, wall_ff1, 2359296);
  cvt_w_h<<<9216, 256, 0, stream>>>(ff_w2, wall_ff2, 2359296);

  const int total = (int)XN;
  embed_kernel<<<(total + 255) / 256, 256, 0, stream>>>(tokens, emb, x, total);

  for (int l = 0; l < 4; ++l) {
    ln_kernel<<<8192, 256, 0, stream>>>(x, ln1_s + l * 768, ln1_b + l * 768, h_f16);
    gemm128<0><<<1152, 256, 0, stream>>>(h_f16, wall_in + (size_t)l * 1769472,
                                         in_b + l * 2304, bigu, 2304, 768, 18);
    attn_kernel<<<dim3(S_LEN / QT, 8), 512, 0, stream>>>(bigu, mask, h_f16,
                                                         allw + (size_t)l * 8 * 1024 * 1024);
    gemm64r<<<768, 256, 0, stream>>>(h_f16, wall_out + (size_t)l * 589824,
                                     out_b + l * 768, x, 768, 768, 6);
    ln_kernel<<<8192, 256, 0, stream>>>(x, ln2_s + l * 768, ln2_b + l * 768, h_f16);
    gemm128<1><<<1536, 256, 0, stream>>>(h_f16, wall_ff1 + (size_t)l * 2359296,
                                         ff_b1 + l * 3072, bigu, 3072, 768, 24);
    gemm64r<<<768, 256, 0, stream>>>(bigu, wall_ff2 + (size_t)l * 2359296,
                                     ff_b2 + l * 768, x, 768, 3072, 6);
  }

  pool_score<<<2048, 256, 0, stream>>>(x, mask, pool_w, pool_b, sc_ws);
  pool_softmax<<<8, 256, 0, stream>>>(sc_ws);
  pool_sum<<<dim3(24, 8), 256, 0, stream>>>(x, sc_ws, partial);
  cls_finish<<<8, 256, 0, stream>>>(partial, cls_ln_s, cls_ln_b,
                                    cls_w1, cls_b1, cls_w2, cls_b2, outp);
}

// Round 10
// 1479.281 us; speedup vs baseline: 10.5761x; 1.0160x over previous
//
#include <hip/hip_runtime.h>
#include <math.h>

#define S_LEN 1024
#define D_MODEL 768
#define NHEAD 12
#define NEG_INF -3.4028234663852886e38f

#define QT 32           // queries per attention block
#define KB 288          // key band per block = QT + 2*128

typedef _Float16 f16x8 __attribute__((ext_vector_type(8)));
typedef __attribute__((ext_vector_type(4))) float f32x4;

typedef const __attribute__((address_space(1))) unsigned int ga_u32;
typedef __attribute__((address_space(3))) unsigned int ls_u32;
__device__ __forceinline__ void gload16(const void* g, void* l) {
  __builtin_amdgcn_global_load_lds((ga_u32*)g, (ls_u32*)l, 16, 0, 0);
}

__device__ __forceinline__ float gelu_exact(float v) {
  return 0.5f * v * (1.0f + erff(v * 0.7071067811865475f));
}
__device__ __forceinline__ unsigned short f2h(float f) {
  union { _Float16 h; unsigned short u; } x; x.h = (_Float16)f; return x.u;
}

// ---------------- embedding + sinusoidal positional encoding ----------------
__global__ __launch_bounds__(256) void embed_kernel(
    const int* __restrict__ tok, const float* __restrict__ emb,
    float* __restrict__ X, int total) {
  int i = blockIdx.x * 256 + threadIdx.x;
  if (i >= total) return;
  int d = i % D_MODEL;
  int bs = i / D_MODEL;
  int s = bs & (S_LEN - 1);
  int t = tok[bs];
  float div = expf((float)(d & ~1) * (-9.210340371976184f / 768.0f));
  float ang = (float)s * div;
  float pe = (d & 1) ? cosf(ang) : sinf(ang);
  X[i] = emb[(size_t)t * D_MODEL + d] + pe;
}

// ---------------- weight convert: fp32 -> fp16 ----------------
__global__ __launch_bounds__(256) void cvt_w_h(
    const float* __restrict__ W, unsigned short* __restrict__ H, int n4) {
  int i = blockIdx.x * 256 + threadIdx.x;
  if (i >= n4) return;
  float4 w = ((const float4*)W)[i];
  ushort4 h;
  h.x = f2h(w.x); h.y = f2h(w.y); h.z = f2h(w.z); h.w = f2h(w.w);
  ((ushort4*)H)[i] = h;
}

// ---------------- LayerNorm over D=768 -> fp16 output ----------------
__global__ __launch_bounds__(256) void ln_kernel(
    const float* __restrict__ X, const float* __restrict__ gam,
    const float* __restrict__ bet, unsigned short* __restrict__ Y) {
  __shared__ float scratch[4];
  const int row = blockIdx.x;
  const int tid = threadIdx.x;
  const float* xr = X + (size_t)row * D_MODEL;
  float v0 = xr[tid], v1 = xr[tid + 256], v2 = xr[tid + 512];
  float s = v0 + v1 + v2;
#pragma unroll
  for (int o = 32; o; o >>= 1) s += __shfl_xor(s, o, 64);
  if ((tid & 63) == 0) scratch[tid >> 6] = s;
  __syncthreads();
  float mean = (scratch[0] + scratch[1] + scratch[2] + scratch[3]) * (1.0f / 768.0f);
  __syncthreads();
  float d0 = v0 - mean, d1 = v1 - mean, d2 = v2 - mean;
  float ss = d0 * d0 + d1 * d1 + d2 * d2;
#pragma unroll
  for (int o = 32; o; o >>= 1) ss += __shfl_xor(ss, o, 64);
  if ((tid & 63) == 0) scratch[tid >> 6] = ss;
  __syncthreads();
  float var = (scratch[0] + scratch[1] + scratch[2] + scratch[3]) * (1.0f / 768.0f);
  float rstd = rsqrtf(var + 1e-5f);
  unsigned short* yr = Y + (size_t)row * D_MODEL;
  yr[tid]       = f2h(d0 * rstd * gam[tid]       + bet[tid]);
  yr[tid + 256] = f2h(d1 * rstd * gam[tid + 256] + bet[tid + 256]);
  yr[tid + 512] = f2h(d2 * rstd * gam[tid + 512] + bet[tid + 512]);
}

// ---------------- gemm128: C_f16[m,n] = A*W^T + bias (EPI1: gelu) ----------------
// 128x128 tile, BK=32, 4 waves, 3-deep counted-vmcnt global_load_lds pipeline
// (T4: raw s_barrier + s_waitcnt vmcnt(N), never 0 in steady state).
template <int EPI>
__global__ __launch_bounds__(256) void gemm128(
    const unsigned short* __restrict__ A, const unsigned short* __restrict__ W,
    const float* __restrict__ bias, unsigned short* __restrict__ C,
    int N, int K, int NX) {
  __shared__ __align__(16) unsigned short SH[24576];  // 3 buffers x (A 8KB + B 8KB)
  const int tid = threadIdx.x;
  const int nwg = gridDim.x;
  const int wg = ((blockIdx.x & 7) * (nwg >> 3)) + (blockIdx.x >> 3);
  const int ty = wg / NX, tx = wg - ty * NX;
  const int m0 = ty << 7, n0 = tx << 7;
  const int wave = tid >> 6, lane = tid & 63;
  const int wr = (wave >> 1) << 6, wc = (wave & 1) << 6;
  const int lq = lane >> 4, lr = lane & 15;
  const int rA0 = (wave << 5) + (lane >> 2);
  const int rA1 = rA0 + 16;
  const int sl = lane & 3;
  const size_t gA0 = (size_t)(m0 + rA0) * K + ((sl ^ ((rA0 >> 1) & 3)) << 3);
  const size_t gA1 = (size_t)(m0 + rA1) * K + ((sl ^ ((rA1 >> 1) & 3)) << 3);
  const size_t gB0 = (size_t)(n0 + rA0) * K + ((sl ^ ((rA0 >> 1) & 3)) << 3);
  const size_t gB1 = (size_t)(n0 + rA1) * K + ((sl ^ ((rA1 >> 1) & 3)) << 3);
  const int lws = wave << 10;

  const int nt = K >> 5;
  auto stage = [&](int buf, int t) {
    unsigned short* base = SH + (buf << 13);
    const int kk = t << 5;
    gload16(A + gA0 + kk, base + lws);
    gload16(A + gA1 + kk, base + lws + 512);
    gload16(W + gB0 + kk, base + 4096 + lws);
    gload16(W + gB1 + kk, base + 4096 + lws + 512);
  };
  stage(0, 0);
  stage(1, 1);

  f32x4 acc[4][4] = {};
  int cb = 0;                         // compute-buffer index (cycles 0,1,2)
  for (int t = 0; t < nt; ++t) {
    if (t + 2 < nt) {
      int sb = cb + 2; if (sb >= 3) sb -= 3;
      stage(sb, t + 2);
      asm volatile("s_waitcnt vmcnt(8)" ::: "memory");   // tile t's 4 loads done
    } else if (t + 2 == nt) {
      asm volatile("s_waitcnt vmcnt(4)" ::: "memory");
    } else {
      asm volatile("s_waitcnt vmcnt(0)" ::: "memory");
    }
    __builtin_amdgcn_s_barrier();                         // everyone's tile t ready
    __builtin_amdgcn_sched_barrier(0);
    const unsigned short* As = SH + (cb << 13);
    const unsigned short* Bs = As + 4096;
    f16x8 af[4], bq[4];
#pragma unroll
    for (int i = 0; i < 4; ++i) {
      int r = wr + (i << 4) + lr;
      af[i] = *(const f16x8*)&As[r * 32 + ((lq ^ ((r >> 1) & 3)) << 3)];
    }
#pragma unroll
    for (int j = 0; j < 4; ++j) {
      int r = wc + (j << 4) + lr;
      bq[j] = *(const f16x8*)&Bs[r * 32 + ((lq ^ ((r >> 1) & 3)) << 3)];
    }
#pragma unroll
    for (int i = 0; i < 4; ++i)
#pragma unroll
      for (int j = 0; j < 4; ++j)
        acc[i][j] = __builtin_amdgcn_mfma_f32_16x16x32_f16(af[i], bq[j], acc[i][j], 0, 0, 0);
    __builtin_amdgcn_sched_barrier(0);
    __builtin_amdgcn_s_barrier();                         // buf cb free for restage
    cb = (cb == 2) ? 0 : cb + 1;
  }
  // bias per j-fragment column
  float bval[4];
#pragma unroll
  for (int j = 0; j < 4; ++j) bval[j] = bias[n0 + wc + (j << 4) + lr];
  __syncthreads();
  // repacked epilogue: two 64-row halves through LDS buffer 0, 16B/lane stores
#pragma unroll
  for (int hh = 0; hh < 2; ++hh) {
    if ((wave >> 1) == hh) {
#pragma unroll
      for (int i = 0; i < 4; ++i)
#pragma unroll
        for (int j = 0; j < 4; ++j) {
          const int colb = wc + (j << 4) + lr;
#pragma unroll
          for (int r = 0; r < 4; ++r) {
            const int rowl = (i << 4) + (lq << 2) + r;
            float v = acc[i][j][r] + bval[j];
            if (EPI == 1) v = gelu_exact(v);
            const int ch = (colb >> 3) ^ (rowl & 7);
            SH[rowl * 128 + (ch << 3) + (colb & 7)] = f2h(v);
          }
        }
    }
    __syncthreads();
#pragma unroll
    for (int it = 0; it < 4; ++it) {
      const int cid = tid + (it << 8);
      const int row = cid >> 4, ch = cid & 15;
      uint4 v8 = *(uint4*)&SH[row * 128 + ((ch ^ (row & 7)) << 3)];
      *(uint4*)&C[(size_t)(m0 + (hh << 6) + row) * N + n0 + (ch << 3)] = v8;
    }
    __syncthreads();
  }
}

// ---------------- gemm64r: x_f32[m,n] += A*W^T + bias (residual) ----------------
// 64x128 tile, BK=32, 4 waves, 3-deep counted-vmcnt pipeline.
__global__ __launch_bounds__(256) void gemm64r(
    const unsigned short* __restrict__ A, const unsigned short* __restrict__ W,
    const float* __restrict__ bias, float* __restrict__ C, int N, int K, int NX) {
  __shared__ __align__(16) unsigned short SH[18432];  // 3 x (A 4KB + B 8KB)
  const int tid = threadIdx.x;
  const int nwg = gridDim.x;
  const int wg = ((blockIdx.x & 7) * (nwg >> 3)) + (blockIdx.x >> 3);
  const int ty = wg / NX, tx = wg - ty * NX;
  const int m0 = ty << 6, n0 = tx << 7;
  const int wave = tid >> 6, lane = tid & 63;
  const int wr = (wave >> 1) << 5, wc = (wave & 1) << 6;
  const int lq = lane >> 4, lr = lane & 15;
  const int rA = (wave << 4) + (lane >> 2);
  const int rB0 = (wave << 5) + (lane >> 2);
  const int rB1 = rB0 + 16;
  const int sl = lane & 3;
  const size_t gA  = (size_t)(m0 + rA) * K + ((sl ^ ((rA >> 1) & 3)) << 3);
  const size_t gB0 = (size_t)(n0 + rB0) * K + ((sl ^ ((rB0 >> 1) & 3)) << 3);
  const size_t gB1 = (size_t)(n0 + rB1) * K + ((sl ^ ((rB1 >> 1) & 3)) << 3);
  const int lwA = wave << 9;
  const int lwB = wave << 10;

  const int nt = K >> 5;
  auto stage = [&](int buf, int t) {
    unsigned short* base = SH + buf * 6144;
    const int kk = t << 5;
    gload16(A + gA + kk, base + lwA);
    gload16(W + gB0 + kk, base + 2048 + lwB);
    gload16(W + gB1 + kk, base + 2048 + lwB + 512);
  };
  stage(0, 0);
  stage(1, 1);

  f32x4 acc[2][4] = {};
  int cb = 0;
  for (int t = 0; t < nt; ++t) {
    if (t + 2 < nt) {
      int sb = cb + 2; if (sb >= 3) sb -= 3;
      stage(sb, t + 2);
      asm volatile("s_waitcnt vmcnt(6)" ::: "memory");   // tile t's 3 loads done
    } else if (t + 2 == nt) {
      asm volatile("s_waitcnt vmcnt(3)" ::: "memory");
    } else {
      asm volatile("s_waitcnt vmcnt(0)" ::: "memory");
    }
    __builtin_amdgcn_s_barrier();
    __builtin_amdgcn_sched_barrier(0);
    const unsigned short* As = SH + cb * 6144;
    const unsigned short* Bs = As + 2048;
    f16x8 af[2], bq[4];
#pragma unroll
    for (int i = 0; i < 2; ++i) {
      int r = wr + (i << 4) + lr;
      af[i] = *(const f16x8*)&As[r * 32 + ((lq ^ ((r >> 1) & 3)) << 3)];
    }
#pragma unroll
    for (int j = 0; j < 4; ++j) {
      int r = wc + (j << 4) + lr;
      bq[j] = *(const f16x8*)&Bs[r * 32 + ((lq ^ ((r >> 1) & 3)) << 3)];
    }
#pragma unroll
    for (int i = 0; i < 2; ++i)
#pragma unroll
      for (int j = 0; j < 4; ++j)
        acc[i][j] = __builtin_amdgcn_mfma_f32_16x16x32_f16(af[i], bq[j], acc[i][j], 0, 0, 0);
    __builtin_amdgcn_sched_barrier(0);
    __builtin_amdgcn_s_barrier();
    cb = (cb == 2) ? 0 : cb + 1;
  }
#pragma unroll
  for (int j = 0; j < 4; ++j) {
    const int gcol = n0 + wc + (j << 4) + lr;
    const float bv = bias[gcol];
#pragma unroll
    for (int i = 0; i < 2; ++i) {
      const int grow0 = m0 + wr + (i << 4) + (lq << 2);
#pragma unroll
      for (int r = 0; r < 4; ++r) {
        size_t off = (size_t)(grow0 + r) * N + gcol;
        C[off] += acc[i][j][r] + bv;
      }
    }
  }
}

// ---------------- banded attention: MFMA QK^T + softmax + MFMA PV (fp16) ---------
__global__ __launch_bounds__(512) void attn_kernel(
    const unsigned short* __restrict__ qkv, const int* __restrict__ mask,
    unsigned short* __restrict__ attn_out, float* __restrict__ allw) {
  __shared__ __align__(16) unsigned short Ks[KB * 72];
  __shared__ __align__(16) unsigned short Vt[64 * 328];
  __shared__ __align__(16) unsigned short Qs[32 * 72];
  __shared__ __align__(16) unsigned short Ps[32 * 328];
  __shared__ __align__(16) float redmax[2][16][4];
  __shared__ __align__(16) float redsum[2][16][4];
  __shared__ int kvalid[KB];

  const int qt0 = blockIdx.x * QT;
  const int b = blockIdx.y;
  const int tid = threadIdx.x;
  const int w = tid >> 6, lane = tid & 63;
  const int lr = lane & 15, lg = lane >> 4;
  const int k0 = qt0 - 128;
  const int qh = w & 1, wq = w >> 1;
  const int nkt = (wq < 2) ? 5 : 4;

  for (int j = tid; j < KB; j += 512) {
    int key = k0 + j;
    kvalid[j] = (key >= 0 && key < S_LEN && mask[b * S_LEN + key] != 0) ? 1 : 0;
  }

  f32x4 pm[5] = {};
  const size_t rowbase = (size_t)(b * S_LEN) * 2304;
  const int qloc = lg << 2;
  const int qbase = (qh << 4) + qloc;

  for (int h = 0; h < NHEAD; ++h) {
    const int hoff = h << 6;
    if (tid < 256) {
      int r = tid >> 3, c = tid & 7;
      uint4 v = *(const uint4*)(qkv + rowbase + (size_t)(qt0 + r) * 2304 + hoff + (c << 3));
      *(uint4*)&Qs[r * 72 + ((c ^ (r & 7)) << 3)] = v;
    }
    for (int idx = tid; idx < 2304; idx += 512) {
      int r = idx >> 3, c = idx & 7;
      int key = k0 + r;
      uint4 kv = {0, 0, 0, 0}, vv = {0, 0, 0, 0};
      if ((unsigned)key < (unsigned)S_LEN) {
        const unsigned short* base = qkv + rowbase + (size_t)key * 2304 + hoff + (c << 3);
        kv = *(const uint4*)(base + 768);
        vv = *(const uint4*)(base + 1536);
      }
      *(uint4*)&Ks[r * 72 + ((c ^ (r & 7)) << 3)] = kv;
      const unsigned short* ve = (const unsigned short*)&vv;
      int jc = r >> 3, jw = r & 7;
#pragma unroll
      for (int e = 0; e < 8; ++e) {
        int d = (c << 3) + e;
        Vt[d * 328 + ((jc ^ ((d >> 2) & 7)) << 3) + jw] = ve[e];
      }
    }
    __syncthreads();

    f16x8 aq[2];
#pragma unroll
    for (int kc = 0; kc < 2; ++kc) {
      int r = (qh << 4) + lr;
      aq[kc] = *(f16x8*)&Qs[r * 72 + ((((kc << 2) + lg) ^ (r & 7)) << 3)];
    }
    f32x4 sc[5];
#pragma unroll
    for (int t = 0; t < 5; ++t) {
      sc[t] = (f32x4){0.0f, 0.0f, 0.0f, 0.0f};
      if (t < nkt) {
        int r = ((wq + (t << 2)) << 4) + lr;
#pragma unroll
        for (int kc = 0; kc < 2; ++kc) {
          f16x8 bk = *(f16x8*)&Ks[r * 72 + ((((kc << 2) + lg) ^ (r & 7)) << 3)];
          sc[t] = __builtin_amdgcn_mfma_f32_16x16x32_f16(aq[kc], bk, sc[t], 0, 0, 0);
        }
      }
    }
#pragma unroll
    for (int t = 0; t < 5; ++t) if (t < nkt) {
      int j = ((wq + (t << 2)) << 4) + lr;
      int okk = kvalid[j];
#pragma unroll
      for (int rg = 0; rg < 4; ++rg) {
        int q = qbase + rg;
        float s = sc[t][rg] * 0.125f;
        sc[t][rg] = (okk && j >= q && j <= q + 256) ? s : NEG_INF;
      }
    }
    float mx[4], zs[4];
#pragma unroll
    for (int rg = 0; rg < 4; ++rg) {
      float m = NEG_INF;
#pragma unroll
      for (int t = 0; t < 5; ++t) if (t < nkt) m = fmaxf(m, sc[t][rg]);
      mx[rg] = m;
    }
#pragma unroll
    for (int o = 1; o < 16; o <<= 1)
#pragma unroll
      for (int rg = 0; rg < 4; ++rg) mx[rg] = fmaxf(mx[rg], __shfl_xor(mx[rg], o, 64));
    if (lr == 0)
#pragma unroll
      for (int rg = 0; rg < 4; ++rg) redmax[qh][qloc + rg][wq] = mx[rg];
    __syncthreads();
#pragma unroll
    for (int rg = 0; rg < 4; ++rg) {
      f32x4 v = *(f32x4*)&redmax[qh][qloc + rg][0];
      mx[rg] = fmaxf(fmaxf(v[0], v[1]), fmaxf(v[2], v[3]));
      zs[rg] = 0.0f;
    }
#pragma unroll
    for (int t = 0; t < 5; ++t) if (t < nkt)
#pragma unroll
      for (int rg = 0; rg < 4; ++rg) {
        float e = expf(sc[t][rg] - mx[rg]);
        sc[t][rg] = e;
        zs[rg] += e;
      }
#pragma unroll
    for (int o = 1; o < 16; o <<= 1)
#pragma unroll
      for (int rg = 0; rg < 4; ++rg) zs[rg] += __shfl_xor(zs[rg], o, 64);
    if (lr == 0)
#pragma unroll
      for (int rg = 0; rg < 4; ++rg) redsum[qh][qloc + rg][wq] = zs[rg];
    __syncthreads();
#pragma unroll
    for (int rg = 0; rg < 4; ++rg) {
      f32x4 v = *(f32x4*)&redsum[qh][qloc + rg][0];
      zs[rg] = 1.0f / (v[0] + v[1] + v[2] + v[3]);
    }
#pragma unroll
    for (int t = 0; t < 5; ++t) if (t < nkt) {
      int j = ((wq + (t << 2)) << 4) + lr;
      int pc = j >> 3, pw = j & 7;
#pragma unroll
      for (int rg = 0; rg < 4; ++rg) {
        float p = sc[t][rg] * zs[rg];
        pm[t][rg] += p;
        int row = qbase + rg;
        Ps[row * 328 + ((pc ^ (row & 7)) << 3) + pw] = f2h(p);
      }
    }
    __syncthreads();
    {
      const int qt = w >> 2, dt = w & 3;
      const int ra = (qt << 4) + lr;
      const int rd = (dt << 4) + lr;
      f32x4 o4 = {0.0f, 0.0f, 0.0f, 0.0f};
#pragma unroll
      for (int ks = 0; ks < 9; ++ks) {
        f16x8 pa = *(f16x8*)&Ps[ra * 328 + ((((ks << 2) + lg) ^ (ra & 7)) << 3)];
        f16x8 vb = *(f16x8*)&Vt[rd * 328 + ((((ks << 2) + lg) ^ ((rd >> 2) & 7)) << 3)];
        o4 = __builtin_amdgcn_mfma_f32_16x16x32_f16(pa, vb, o4, 0, 0, 0);
      }
      unsigned short* op = attn_out +
          ((size_t)(b * S_LEN + qt0 + (qt << 4) + (lg << 2))) * D_MODEL + hoff + (dt << 4) + lr;
#pragma unroll
      for (int rg = 0; rg < 4; ++rg) op[(size_t)rg * D_MODEL] = f2h(o4[rg]);
    }
    __syncthreads();
  }

#pragma unroll
  for (int t = 0; t < 5; ++t) if (t < nkt) {
    int j = ((wq + (t << 2)) << 4) + lr;
    int key = k0 + j;
    if ((unsigned)key < (unsigned)S_LEN) {
      float* ap = allw + ((size_t)(b * S_LEN) + qt0 + qbase) * S_LEN + key;
#pragma unroll
      for (int rg = 0; rg < 4; ++rg) ap[(size_t)rg * S_LEN] = pm[t][rg] * (1.0f / 12.0f);
    }
  }
}

// ---------------- pooling stage 1: scores sc[b,s] = x·pool_w + pool_b ----------
__global__ __launch_bounds__(256) void pool_score(
    const float* __restrict__ X, const int* __restrict__ mask,
    const float* __restrict__ pool_w, const float* __restrict__ pool_b,
    float* __restrict__ sc) {
  const int tid = threadIdx.x;
  const int wave = tid >> 6, lane = tid & 63;
  const int row = blockIdx.x * 4 + wave;
  const float* xr = X + (size_t)row * D_MODEL;
  float acc = 0.0f;
#pragma unroll
  for (int c = 0; c < 3; ++c) {
    int d = (lane << 2) + (c << 8);
    float4 xv = *(const float4*)(xr + d);
    float4 wv = *(const float4*)(pool_w + d);
    acc += xv.x * wv.x + xv.y * wv.y + xv.z * wv.z + xv.w * wv.w;
  }
#pragma unroll
  for (int o = 32; o; o >>= 1) acc += __shfl_xor(acc, o, 64);
  if (lane == 0)
    sc[row] = (mask[row] == 0) ? NEG_INF : (acc + pool_b[0]);
}

// ---------------- pooling stage 2: softmax over S per batch (in-place) ---------
__global__ __launch_bounds__(256) void pool_softmax(float* __restrict__ sc) {
  __shared__ float scratch[4];
  __shared__ float buf[S_LEN];
  const int b = blockIdx.x;
  const int tid = threadIdx.x;
  float* sb = sc + b * S_LEN;
  float m = NEG_INF;
  for (int s = tid; s < S_LEN; s += 256) { buf[s] = sb[s]; m = fmaxf(m, buf[s]); }
#pragma unroll
  for (int o = 32; o; o >>= 1) m = fmaxf(m, __shfl_xor(m, o, 64));
  if ((tid & 63) == 0) scratch[tid >> 6] = m;
  __syncthreads();
  m = fmaxf(fmaxf(scratch[0], scratch[1]), fmaxf(scratch[2], scratch[3]));
  __syncthreads();
  float z = 0.0f;
  for (int s = tid; s < S_LEN; s += 256) { float e = expf(buf[s] - m); buf[s] = e; z += e; }
#pragma unroll
  for (int o = 32; o; o >>= 1) z += __shfl_xor(z, o, 64);
  if ((tid & 63) == 0) scratch[tid >> 6] = z;
  __syncthreads();
  float Z = scratch[0] + scratch[1] + scratch[2] + scratch[3];
  const float inv = 1.0f / Z;
  for (int s = tid; s < S_LEN; s += 256) sb[s] = buf[s] * inv;
}

// ---------------- pooling stage 3: partial weighted sums over s-chunks ---------
__global__ __launch_bounds__(256) void pool_sum(
    const float* __restrict__ X, const float* __restrict__ wgt,
    float* __restrict__ partial) {
  const int bx = blockIdx.x;            // dchunk*8 + schunk
  const int b = blockIdx.y;
  const int dchunk = bx >> 3, schunk = bx & 7;
  const int d = (dchunk << 8) + threadIdx.x;
  const int s0 = schunk << 7;
  const float* xb = X + ((size_t)(b << 10) + s0) * D_MODEL + d;
  const float* wb = wgt + (b << 10) + s0;
  float acc = 0.0f;
  for (int s = 0; s < 128; ++s) acc += wb[s] * xb[(size_t)s * D_MODEL];
  partial[((size_t)((b << 3) + schunk)) * D_MODEL + d] = acc;
}

// ---------------- classifier finish: reduce partials, tanh, LN, MLP ------------
__global__ __launch_bounds__(256) void cls_finish(
    const float* __restrict__ partial,
    const float* __restrict__ ln_s, const float* __restrict__ ln_b,
    const float* __restrict__ w1, const float* __restrict__ b1,
    const float* __restrict__ w2, const float* __restrict__ b2,
    float* __restrict__ out) {
  const int b = blockIdx.x;
  const int tid = threadIdx.x;
  __shared__ float scratch[4];
  __shared__ __align__(16) float pbuf[D_MODEL];
  __shared__ __align__(16) float cbuf[D_MODEL];
  __shared__ __align__(16) float c1[D_MODEL];
  for (int d = tid; d < D_MODEL; d += 256) {
    float acc = 0.0f;
#pragma unroll
    for (int p = 0; p < 8; ++p) acc += partial[((size_t)((b << 3) + p)) * D_MODEL + d];
    pbuf[d] = tanhf(acc);
  }
  __syncthreads();
  float ls = 0.0f;
  for (int d = tid; d < D_MODEL; d += 256) ls += pbuf[d];
#pragma unroll
  for (int o = 32; o; o >>= 1) ls += __shfl_xor(ls, o, 64);
  if ((tid & 63) == 0) scratch[tid >> 6] = ls;
  __syncthreads();
  float mean = (scratch[0] + scratch[1] + scratch[2] + scratch[3]) * (1.0f / 768.0f);
  __syncthreads();
  float vs = 0.0f;
  for (int d = tid; d < D_MODEL; d += 256) { float dd = pbuf[d] - mean; vs += dd * dd; }
#pragma unroll
  for (int o = 32; o; o >>= 1) vs += __shfl_xor(vs, o, 64);
  if ((tid & 63) == 0) scratch[tid >> 6] = vs;
  __syncthreads();
  float var = (scratch[0] + scratch[1] + scratch[2] + scratch[3]) * (1.0f / 768.0f);
  float rstd = rsqrtf(var + 1e-5f);
  __syncthreads();
  for (int d = tid; d < D_MODEL; d += 256)
    cbuf[d] = (pbuf[d] - mean) * rstd * ln_s[d] + ln_b[d];
  __syncthreads();
  for (int i = tid; i < D_MODEL; i += 256) {
    const float* wr = w1 + (size_t)i * D_MODEL;
    float acc = 0.0f;
    for (int d = 0; d < D_MODEL; d += 4) {
      float4 wv = *(const float4*)(wr + d);
      float4 cv = *(const float4*)(&cbuf[d]);
      acc += wv.x * cv.x + wv.y * cv.y + wv.z * cv.z + wv.w * cv.w;
    }
    c1[i] = tanhf(acc + b1[i]);
  }
  __syncthreads();
#pragma unroll
  for (int jc = 0; jc < 2; ++jc) {
    float acc = 0.0f;
    for (int i = tid; i < D_MODEL; i += 256) acc += c1[i] * w2[jc * D_MODEL + i];
#pragma unroll
    for (int o = 32; o; o >>= 1) acc += __shfl_xor(acc, o, 64);
    if ((tid & 63) == 0) scratch[tid >> 6] = acc;
    __syncthreads();
    if (tid == 0) out[b * 2 + jc] = scratch[0] + scratch[1] + scratch[2] + scratch[3] + b2[jc];
    __syncthreads();
  }
}

extern "C" void kernel_launch(void* const* d_in, const int* in_sizes, int n_in,
                              void* d_out, int out_size, void* d_ws, size_t ws_size,
                              hipStream_t stream) {
  const int*   tokens  = (const int*)d_in[0];
  const int*   mask    = (const int*)d_in[1];
  const float* emb     = (const float*)d_in[2];
  const float* in_w    = (const float*)d_in[3];
  const float* in_b    = (const float*)d_in[4];
  const float* out_w   = (const float*)d_in[5];
  const float* out_b   = (const float*)d_in[6];
  const float* ln1_s   = (const float*)d_in[7];
  const float* ln1_b   = (const float*)d_in[8];
  const float* ln2_s   = (const float*)d_in[9];
  const float* ln2_b   = (const float*)d_in[10];
  const float* ff_w1   = (const float*)d_in[11];
  const float* ff_b1   = (const float*)d_in[12];
  const float* ff_w2   = (const float*)d_in[13];
  const float* ff_b2   = (const float*)d_in[14];
  const float* pool_w  = (const float*)d_in[15];
  const float* pool_b  = (const float*)d_in[16];
  const float* cls_ln_s = (const float*)d_in[17];
  const float* cls_ln_b = (const float*)d_in[18];
  const float* cls_w1  = (const float*)d_in[19];
  const float* cls_b1  = (const float*)d_in[20];
  const float* cls_w2  = (const float*)d_in[21];
  const float* cls_b2  = (const float*)d_in[22];

  float* outp = (float*)d_out;
  float* ws = (float*)d_ws;
  const size_t XN = (size_t)8 * 1024 * 768;          // 6,291,456
  const size_t BIGU = (size_t)8192 * 3072;           // 25,165,824 ushorts
  float* x = ws;
  unsigned short* bigu = (unsigned short*)(ws + XN);             // fp16 qkv / gelu
  unsigned short* h_f16 = (unsigned short*)(ws + XN + BIGU / 2); // fp16 activations
  unsigned short* wall = h_f16 + XN;                             // fp16 weight arena
  unsigned short* wall_in  = wall;                               // 4*2304*768
  unsigned short* wall_out = wall + (size_t)7077888;             // 4*768*768
  unsigned short* wall_ff1 = wall + (size_t)9437184;             // 4*3072*768
  unsigned short* wall_ff2 = wall + (size_t)18874368;            // 4*768*3072
  float* clsbuf = (float*)(wall + (size_t)28311552);
  float* sc_ws = clsbuf;                                         // 8192 floats
  float* partial = clsbuf + 8192;                                // 49152 floats
  float* allw = outp + 16;

  hipMemsetAsync(d_out, 0, (size_t)out_size * sizeof(float), stream);

  // upfront weight conversion (all layers)
  cvt_w_h<<<6912, 256, 0, stream>>>(in_w,  wall_in,  1769472);
  cvt_w_h<<<2304, 256, 0, stream>>>(out_w, wall_out,  589824);
  cvt_w_h<<<9216, 256, 0, stream>>>(ff_w1, wall_ff1, 2359296);
  cvt_w_h<<<9216, 256, 0, stream>>>(ff_w2, wall_ff2, 2359296);

  const int total = (int)XN;
  embed_kernel<<<(total + 255) / 256, 256, 0, stream>>>(tokens, emb, x, total);

  for (int l = 0; l < 4; ++l) {
    ln_kernel<<<8192, 256, 0, stream>>>(x, ln1_s + l * 768, ln1_b + l * 768, h_f16);
    gemm128<0><<<1152, 256, 0, stream>>>(h_f16, wall_in + (size_t)l * 1769472,
                                         in_b + l * 2304, bigu, 2304, 768, 18);
    attn_kernel<<<dim3(S_LEN / QT, 8), 512, 0, stream>>>(bigu, mask, h_f16,
                                                         allw + (size_t)l * 8 * 1024 * 1024);
    gemm64r<<<768, 256, 0, stream>>>(h_f16, wall_out + (size_t)l * 589824,
                                     out_b + l * 768, x, 768, 768, 6);
    ln_kernel<<<8192, 256, 0, stream>>>(x, ln2_s + l * 768, ln2_b + l * 768, h_f16);
    gemm128<1><<<1536, 256, 0, stream>>>(h_f16, wall_ff1 + (size_t)l * 2359296,
                                         ff_b1 + l * 3072, bigu, 3072, 768, 24);
    gemm64r<<<768, 256, 0, stream>>>(bigu, wall_ff2 + (size_t)l * 2359296,
                                     ff_b2 + l * 768, x, 768, 3072, 6);
  }

  pool_score<<<2048, 256, 0, stream>>>(x, mask, pool_w, pool_b, sc_ws);
  pool_softmax<<<8, 256, 0, stream>>>(sc_ws);
  pool_sum<<<dim3(24, 8), 256, 0, stream>>>(x, sc_ws, partial);
  cls_finish<<<8, 256, 0, stream>>>(partial, cls_ln_s, cls_ln_b,
                                    cls_w1, cls_b1, cls_w2, cls_b2, outp);
}